// Round 2
// baseline (6493.301 us; speedup 1.0000x reference)
//
#include <hip/hip_runtime.h>

typedef short s16x8 __attribute__((ext_vector_type(8)));
typedef float f32x4 __attribute__((ext_vector_type(4)));

#define DEV __device__ __forceinline__

static constexpr int NC_ = 50000, ND_ = 20000, NG_ = 30000;
static constexpr int EE = 200000, PP_ = 200000;
static constexpr int NTOT = NC_ + ND_ + NG_;   // 100000

DEV unsigned short f2bf(float f) {
  unsigned u = __float_as_uint(f);
  u = u + 0x7FFFu + ((u >> 16) & 1u);
  return (unsigned short)(u >> 16);
}
DEV float bf2f(unsigned short h) { return __uint_as_float(((unsigned)h) << 16); }
// monotone float<->uint encoding for atomicMax on floats (memset-0 == -inf sentinel)
DEV unsigned fenc(float f) { unsigned b = __float_as_uint(f); return (b >> 31) ? ~b : (b | 0x80000000u); }
DEV float fdec(unsigned u) { return __uint_as_float((u >> 31) ? (u & 0x7FFFFFFFu) : ~u); }

// ---------------- batched 128x128 GEMM (MFMA bf16) ----------------
// out[M,128] = act(A[M,128] @ W[128,128] + bias)
// amode 0: A = f32 global.  amode 2: A[row,k] = gelu(ea[row,0]*Wc1[0,k]+ea[row,1]*Wc1[1,k]+bc1[k])
struct GEntry {
  const float* A; const float* W; const float* bias; void* out;
  const float* ea; const float* Wc1; const float* bc1;
  int M; int amode; int act; int outbf16;
};
struct GParams { GEntry e[12]; };

__global__ __launch_bounds__(256) void gemm128(GParams P) {
  GEntry E = P.e[blockIdx.y];
  const int M = E.M;
  const int chunk = blockIdx.x * 512;
  if (chunk >= M) return;

  __shared__ __align__(16) unsigned short ldsW[128 * 128];
  __shared__ float ldsC1[3 * 128];

  const int tid = threadIdx.x;
  // stage W -> LDS transposed+swizzled bf16: element (k,n) at ushort idx n*128 + (k ^ ((n&7)<<3))
  for (int it = tid; it < 16384; it += 256) {
    int k = it >> 7, n = it & 127;
    ldsW[n * 128 + (k ^ ((n & 7) << 3))] = f2bf(E.W[it]);
  }
  if (E.amode == 2 && tid < 128) {
    ldsC1[tid] = E.Wc1[tid];
    ldsC1[128 + tid] = E.Wc1[128 + tid];
    ldsC1[256 + tid] = E.bc1[tid];
  }
  __syncthreads();

  const int w = tid >> 6, lane = tid & 63, g = lane >> 4, c = lane & 15;
  const int colHalf = (w & 1) * 64;
  const int rowHalf = (w >> 1) * 32;

  // B fragments: B[k][n] = W[k][n]; lane (g,c) slot i -> k = s*32+8g+i, n = colHalf+nb*16+c
  s16x8 Bf[4][4];
#pragma unroll
  for (int s = 0; s < 4; ++s)
#pragma unroll
    for (int nb = 0; nb < 4; ++nb) {
      int n = colHalf + nb * 16 + c;
      int idx = n * 128 + ((s * 32 + 8 * g) ^ ((n & 7) << 3));
      Bf[s][nb] = *reinterpret_cast<const s16x8*>(&ldsW[idx]);
    }

  for (int itr = 0; itr < 8; ++itr) {
    if (chunk + itr * 64 >= M) break;
    const int rb = chunk + itr * 64 + rowHalf;

    s16x8 Af[2][4];
#pragma unroll
    for (int mt = 0; mt < 2; ++mt) {
      int row = rb + mt * 16 + c;
      int rr = row < M ? row : M - 1;
      if (E.amode == 0) {
        const float* ap = E.A + (size_t)rr * 128;
#pragma unroll
        for (int s = 0; s < 4; ++s) {
          float4 lo = *reinterpret_cast<const float4*>(ap + s * 32 + 8 * g);
          float4 hi = *reinterpret_cast<const float4*>(ap + s * 32 + 8 * g + 4);
          s16x8 a;
          a[0] = (short)f2bf(lo.x); a[1] = (short)f2bf(lo.y);
          a[2] = (short)f2bf(lo.z); a[3] = (short)f2bf(lo.w);
          a[4] = (short)f2bf(hi.x); a[5] = (short)f2bf(hi.y);
          a[6] = (short)f2bf(hi.z); a[7] = (short)f2bf(hi.w);
          Af[mt][s] = a;
        }
      } else {
        float e0 = E.ea[(size_t)rr * 2], e1 = E.ea[(size_t)rr * 2 + 1];
#pragma unroll
        for (int s = 0; s < 4; ++s) {
          s16x8 a;
#pragma unroll
          for (int i = 0; i < 8; ++i) {
            int k = s * 32 + 8 * g + i;
            float h = e0 * ldsC1[k] + e1 * ldsC1[128 + k] + ldsC1[256 + k];
            h = 0.5f * h * (1.f + erff(h * 0.70710678118f));   // exact gelu
            a[i] = (short)f2bf(h);
          }
          Af[mt][s] = a;
        }
      }
    }

    f32x4 acc[2][4];
#pragma unroll
    for (int mt = 0; mt < 2; ++mt)
#pragma unroll
      for (int nb = 0; nb < 4; ++nb) { acc[mt][nb][0] = 0.f; acc[mt][nb][1] = 0.f; acc[mt][nb][2] = 0.f; acc[mt][nb][3] = 0.f; }

#pragma unroll
    for (int mt = 0; mt < 2; ++mt)
#pragma unroll
      for (int s = 0; s < 4; ++s)
#pragma unroll
        for (int nb = 0; nb < 4; ++nb)
          acc[mt][nb] = __builtin_amdgcn_mfma_f32_16x16x32_bf16(Af[mt][s], Bf[s][nb], acc[mt][nb], 0, 0, 0);

    // D layout: col = lane&15, row = 4*(lane>>4) + reg  (guide m89, HW-verified)
#pragma unroll
    for (int mt = 0; mt < 2; ++mt)
#pragma unroll
      for (int nb = 0; nb < 4; ++nb) {
        int col = colHalf + nb * 16 + c;
        float bv = E.bias ? E.bias[col] : 0.f;
#pragma unroll
        for (int jj = 0; jj < 4; ++jj) {
          int row = rb + mt * 16 + 4 * g + jj;
          if (row < M) {
            float v = acc[mt][nb][jj] + bv;
            if (E.act == 1) v = 1.f / (1.f + expf(-v));
            if (E.outbf16) ((unsigned short*)E.out)[(size_t)row * 128 + col] = f2bf(v);
            else ((float*)E.out)[(size_t)row * 128 + col] = v;
          }
        }
      }
  }
}

// ---------------- per-node attention dots: as/ad[row][h] = dot(h_row[h*32:], attn[rel][h*32:]) ----------------
struct ADParams {
  const unsigned short* h[12]; float* out[12]; int M[12]; int rel[12];
  const float* attn;   // + l*6*128
};
__global__ __launch_bounds__(256) void attdot_kernel(ADParams P) {
  int s = blockIdx.y;
  int row = blockIdx.x * 4 + (threadIdx.x >> 6);
  int lane = threadIdx.x & 63;
  if (row >= P.M[s]) return;
  const unsigned short* hp = P.h[s] + (size_t)row * 128 + lane * 2;
  ushort2 u = *reinterpret_cast<const ushort2*>(hp);
  const float* at = P.attn + P.rel[s] * 128 + lane * 2;
  float p = bf2f(u.x) * at[0] + bf2f(u.y) * at[1];
  // head = lane/16; reduce within 16-lane groups
  p += __shfl_xor(p, 1);
  p += __shfl_xor(p, 2);
  p += __shfl_xor(p, 4);
  p += __shfl_xor(p, 8);
  if ((lane & 15) == 0) P.out[s][(size_t)row * 4 + (lane >> 4)] = p;
}

// ---------------- edge passes ----------------
struct EParams {
  const unsigned short* hs[6];
  const int* src[6];
  const int* dst[6];
  float* ebuf[6];
  unsigned int* smax[6];
  float* ssum[6];
  float* agg[6];
  const float* as_[6];   // as + HSOFF*4
  const float* ad_[6];   // ad + HDOFF*4
  const int* ea[2];
  const float* gtab;     // [2*50*128]
  const unsigned short* G;  // gate buffer for current p3 pass (rel 4 or 5)
  int relLo, relHi;
};

// P1: e[edge][h] = leaky_relu(as[si][h] + ad[di][h]); seg max (1 thread/edge)
__global__ __launch_bounds__(256) void p1_kernel(EParams P) {
  int gt = blockIdx.x * blockDim.x + threadIdx.x;
  int n = gridDim.x * blockDim.x;
  for (int idx = gt; idx < 6 * EE; idx += n) {
    int rel = idx / EE, i = idx - rel * EE;
    int si = P.src[rel][i], di = P.dst[rel][i];
    float4 av = *reinterpret_cast<const float4*>(P.as_[rel] + (size_t)si * 4);
    float4 dv = *reinterpret_cast<const float4*>(P.ad_[rel] + (size_t)di * 4);
    float4 e;
    e.x = av.x + dv.x; e.x = e.x > 0.f ? e.x : 0.2f * e.x;
    e.y = av.y + dv.y; e.y = e.y > 0.f ? e.y : 0.2f * e.y;
    e.z = av.z + dv.z; e.z = e.z > 0.f ? e.z : 0.2f * e.z;
    e.w = av.w + dv.w; e.w = e.w > 0.f ? e.w : 0.2f * e.w;
    *reinterpret_cast<float4*>(P.ebuf[rel] + (size_t)i * 4) = e;
    unsigned* sm = P.smax[rel] + (size_t)di * 4;
    atomicMax(sm + 0, fenc(e.x));
    atomicMax(sm + 1, fenc(e.y));
    atomicMax(sm + 2, fenc(e.z));
    atomicMax(sm + 3, fenc(e.w));
  }
}

// P2: ex = exp(e - max); seg sum (1 thread/edge)
__global__ __launch_bounds__(256) void p2_kernel(EParams P) {
  int gt = blockIdx.x * blockDim.x + threadIdx.x;
  int n = gridDim.x * blockDim.x;
  for (int idx = gt; idx < 6 * EE; idx += n) {
    int rel = idx / EE, i = idx - rel * EE;
    int di = P.dst[rel][i];
    float4 e = *reinterpret_cast<const float4*>(P.ebuf[rel] + (size_t)i * 4);
    uint4 mu = *reinterpret_cast<const uint4*>(P.smax[rel] + (size_t)di * 4);
    float4 ex;
    ex.x = expf(e.x - fdec(mu.x));
    ex.y = expf(e.y - fdec(mu.y));
    ex.z = expf(e.z - fdec(mu.z));
    ex.w = expf(e.w - fdec(mu.w));
    *reinterpret_cast<float4*>(P.ebuf[rel] + (size_t)i * 4) = ex;
    float* sp = P.ssum[rel] + (size_t)di * 4;
    unsafeAtomicAdd(sp + 0, ex.x);
    unsafeAtomicAdd(sp + 1, ex.y);
    unsafeAtomicAdd(sp + 2, ex.z);
    unsafeAtomicAdd(sp + 3, ex.w);
  }
}

// P3: agg[dst] += alpha * ms * gate  (half-wave of 32 lanes per edge)
__global__ __launch_bounds__(256) void p3_kernel(EParams P) {
  int gt = blockIdx.x * blockDim.x + threadIdx.x;
  int hw = gt >> 5, j = gt & 31;
  int nhw = (gridDim.x * blockDim.x) >> 5;
  int relCount = P.relHi - P.relLo + 1;
  for (int idx = hw; idx < relCount * EE; idx += nhw) {
    int rel = P.relLo + idx / EE;
    int i = idx % EE;
    int si = P.src[rel][i], di = P.dst[rel][i];
    int h = j >> 3;
    float ex = P.ebuf[rel][(size_t)i * 4 + h];
    float ss = P.ssum[rel][(size_t)di * 4 + h];
    float alpha = ex / (ss + 1e-16f);
    ushort4 ms = *reinterpret_cast<const ushort4*>(P.hs[rel] + (size_t)si * 128 + 4 * j);
    float g0 = 1.f, g1 = 1.f, g2 = 1.f, g3 = 1.f;
    if (rel < 2) {
      int a = P.ea[rel][(size_t)i * 2], s2 = P.ea[rel][(size_t)i * 2 + 1];
      float4 gv = *reinterpret_cast<const float4*>(P.gtab + (size_t)(rel * 50 + a * 5 + s2) * 128 + 4 * j);
      g0 = gv.x; g1 = gv.y; g2 = gv.z; g3 = gv.w;
    } else if (rel >= 4) {
      ushort4 gq = *reinterpret_cast<const ushort4*>(P.G + (size_t)i * 128 + 4 * j);
      g0 = bf2f(gq.x); g1 = bf2f(gq.y); g2 = bf2f(gq.z); g3 = bf2f(gq.w);
    }
    float* ap = P.agg[rel] + (size_t)di * 128 + 4 * j;
    unsafeAtomicAdd(ap + 0, alpha * bf2f(ms.x) * g0);
    unsafeAtomicAdd(ap + 1, alpha * bf2f(ms.y) * g1);
    unsafeAtomicAdd(ap + 2, alpha * bf2f(ms.z) * g2);
    unsafeAtomicAdd(ap + 3, alpha * bf2f(ms.w) * g3);
  }
}

// categorical gate table: 2 relations x 50 (a,s) combos x 128
__global__ void gatetab_kernel(const float* at_emb, const float* as_emb,
                               const float* Wcat, const float* bcat, float* gtab, int l) {
  int rel = blockIdx.x / 50, combo = blockIdx.x % 50;
  int a = combo / 5, s2 = combo % 5;
  int d = threadIdx.x;
  const float* Wb = Wcat + (size_t)(l * 2 + rel) * 64 * 128;
  float acc = bcat[(size_t)(l * 2 + rel) * 128 + d];
  const float* ae = at_emb + (size_t)(l * 10 + a) * 32;
  const float* se = as_emb + (size_t)(l * 5 + s2) * 32;
  for (int k = 0; k < 32; ++k) acc += ae[k] * Wb[k * 128 + d];
  for (int k = 0; k < 32; ++k) acc += se[k] * Wb[(32 + k) * 128 + d];
  gtab[(size_t)(rel * 50 + combo) * 128 + d] = 1.f / (1.f + expf(-acc));
}

// LayerNorm(xs + tmp) -> xs, one wave per row
__global__ __launch_bounds__(256) void ln_kernel(float* xs, const float* tmp,
                                                 const float* g_base, const float* b_base) {
  int wid = (blockIdx.x * blockDim.x + threadIdx.x) >> 6;
  int lane = threadIdx.x & 63;
  int nw = (gridDim.x * blockDim.x) >> 6;
  for (int row = wid; row < NTOT; row += nw) {
    int t = row < NC_ ? 0 : (row < NC_ + ND_ ? 1 : 2);
    size_t ro = (size_t)row * 128 + 2 * lane;
    float2 x = *reinterpret_cast<const float2*>(xs + ro);
    float2 tv = *reinterpret_cast<const float2*>(tmp + ro);
    float a = x.x + tv.x, b = x.y + tv.y;
    float s = a + b;
#pragma unroll
    for (int m = 1; m <= 32; m <<= 1) s += __shfl_xor(s, m);
    float mu = s * 0.0078125f;
    float da = a - mu, db = b - mu;
    float v = da * da + db * db;
#pragma unroll
    for (int m = 1; m <= 32; m <<= 1) v += __shfl_xor(v, m);
    float rs = rsqrtf(v * 0.0078125f + 1e-5f);
    float2 gg = *reinterpret_cast<const float2*>(g_base + t * 128 + 2 * lane);
    float2 bb = *reinterpret_cast<const float2*>(b_base + t * 128 + 2 * lane);
    float2 o;
    o.x = da * rs * gg.x + bb.x;
    o.y = db * rs * gg.y + bb.y;
    *reinterpret_cast<float2*>(xs + ro) = o;
  }
}

// out[p] = dot(Y[pair_src[p]], xs1[pair_dst[p]]) — one wave per pair
__global__ __launch_bounds__(256) void pair_kernel(const float* Y, const float* x1,
                                                   const int* ps, const int* pd, float* out) {
  int wid = (blockIdx.x * blockDim.x + threadIdx.x) >> 6;
  int lane = threadIdx.x & 63;
  int nw = (gridDim.x * blockDim.x) >> 6;
  for (int p = wid; p < PP_; p += nw) {
    int ai = ps[p], bi = pd[p];
    float2 y = *reinterpret_cast<const float2*>(Y + (size_t)ai * 128 + 2 * lane);
    float2 x = *reinterpret_cast<const float2*>(x1 + (size_t)bi * 128 + 2 * lane);
    float s = y.x * x.x + y.y * x.y;
#pragma unroll
    for (int m = 1; m <= 32; m <<= 1) s += __shfl_xor(s, m);
    if (lane == 0) out[p] = s;
  }
}

// ws-too-small sentinel: makes the failure mode visible (absmax ~1e6, not max|ref|)
__global__ void fill_kernel(float* out, int n, float v) {
  int i = blockIdx.x * blockDim.x + threadIdx.x;
  if (i < n) out[i] = v;
}

// ---------------- host ----------------
extern "C" void kernel_launch(void* const* d_in, const int* in_sizes, int n_in,
                              void* d_out, int out_size, void* d_ws, size_t ws_size,
                              hipStream_t stream) {
  (void)in_sizes; (void)n_in;
  const float* emb_c = (const float*)d_in[0];
  const float* emb_d = (const float*)d_in[1];
  const float* emb_g = (const float*)d_in[2];
  const float* Wsrc  = (const float*)d_in[3];
  const float* bsrc  = (const float*)d_in[4];
  const float* Wdst  = (const float*)d_in[5];
  const float* bdst  = (const float*)d_in[6];
  const float* attn  = (const float*)d_in[7];
  const float* Wout  = (const float*)d_in[8];
  const float* bout  = (const float*)d_in[9];
  const float* ln_g  = (const float*)d_in[10];
  const float* ln_b  = (const float*)d_in[11];
  const float* at_emb = (const float*)d_in[12];
  const float* as_emb = (const float*)d_in[13];
  const float* Wcat  = (const float*)d_in[14];
  const float* bcat  = (const float*)d_in[15];
  const float* Wc1   = (const float*)d_in[16];
  const float* bc1   = (const float*)d_in[17];
  const float* Wc2   = (const float*)d_in[18];
  const float* bc2   = (const float*)d_in[19];
  const float* W_cd  = (const float*)d_in[20];
  const float* ea4   = (const float*)d_in[21];
  const float* ea5   = (const float*)d_in[22];
  const int* srcs[6] = {(const int*)d_in[23], (const int*)d_in[25], (const int*)d_in[27],
                        (const int*)d_in[29], (const int*)d_in[31], (const int*)d_in[33]};
  const int* dsts[6] = {(const int*)d_in[24], (const int*)d_in[26], (const int*)d_in[28],
                        (const int*)d_in[30], (const int*)d_in[32], (const int*)d_in[34]};
  const int* ea0 = (const int*)d_in[35];
  const int* ea1 = (const int*)d_in[36];
  const int* pair_src = (const int*)d_in[37];
  const int* pair_dst = (const int*)d_in[38];

  static const int ST_[6] = {0, 2, 0, 1, 1, 2};
  static const int DT_[6] = {2, 0, 1, 0, 2, 1};
  static const int NT_[3] = {NC_, ND_, NG_};
  static const int HSOFF[6] = {0, 50000, 80000, 130000, 150000, 170000};   // cum rows of N[ST]
  static const int HDOFF[6] = {0, 30000, 80000, 100000, 150000, 180000};   // cum rows of N[DT]
  const size_t tbase[3] = {0, (size_t)NC_ * 128, (size_t)(NC_ + ND_) * 128};

  // workspace carve (~240.5 MB)
  size_t off = 0;
  auto alloc = [&](size_t bytes) { off = (off + 255) & ~(size_t)255; size_t o = off; off += bytes; return o; };
  size_t o_xs   = alloc((size_t)NTOT * 512);          // f32 node states
  size_t o_agg  = alloc((size_t)NTOT * 512);          // f32 agg; reused as Y at the end
  size_t o_smax = alloc((size_t)6 * 50000 * 16);
  size_t o_ssum = alloc((size_t)6 * 50000 * 16);
  size_t memset_span = (o_ssum + (size_t)6 * 50000 * 16) - o_agg;
  size_t o_hs   = alloc((size_t)200000 * 256);        // bf16 src projections; reused as tmp (f32) after p3
  size_t o_hd   = alloc((size_t)200000 * 256);        // bf16 dst projections; reused as G4 then G5
  size_t o_ebuf = alloc((size_t)6 * EE * 16);
  size_t o_as   = alloc((size_t)200000 * 16);
  size_t o_ad   = alloc((size_t)200000 * 16);
  size_t o_gtab = alloc((size_t)100 * 512);
  if (off > ws_size) {   // loud failure: absmax will read ~1e6
    fill_kernel<<<(PP_ + 255) / 256, 256, 0, stream>>>((float*)d_out, out_size, 1.0e6f);
    return;
  }

  char* ws = (char*)d_ws;
  float* xs = (float*)(ws + o_xs);
  float* agg = (float*)(ws + o_agg);
  unsigned* smax = (unsigned*)(ws + o_smax);
  float* ssum = (float*)(ws + o_ssum);
  unsigned short* hs = (unsigned short*)(ws + o_hs);
  float* tmp = (float*)(ws + o_hs);                   // alias (NTOT*512 == 200000*256 bytes)
  unsigned short* hd = (unsigned short*)(ws + o_hd);
  unsigned short* G = (unsigned short*)(ws + o_hd);   // alias
  float* ebuf = (float*)(ws + o_ebuf);
  float* as_v = (float*)(ws + o_as);
  float* ad_v = (float*)(ws + o_ad);
  float* gtab = (float*)(ws + o_gtab);
  float* Y = agg;                                      // alias

  // xs <- embeddings
  hipMemcpyAsync(xs, emb_c, (size_t)NC_ * 512, hipMemcpyDeviceToDevice, stream);
  hipMemcpyAsync(xs + tbase[1], emb_d, (size_t)ND_ * 512, hipMemcpyDeviceToDevice, stream);
  hipMemcpyAsync(xs + tbase[2], emb_g, (size_t)NG_ * 512, hipMemcpyDeviceToDevice, stream);

  for (int l = 0; l < 2; ++l) {
    hipMemsetAsync(ws + o_agg, 0, memset_span, stream);
    gatetab_kernel<<<100, 128, 0, stream>>>(at_emb, as_emb, Wcat, bcat, gtab, l);

    // 12 projections
    GParams gp{};
    for (int r = 0; r < 6; ++r) {
      int st = ST_[r], dt = DT_[r];
      gp.e[2 * r + 0] = {xs + tbase[st], Wsrc + (size_t)(l * 6 + r) * 16384, bsrc + (size_t)(l * 6 + r) * 128,
                         (void*)(hs + (size_t)HSOFF[r] * 128), nullptr, nullptr, nullptr, NT_[st], 0, 0, 1};
      gp.e[2 * r + 1] = {xs + tbase[dt], Wdst + (size_t)(l * 6 + r) * 16384, bdst + (size_t)(l * 6 + r) * 128,
                         (void*)(hd + (size_t)HDOFF[r] * 128), nullptr, nullptr, nullptr, NT_[dt], 0, 0, 1};
    }
    gemm128<<<dim3(98, 12), 256, 0, stream>>>(gp);

    // per-node attention dots (frees hd)
    ADParams ap{};
    for (int r = 0; r < 6; ++r) {
      ap.h[r] = hs + (size_t)HSOFF[r] * 128;  ap.out[r] = as_v + (size_t)HSOFF[r] * 4;
      ap.M[r] = NT_[ST_[r]];  ap.rel[r] = r;
      ap.h[6 + r] = hd + (size_t)HDOFF[r] * 128;  ap.out[6 + r] = ad_v + (size_t)HDOFF[r] * 4;
      ap.M[6 + r] = NT_[DT_[r]];  ap.rel[6 + r] = r;
    }
    ap.attn = attn + (size_t)l * 6 * 128;
    attdot_kernel<<<dim3(12500, 12), 256, 0, stream>>>(ap);

    // G4 gate -> reuse hd buffer
    GParams g4{};
    g4.e[0] = {nullptr, Wc2 + (size_t)(l * 2 + 0) * 16384, bc2 + (size_t)(l * 2 + 0) * 128, (void*)G,
               ea4, Wc1 + (size_t)(l * 2 + 0) * 256, bc1 + (size_t)(l * 2 + 0) * 128, EE, 2, 1, 1};
    gemm128<<<dim3(391, 1), 256, 0, stream>>>(g4);

    EParams ep{};
    for (int r = 0; r < 6; ++r) {
      ep.hs[r] = hs + (size_t)HSOFF[r] * 128;
      ep.src[r] = srcs[r];
      ep.dst[r] = dsts[r];
      ep.ebuf[r] = ebuf + (size_t)r * EE * 4;
      ep.smax[r] = smax + (size_t)r * 50000 * 4;
      ep.ssum[r] = ssum + (size_t)r * 50000 * 4;
      ep.agg[r] = agg + tbase[DT_[r]];
      ep.as_[r] = as_v + (size_t)HSOFF[r] * 4;
      ep.ad_[r] = ad_v + (size_t)HDOFF[r] * 4;
    }
    ep.ea[0] = ea0; ep.ea[1] = ea1;
    ep.gtab = gtab;
    ep.G = G;

    p1_kernel<<<2048, 256, 0, stream>>>(ep);
    p2_kernel<<<2048, 256, 0, stream>>>(ep);

    ep.relLo = 0; ep.relHi = 4;     // rels 0-4 (rel4 uses G=G4)
    p3_kernel<<<4096, 256, 0, stream>>>(ep);

    // G5 gate -> same buffer
    GParams g5{};
    g5.e[0] = {nullptr, Wc2 + (size_t)(l * 2 + 1) * 16384, bc2 + (size_t)(l * 2 + 1) * 128, (void*)G,
               ea5, Wc1 + (size_t)(l * 2 + 1) * 256, bc1 + (size_t)(l * 2 + 1) * 128, EE, 2, 1, 1};
    gemm128<<<dim3(391, 1), 256, 0, stream>>>(g5);

    ep.relLo = 5; ep.relHi = 5;     // rel5 uses G=G5
    p3_kernel<<<2048, 256, 0, stream>>>(ep);

    // tmp = agg @ Wout + bout (f32 out; tmp aliases hs which is now dead)
    GParams gw{};
    for (int t = 0; t < 3; ++t)
      gw.e[t] = {agg + tbase[t], Wout + (size_t)(l * 3 + t) * 16384, bout + (size_t)(l * 3 + t) * 128,
                 (void*)(tmp + tbase[t]), nullptr, nullptr, nullptr, NT_[t], 0, 0, 0};
    gemm128<<<dim3(98, 3), 256, 0, stream>>>(gw);

    ln_kernel<<<2048, 256, 0, stream>>>(xs, tmp, ln_g + (size_t)l * 384, ln_b + (size_t)l * 384);
  }

  // Y = xs0 @ W_cd (f32 out, no bias; Y aliases agg which is now dead)
  GParams gy{};
  gy.e[0] = {xs, W_cd, nullptr, (void*)Y, nullptr, nullptr, nullptr, NC_, 0, 0, 0};
  gemm128<<<dim3(98, 1), 256, 0, stream>>>(gy);

  pair_kernel<<<2048, 256, 0, stream>>>(Y, xs + tbase[1], pair_src, pair_dst, (float*)d_out);
}

// Round 3
// 2393.051 us; speedup vs baseline: 2.7134x; 2.7134x over previous
//
#include <hip/hip_runtime.h>

typedef short s16x8 __attribute__((ext_vector_type(8)));
typedef float f32x4 __attribute__((ext_vector_type(4)));

#define DEV __device__ __forceinline__

static constexpr int NC_ = 50000, ND_ = 20000, NG_ = 30000;
static constexpr int EE = 200000, PP_ = 200000;
static constexpr int NTOT = NC_ + ND_ + NG_;   // 100000

DEV unsigned short f2bf(float f) {
  unsigned u = __float_as_uint(f);
  u = u + 0x7FFFu + ((u >> 16) & 1u);
  return (unsigned short)(u >> 16);
}
DEV float bf2f(unsigned short h) { return __uint_as_float(((unsigned)h) << 16); }
DEV float sel4(float a, float b, float c, float d, int h) {
  float lo = (h & 1) ? b : a;
  float hi = (h & 1) ? d : c;
  return (h & 2) ? hi : lo;
}

// ---------------- batched 128x128 GEMM (MFMA bf16) ----------------
struct GEntry {
  const float* A; const float* W; const float* bias; void* out;
  const float* ea; const float* Wc1; const float* bc1;
  int M; int amode; int act; int outbf16;
};
struct GParams { GEntry e[12]; };

__global__ __launch_bounds__(256) void gemm128(GParams P) {
  GEntry E = P.e[blockIdx.y];
  const int M = E.M;
  const int chunk = blockIdx.x * 512;
  if (chunk >= M) return;

  __shared__ __align__(16) unsigned short ldsW[128 * 128];
  __shared__ float ldsC1[3 * 128];

  const int tid = threadIdx.x;
  for (int it = tid; it < 16384; it += 256) {
    int k = it >> 7, n = it & 127;
    ldsW[n * 128 + (k ^ ((n & 7) << 3))] = f2bf(E.W[it]);
  }
  if (E.amode == 2 && tid < 128) {
    ldsC1[tid] = E.Wc1[tid];
    ldsC1[128 + tid] = E.Wc1[128 + tid];
    ldsC1[256 + tid] = E.bc1[tid];
  }
  __syncthreads();

  const int w = tid >> 6, lane = tid & 63, g = lane >> 4, c = lane & 15;
  const int colHalf = (w & 1) * 64;
  const int rowHalf = (w >> 1) * 32;

  s16x8 Bf[4][4];
#pragma unroll
  for (int s = 0; s < 4; ++s)
#pragma unroll
    for (int nb = 0; nb < 4; ++nb) {
      int n = colHalf + nb * 16 + c;
      int idx = n * 128 + ((s * 32 + 8 * g) ^ ((n & 7) << 3));
      Bf[s][nb] = *reinterpret_cast<const s16x8*>(&ldsW[idx]);
    }

  for (int itr = 0; itr < 8; ++itr) {
    if (chunk + itr * 64 >= M) break;
    const int rb = chunk + itr * 64 + rowHalf;

    s16x8 Af[2][4];
#pragma unroll
    for (int mt = 0; mt < 2; ++mt) {
      int row = rb + mt * 16 + c;
      int rr = row < M ? row : M - 1;
      if (E.amode == 0) {
        const float* ap = E.A + (size_t)rr * 128;
#pragma unroll
        for (int s = 0; s < 4; ++s) {
          float4 lo = *reinterpret_cast<const float4*>(ap + s * 32 + 8 * g);
          float4 hi = *reinterpret_cast<const float4*>(ap + s * 32 + 8 * g + 4);
          s16x8 a;
          a[0] = (short)f2bf(lo.x); a[1] = (short)f2bf(lo.y);
          a[2] = (short)f2bf(lo.z); a[3] = (short)f2bf(lo.w);
          a[4] = (short)f2bf(hi.x); a[5] = (short)f2bf(hi.y);
          a[6] = (short)f2bf(hi.z); a[7] = (short)f2bf(hi.w);
          Af[mt][s] = a;
        }
      } else {
        float e0 = E.ea[(size_t)rr * 2], e1 = E.ea[(size_t)rr * 2 + 1];
#pragma unroll
        for (int s = 0; s < 4; ++s) {
          s16x8 a;
#pragma unroll
          for (int i = 0; i < 8; ++i) {
            int k = s * 32 + 8 * g + i;
            float h = e0 * ldsC1[k] + e1 * ldsC1[128 + k] + ldsC1[256 + k];
            h = 0.5f * h * (1.f + erff(h * 0.70710678118f));
            a[i] = (short)f2bf(h);
          }
          Af[mt][s] = a;
        }
      }
    }

    f32x4 acc[2][4];
#pragma unroll
    for (int mt = 0; mt < 2; ++mt)
#pragma unroll
      for (int nb = 0; nb < 4; ++nb) { acc[mt][nb][0] = 0.f; acc[mt][nb][1] = 0.f; acc[mt][nb][2] = 0.f; acc[mt][nb][3] = 0.f; }

#pragma unroll
    for (int mt = 0; mt < 2; ++mt)
#pragma unroll
      for (int s = 0; s < 4; ++s)
#pragma unroll
        for (int nb = 0; nb < 4; ++nb)
          acc[mt][nb] = __builtin_amdgcn_mfma_f32_16x16x32_bf16(Af[mt][s], Bf[s][nb], acc[mt][nb], 0, 0, 0);

#pragma unroll
    for (int mt = 0; mt < 2; ++mt)
#pragma unroll
      for (int nb = 0; nb < 4; ++nb) {
        int col = colHalf + nb * 16 + c;
        float bv = E.bias ? E.bias[col] : 0.f;
#pragma unroll
        for (int jj = 0; jj < 4; ++jj) {
          int row = rb + mt * 16 + 4 * g + jj;
          if (row < M) {
            float v = acc[mt][nb][jj] + bv;
            if (E.act == 1) v = 1.f / (1.f + expf(-v));
            if (E.outbf16) ((unsigned short*)E.out)[(size_t)row * 128 + col] = f2bf(v);
            else ((float*)E.out)[(size_t)row * 128 + col] = v;
          }
        }
      }
  }
}

// ---------------- per-node attention dots ----------------
struct ADParams {
  const unsigned short* h[12]; float* out[12]; int M[12]; int rel[12];
  const float* attn;
};
__global__ __launch_bounds__(256) void attdot_kernel(ADParams P) {
  int s = blockIdx.y;
  int row = blockIdx.x * 4 + (threadIdx.x >> 6);
  int lane = threadIdx.x & 63;
  if (row >= P.M[s]) return;
  const unsigned short* hp = P.h[s] + (size_t)row * 128 + lane * 2;
  ushort2 u = *reinterpret_cast<const ushort2*>(hp);
  const float* at = P.attn + P.rel[s] * 128 + lane * 2;
  float p = bf2f(u.x) * at[0] + bf2f(u.y) * at[1];
  p += __shfl_xor(p, 1);
  p += __shfl_xor(p, 2);
  p += __shfl_xor(p, 4);
  p += __shfl_xor(p, 8);
  if ((lane & 15) == 0) P.out[s][(size_t)row * 4 + (lane >> 4)] = p;
}

// ---------------- CSR build (once per call; edges static) ----------------
struct CSRParams {
  const int* dst[6];
  int* cnt;      // 6 x 50000
  int* rowp;     // 6 x 50001
  int* cursor;   // 6 x 50000
  int* col;      // 6 x EE
  int ndst[6];
};

__global__ __launch_bounds__(256) void hist_kernel(CSRParams P) {
  int gt = blockIdx.x * blockDim.x + threadIdx.x;
  int n = gridDim.x * blockDim.x;
  for (int idx = gt; idx < 6 * EE; idx += n) {
    int rel = idx / EE, i = idx - rel * EE;
    atomicAdd(&P.cnt[rel * 50000 + P.dst[rel][i]], 1);
  }
}

__global__ __launch_bounds__(1024) void scan_kernel(CSRParams P) {
  int rel = blockIdx.x;
  int n = P.ndst[rel];
  const int* c = P.cnt + rel * 50000;
  int* rp = P.rowp + rel * 50001;
  int* cur = P.cursor + rel * 50000;
  __shared__ int part[1024];
  int tid = threadIdx.x;
  int chunk = (n + 1023) / 1024;
  int lo = tid * chunk, hi = lo + chunk;
  if (hi > n) hi = n;
  int s = 0;
  for (int j = lo; j < hi; ++j) s += c[j];
  part[tid] = s;
  __syncthreads();
  if (tid == 0) {
    int acc = 0;
    for (int k = 0; k < 1024; ++k) { int v = part[k]; part[k] = acc; acc += v; }
    rp[n] = acc;
  }
  __syncthreads();
  int acc = part[tid];
  for (int j = lo; j < hi; ++j) { rp[j] = acc; cur[j] = acc; acc += c[j]; }
}

__global__ __launch_bounds__(256) void scatter_kernel(CSRParams P) {
  int gt = blockIdx.x * blockDim.x + threadIdx.x;
  int n = gridDim.x * blockDim.x;
  for (int idx = gt; idx < 6 * EE; idx += n) {
    int rel = idx / EE, i = idx - rel * EE;
    int d = P.dst[rel][i];
    int pos = atomicAdd(&P.cursor[rel * 50000 + d], 1);
    P.col[rel * EE + pos] = i;
  }
}

// ---------------- fused per-dst aggregation (gather, no atomics) ----------------
struct AggRel {
  const int* src; const int* col; const int* rowp;
  const float* asv; const float* adv;
  const unsigned short* hs;
  const int* ea;        // for gtype 1/2
  int gtype;            // 0 none, 1 gtab rel0, 2 gtab rel1, 3 G buffer
};
struct AggGroup { int n; float* agg; AggRel rel[2]; };
struct AggParams {
  AggGroup grp[2]; int ngrp;
  const float* gtab; const unsigned short* G;
};

__global__ __launch_bounds__(256) void agg_kernel(AggParams P) {
  int wid = (blockIdx.x * 256 + threadIdx.x) >> 6;
  int lane = threadIdx.x & 63;
  int h = lane >> 4;
  int gi = 0, node = wid;
  if (node >= P.grp[0].n) {
    node -= P.grp[0].n; gi = 1;
    if (gi >= P.ngrp || node >= P.grp[1].n) return;
  }
  const AggGroup& G = P.grp[gi];
  float a0 = 0.f, a1 = 0.f;

  for (int rs = 0; rs < 2; ++rs) {
    const AggRel& R = G.rel[rs];
    int rp = R.rowp[node], re = R.rowp[node + 1];
    if (rp == re) continue;
    float4 ad4 = *reinterpret_cast<const float4*>(R.adv + (size_t)node * 4);

    float m0 = -1e30f, m1 = -1e30f, m2 = -1e30f, m3 = -1e30f;
    float s0 = 0.f, s1 = 0.f, s2 = 0.f, s3 = 0.f;
    int deg = re - rp;

    if (deg <= 64) {
      float e0 = -1e30f, e1 = -1e30f, e2 = -1e30f, e3 = -1e30f;
      int k = rp + lane;
      bool ok = k < re;
      if (ok) {
        int i = R.col[k];
        int si = R.src[i];
        float4 s4 = *reinterpret_cast<const float4*>(R.asv + (size_t)si * 4);
        e0 = s4.x + ad4.x; e0 = e0 > 0.f ? e0 : 0.2f * e0;
        e1 = s4.y + ad4.y; e1 = e1 > 0.f ? e1 : 0.2f * e1;
        e2 = s4.z + ad4.z; e2 = e2 > 0.f ? e2 : 0.2f * e2;
        e3 = s4.w + ad4.w; e3 = e3 > 0.f ? e3 : 0.2f * e3;
      }
      m0 = e0; m1 = e1; m2 = e2; m3 = e3;
#pragma unroll
      for (int d = 1; d < 64; d <<= 1) {
        m0 = fmaxf(m0, __shfl_xor(m0, d));
        m1 = fmaxf(m1, __shfl_xor(m1, d));
        m2 = fmaxf(m2, __shfl_xor(m2, d));
        m3 = fmaxf(m3, __shfl_xor(m3, d));
      }
      s0 = ok ? __expf(e0 - m0) : 0.f;
      s1 = ok ? __expf(e1 - m1) : 0.f;
      s2 = ok ? __expf(e2 - m2) : 0.f;
      s3 = ok ? __expf(e3 - m3) : 0.f;
#pragma unroll
      for (int d = 1; d < 64; d <<= 1) {
        s0 += __shfl_xor(s0, d);
        s1 += __shfl_xor(s1, d);
        s2 += __shfl_xor(s2, d);
        s3 += __shfl_xor(s3, d);
      }
    } else {
      for (int b = rp; b < re; b += 64) {
        int k = b + lane;
        if (k < re) {
          int i = R.col[k];
          int si = R.src[i];
          float4 s4 = *reinterpret_cast<const float4*>(R.asv + (size_t)si * 4);
          float e0 = s4.x + ad4.x; e0 = e0 > 0.f ? e0 : 0.2f * e0;
          float e1 = s4.y + ad4.y; e1 = e1 > 0.f ? e1 : 0.2f * e1;
          float e2 = s4.z + ad4.z; e2 = e2 > 0.f ? e2 : 0.2f * e2;
          float e3 = s4.w + ad4.w; e3 = e3 > 0.f ? e3 : 0.2f * e3;
          m0 = fmaxf(m0, e0); m1 = fmaxf(m1, e1); m2 = fmaxf(m2, e2); m3 = fmaxf(m3, e3);
        }
      }
#pragma unroll
      for (int d = 1; d < 64; d <<= 1) {
        m0 = fmaxf(m0, __shfl_xor(m0, d));
        m1 = fmaxf(m1, __shfl_xor(m1, d));
        m2 = fmaxf(m2, __shfl_xor(m2, d));
        m3 = fmaxf(m3, __shfl_xor(m3, d));
      }
      for (int b = rp; b < re; b += 64) {
        int k = b + lane;
        if (k < re) {
          int i = R.col[k];
          int si = R.src[i];
          float4 s4 = *reinterpret_cast<const float4*>(R.asv + (size_t)si * 4);
          float e0 = s4.x + ad4.x; e0 = e0 > 0.f ? e0 : 0.2f * e0;
          float e1 = s4.y + ad4.y; e1 = e1 > 0.f ? e1 : 0.2f * e1;
          float e2 = s4.z + ad4.z; e2 = e2 > 0.f ? e2 : 0.2f * e2;
          float e3 = s4.w + ad4.w; e3 = e3 > 0.f ? e3 : 0.2f * e3;
          s0 += __expf(e0 - m0); s1 += __expf(e1 - m1); s2 += __expf(e2 - m2); s3 += __expf(e3 - m3);
        }
      }
#pragma unroll
      for (int d = 1; d < 64; d <<= 1) {
        s0 += __shfl_xor(s0, d);
        s1 += __shfl_xor(s1, d);
        s2 += __shfl_xor(s2, d);
        s3 += __shfl_xor(s3, d);
      }
    }

    // per-lane head constants (static select — no scratch)
    float mh = sel4(m0, m1, m2, m3, h);
    float sh = sel4(s0, s1, s2, s3, h);
    float invh = 1.f / (sh + 1e-16f);
    float adh = sel4(ad4.x, ad4.y, ad4.z, ad4.w, h);

    for (int k = rp; k < re; ++k) {
      int i = R.col[k];                 // broadcast
      int si = R.src[i];                // broadcast
      float4 s4 = *reinterpret_cast<const float4*>(R.asv + (size_t)si * 4);
      float eh = sel4(s4.x, s4.y, s4.z, s4.w, h) + adh;
      eh = eh > 0.f ? eh : 0.2f * eh;
      float alpha = __expf(eh - mh) * invh;
      ushort2 ms = *reinterpret_cast<const ushort2*>(R.hs + (size_t)si * 128 + 2 * lane);
      float g0 = 1.f, g1 = 1.f;
      if (R.gtype == 1 || R.gtype == 2) {
        int a = R.ea[(size_t)i * 2], s2i = R.ea[(size_t)i * 2 + 1];
        const float* gp = P.gtab + (size_t)((R.gtype - 1) * 50 + a * 5 + s2i) * 128 + 2 * lane;
        g0 = gp[0]; g1 = gp[1];
      } else if (R.gtype == 3) {
        ushort2 gq = *reinterpret_cast<const ushort2*>(P.G + (size_t)i * 128 + 2 * lane);
        g0 = bf2f(gq.x); g1 = bf2f(gq.y);
      }
      a0 += alpha * bf2f(ms.x) * g0;
      a1 += alpha * bf2f(ms.y) * g1;
    }
  }
  float2 o; o.x = a0; o.y = a1;
  *reinterpret_cast<float2*>(G.agg + (size_t)node * 128 + 2 * lane) = o;
}

// categorical gate table
__global__ void gatetab_kernel(const float* at_emb, const float* as_emb,
                               const float* Wcat, const float* bcat, float* gtab, int l) {
  int rel = blockIdx.x / 50, combo = blockIdx.x % 50;
  int a = combo / 5, s2 = combo % 5;
  int d = threadIdx.x;
  const float* Wb = Wcat + (size_t)(l * 2 + rel) * 64 * 128;
  float acc = bcat[(size_t)(l * 2 + rel) * 128 + d];
  const float* ae = at_emb + (size_t)(l * 10 + a) * 32;
  const float* se = as_emb + (size_t)(l * 5 + s2) * 32;
  for (int k = 0; k < 32; ++k) acc += ae[k] * Wb[k * 128 + d];
  for (int k = 0; k < 32; ++k) acc += se[k] * Wb[(32 + k) * 128 + d];
  gtab[(size_t)(rel * 50 + combo) * 128 + d] = 1.f / (1.f + expf(-acc));
}

// LayerNorm(xs + tmp) -> xs
__global__ __launch_bounds__(256) void ln_kernel(float* xs, const float* tmp,
                                                 const float* g_base, const float* b_base) {
  int wid = (blockIdx.x * blockDim.x + threadIdx.x) >> 6;
  int lane = threadIdx.x & 63;
  int nw = (gridDim.x * blockDim.x) >> 6;
  for (int row = wid; row < NTOT; row += nw) {
    int t = row < NC_ ? 0 : (row < NC_ + ND_ ? 1 : 2);
    size_t ro = (size_t)row * 128 + 2 * lane;
    float2 x = *reinterpret_cast<const float2*>(xs + ro);
    float2 tv = *reinterpret_cast<const float2*>(tmp + ro);
    float a = x.x + tv.x, b = x.y + tv.y;
    float s = a + b;
#pragma unroll
    for (int m = 1; m <= 32; m <<= 1) s += __shfl_xor(s, m);
    float mu = s * 0.0078125f;
    float da = a - mu, db = b - mu;
    float v = da * da + db * db;
#pragma unroll
    for (int m = 1; m <= 32; m <<= 1) v += __shfl_xor(v, m);
    float rs = rsqrtf(v * 0.0078125f + 1e-5f);
    float2 gg = *reinterpret_cast<const float2*>(g_base + t * 128 + 2 * lane);
    float2 bb = *reinterpret_cast<const float2*>(b_base + t * 128 + 2 * lane);
    float2 o;
    o.x = da * rs * gg.x + bb.x;
    o.y = db * rs * gg.y + bb.y;
    *reinterpret_cast<float2*>(xs + ro) = o;
  }
}

__global__ __launch_bounds__(256) void pair_kernel(const float* Y, const float* x1,
                                                   const int* ps, const int* pd, float* out) {
  int wid = (blockIdx.x * blockDim.x + threadIdx.x) >> 6;
  int lane = threadIdx.x & 63;
  int nw = (gridDim.x * blockDim.x) >> 6;
  for (int p = wid; p < PP_; p += nw) {
    int ai = ps[p], bi = pd[p];
    float2 y = *reinterpret_cast<const float2*>(Y + (size_t)ai * 128 + 2 * lane);
    float2 x = *reinterpret_cast<const float2*>(x1 + (size_t)bi * 128 + 2 * lane);
    float s = y.x * x.x + y.y * x.y;
#pragma unroll
    for (int m = 1; m <= 32; m <<= 1) s += __shfl_xor(s, m);
    if (lane == 0) out[p] = s;
  }
}

__global__ void fill_kernel(float* out, int n, float v) {
  int i = blockIdx.x * blockDim.x + threadIdx.x;
  if (i < n) out[i] = v;
}

// ---------------- host ----------------
extern "C" void kernel_launch(void* const* d_in, const int* in_sizes, int n_in,
                              void* d_out, int out_size, void* d_ws, size_t ws_size,
                              hipStream_t stream) {
  (void)in_sizes; (void)n_in;
  const float* emb_c = (const float*)d_in[0];
  const float* emb_d = (const float*)d_in[1];
  const float* emb_g = (const float*)d_in[2];
  const float* Wsrc  = (const float*)d_in[3];
  const float* bsrc  = (const float*)d_in[4];
  const float* Wdst  = (const float*)d_in[5];
  const float* bdst  = (const float*)d_in[6];
  const float* attn  = (const float*)d_in[7];
  const float* Wout  = (const float*)d_in[8];
  const float* bout  = (const float*)d_in[9];
  const float* ln_g  = (const float*)d_in[10];
  const float* ln_b  = (const float*)d_in[11];
  const float* at_emb = (const float*)d_in[12];
  const float* as_emb = (const float*)d_in[13];
  const float* Wcat  = (const float*)d_in[14];
  const float* bcat  = (const float*)d_in[15];
  const float* Wc1   = (const float*)d_in[16];
  const float* bc1   = (const float*)d_in[17];
  const float* Wc2   = (const float*)d_in[18];
  const float* bc2   = (const float*)d_in[19];
  const float* W_cd  = (const float*)d_in[20];
  const float* ea4   = (const float*)d_in[21];
  const float* ea5   = (const float*)d_in[22];
  const int* srcs[6] = {(const int*)d_in[23], (const int*)d_in[25], (const int*)d_in[27],
                        (const int*)d_in[29], (const int*)d_in[31], (const int*)d_in[33]};
  const int* dsts[6] = {(const int*)d_in[24], (const int*)d_in[26], (const int*)d_in[28],
                        (const int*)d_in[30], (const int*)d_in[32], (const int*)d_in[34]};
  const int* ea0 = (const int*)d_in[35];
  const int* ea1 = (const int*)d_in[36];
  const int* pair_src = (const int*)d_in[37];
  const int* pair_dst = (const int*)d_in[38];

  static const int ST_[6] = {0, 2, 0, 1, 1, 2};
  static const int DT_[6] = {2, 0, 1, 0, 2, 1};
  static const int NT_[3] = {NC_, ND_, NG_};
  static const int HSOFF[6] = {0, 50000, 80000, 130000, 150000, 170000};
  static const int HDOFF[6] = {0, 30000, 80000, 100000, 150000, 180000};
  const size_t tbase[3] = {0, (size_t)NC_ * 128, (size_t)(NC_ + ND_) * 128};

  // workspace carve (~216 MB)
  size_t off = 0;
  auto alloc = [&](size_t bytes) { off = (off + 255) & ~(size_t)255; size_t o = off; off += bytes; return o; };
  size_t o_xs   = alloc((size_t)NTOT * 512);
  size_t o_agg  = alloc((size_t)NTOT * 512);          // reused as Y
  size_t o_hs   = alloc((size_t)200000 * 256);        // bf16; reused as tmp (f32) after agg
  size_t o_hd   = alloc((size_t)200000 * 256);        // bf16; reused as G (G4 then G5)
  size_t o_as   = alloc((size_t)200000 * 16);
  size_t o_ad   = alloc((size_t)200000 * 16);
  size_t o_gtab = alloc((size_t)100 * 512);
  size_t o_cnt  = alloc((size_t)6 * 50000 * 4);
  size_t o_rowp = alloc((size_t)6 * 50001 * 4);
  size_t o_cur  = alloc((size_t)6 * 50000 * 4);
  size_t o_col  = alloc((size_t)6 * EE * 4);
  if (off > ws_size) {
    fill_kernel<<<(PP_ + 255) / 256, 256, 0, stream>>>((float*)d_out, out_size, 1.0e6f);
    return;
  }

  char* ws = (char*)d_ws;
  float* xs = (float*)(ws + o_xs);
  float* agg = (float*)(ws + o_agg);
  unsigned short* hs = (unsigned short*)(ws + o_hs);
  float* tmp = (float*)(ws + o_hs);
  unsigned short* hd = (unsigned short*)(ws + o_hd);
  unsigned short* G = (unsigned short*)(ws + o_hd);
  float* as_v = (float*)(ws + o_as);
  float* ad_v = (float*)(ws + o_ad);
  float* gtab = (float*)(ws + o_gtab);
  int* cnt = (int*)(ws + o_cnt);
  int* rowp = (int*)(ws + o_rowp);
  int* cursor = (int*)(ws + o_cur);
  int* col = (int*)(ws + o_col);
  float* Y = agg;

  hipMemcpyAsync(xs, emb_c, (size_t)NC_ * 512, hipMemcpyDeviceToDevice, stream);
  hipMemcpyAsync(xs + tbase[1], emb_d, (size_t)ND_ * 512, hipMemcpyDeviceToDevice, stream);
  hipMemcpyAsync(xs + tbase[2], emb_g, (size_t)NG_ * 512, hipMemcpyDeviceToDevice, stream);

  // ---- CSR build (once per call) ----
  hipMemsetAsync(cnt, 0, (size_t)6 * 50000 * 4, stream);
  CSRParams cp{};
  for (int r = 0; r < 6; ++r) { cp.dst[r] = dsts[r]; cp.ndst[r] = NT_[DT_[r]]; }
  cp.cnt = cnt; cp.rowp = rowp; cp.cursor = cursor; cp.col = col;
  hist_kernel<<<2048, 256, 0, stream>>>(cp);
  scan_kernel<<<6, 1024, 0, stream>>>(cp);
  scatter_kernel<<<2048, 256, 0, stream>>>(cp);

  for (int l = 0; l < 2; ++l) {
    gatetab_kernel<<<100, 128, 0, stream>>>(at_emb, as_emb, Wcat, bcat, gtab, l);

    GParams gp{};
    for (int r = 0; r < 6; ++r) {
      int st = ST_[r], dt = DT_[r];
      gp.e[2 * r + 0] = {xs + tbase[st], Wsrc + (size_t)(l * 6 + r) * 16384, bsrc + (size_t)(l * 6 + r) * 128,
                         (void*)(hs + (size_t)HSOFF[r] * 128), nullptr, nullptr, nullptr, NT_[st], 0, 0, 1};
      gp.e[2 * r + 1] = {xs + tbase[dt], Wdst + (size_t)(l * 6 + r) * 16384, bdst + (size_t)(l * 6 + r) * 128,
                         (void*)(hd + (size_t)HDOFF[r] * 128), nullptr, nullptr, nullptr, NT_[dt], 0, 0, 1};
    }
    gemm128<<<dim3(98, 12), 256, 0, stream>>>(gp);

    ADParams ap{};
    for (int r = 0; r < 6; ++r) {
      ap.h[r] = hs + (size_t)HSOFF[r] * 128;  ap.out[r] = as_v + (size_t)HSOFF[r] * 4;
      ap.M[r] = NT_[ST_[r]];  ap.rel[r] = r;
      ap.h[6 + r] = hd + (size_t)HDOFF[r] * 128;  ap.out[6 + r] = ad_v + (size_t)HDOFF[r] * 4;
      ap.M[6 + r] = NT_[DT_[r]];  ap.rel[6 + r] = r;
    }
    ap.attn = attn + (size_t)l * 6 * 128;
    attdot_kernel<<<dim3(12500, 12), 256, 0, stream>>>(ap);   // frees hd

    // G4 gate (reuses hd)
    GParams g4{};
    g4.e[0] = {nullptr, Wc2 + (size_t)(l * 2 + 0) * 16384, bc2 + (size_t)(l * 2 + 0) * 128, (void*)G,
               ea4, Wc1 + (size_t)(l * 2 + 0) * 256, bc1 + (size_t)(l * 2 + 0) * 128, EE, 2, 1, 1};
    gemm128<<<dim3(391, 1), 256, 0, stream>>>(g4);

    auto mkrel = [&](int r) {
      AggRel R;
      R.src = srcs[r]; R.col = col + (size_t)r * EE; R.rowp = rowp + (size_t)r * 50001;
      R.asv = as_v + (size_t)HSOFF[r] * 4; R.adv = ad_v + (size_t)HDOFF[r] * 4;
      R.hs = hs + (size_t)HSOFF[r] * 128;
      R.ea = (r == 0) ? ea0 : (r == 1) ? ea1 : nullptr;
      R.gtype = (r == 0) ? 1 : (r == 1) ? 2 : (r >= 4) ? 3 : 0;
      return R;
    };

    // agg A: dst type 2 (rels 0,4 — needs G4) and dst type 0 (rels 1,3)
    AggParams pa{};
    pa.grp[0].n = NG_; pa.grp[0].agg = agg + tbase[2];
    pa.grp[0].rel[0] = mkrel(0); pa.grp[0].rel[1] = mkrel(4);
    pa.grp[1].n = NC_; pa.grp[1].agg = agg + tbase[0];
    pa.grp[1].rel[0] = mkrel(1); pa.grp[1].rel[1] = mkrel(3);
    pa.ngrp = 2; pa.gtab = gtab; pa.G = G;
    agg_kernel<<<(NG_ + NC_ + 3) / 4, 256, 0, stream>>>(pa);

    // G5 gate (same buffer)
    GParams g5{};
    g5.e[0] = {nullptr, Wc2 + (size_t)(l * 2 + 1) * 16384, bc2 + (size_t)(l * 2 + 1) * 128, (void*)G,
               ea5, Wc1 + (size_t)(l * 2 + 1) * 256, bc1 + (size_t)(l * 2 + 1) * 128, EE, 2, 1, 1};
    gemm128<<<dim3(391, 1), 256, 0, stream>>>(g5);

    // agg B: dst type 1 (rels 2,5 — needs G5)
    AggParams pb{};
    pb.grp[0].n = ND_; pb.grp[0].agg = agg + tbase[1];
    pb.grp[0].rel[0] = mkrel(2); pb.grp[0].rel[1] = mkrel(5);
    pb.grp[1].n = 0; pb.grp[1].agg = nullptr;
    pb.grp[1].rel[0] = mkrel(2); pb.grp[1].rel[1] = mkrel(5);
    pb.ngrp = 1; pb.gtab = gtab; pb.G = G;
    agg_kernel<<<(ND_ + 3) / 4, 256, 0, stream>>>(pb);

    // tmp = agg @ Wout + bout (tmp aliases hs, dead after agg)
    GParams gw{};
    for (int t = 0; t < 3; ++t)
      gw.e[t] = {agg + tbase[t], Wout + (size_t)(l * 3 + t) * 16384, bout + (size_t)(l * 3 + t) * 128,
                 (void*)(tmp + tbase[t]), nullptr, nullptr, nullptr, NT_[t], 0, 0, 0};
    gemm128<<<dim3(98, 3), 256, 0, stream>>>(gw);

    ln_kernel<<<2048, 256, 0, stream>>>(xs, tmp, ln_g + (size_t)l * 384, ln_b + (size_t)l * 384);
  }

  // Y = xs0 @ W_cd (Y aliases agg, dead now)
  GParams gy{};
  gy.e[0] = {xs, W_cd, nullptr, (void*)Y, nullptr, nullptr, nullptr, NC_, 0, 0, 0};
  gemm128<<<dim3(98, 1), 256, 0, stream>>>(gy);

  pair_kernel<<<2048, 256, 0, stream>>>(Y, xs + tbase[1], pair_src, pair_dst, (float*)d_out);
}

// Round 4
// 1908.370 us; speedup vs baseline: 3.4025x; 1.2540x over previous
//
#include <hip/hip_runtime.h>

typedef short s16x8 __attribute__((ext_vector_type(8)));
typedef float f32x4 __attribute__((ext_vector_type(4)));

#define DEV __device__ __forceinline__

static constexpr int NC_ = 50000, ND_ = 20000, NG_ = 30000;
static constexpr int EE = 200000, PP_ = 200000;
static constexpr int NTOT = NC_ + ND_ + NG_;   // 100000

DEV unsigned short f2bf(float f) {
  unsigned u = __float_as_uint(f);
  u = u + 0x7FFFu + ((u >> 16) & 1u);
  return (unsigned short)(u >> 16);
}
DEV float bf2f(unsigned short h) { return __uint_as_float(((unsigned)h) << 16); }
DEV float sel4(float a, float b, float c, float d, int h) {
  float lo = (h & 1) ? b : a;
  float hi = (h & 1) ? d : c;
  return (h & 2) ? hi : lo;
}

// ---------------- batched 128x128 GEMM (MFMA bf16, bf16 A) ----------------
// amode 0: A = bf16 global rows.  amode 2: A[row,k] = gelu(ea[row,0]*Wc1[0,k]+ea[row,1]*Wc1[1,k]+bc1[k])
struct GEntry {
  const unsigned short* A; const float* W; const float* bias; void* out;
  const float* ea; const float* Wc1; const float* bc1;
  int M; int amode; int act; int outbf16;
};
struct GParams { GEntry e[8]; };

__global__ __launch_bounds__(256) void gemm128(GParams P) {
  GEntry E = P.e[blockIdx.y];
  const int M = E.M;
  const int chunk = blockIdx.x * 512;
  if (chunk >= M) return;

  __shared__ __align__(16) unsigned short ldsW[128 * 128];
  __shared__ float ldsC1[3 * 128];

  const int tid = threadIdx.x;
  for (int it = tid; it < 16384; it += 256) {
    int k = it >> 7, n = it & 127;
    ldsW[n * 128 + (k ^ ((n & 7) << 3))] = f2bf(E.W[it]);
  }
  if (E.amode == 2 && tid < 128) {
    ldsC1[tid] = E.Wc1[tid];
    ldsC1[128 + tid] = E.Wc1[128 + tid];
    ldsC1[256 + tid] = E.bc1[tid];
  }
  __syncthreads();

  const int w = tid >> 6, lane = tid & 63, g = lane >> 4, c = lane & 15;
  const int colHalf = (w & 1) * 64;
  const int rowHalf = (w >> 1) * 32;

  s16x8 Bf[4][4];
#pragma unroll
  for (int s = 0; s < 4; ++s)
#pragma unroll
    for (int nb = 0; nb < 4; ++nb) {
      int n = colHalf + nb * 16 + c;
      int idx = n * 128 + ((s * 32 + 8 * g) ^ ((n & 7) << 3));
      Bf[s][nb] = *reinterpret_cast<const s16x8*>(&ldsW[idx]);
    }

  for (int itr = 0; itr < 8; ++itr) {
    if (chunk + itr * 64 >= M) break;
    const int rb = chunk + itr * 64 + rowHalf;

    s16x8 Af[2][4];
#pragma unroll
    for (int mt = 0; mt < 2; ++mt) {
      int row = rb + mt * 16 + c;
      int rr = row < M ? row : M - 1;
      if (E.amode == 0) {
        const unsigned short* ap = E.A + (size_t)rr * 128;
#pragma unroll
        for (int s = 0; s < 4; ++s)
          Af[mt][s] = *reinterpret_cast<const s16x8*>(ap + s * 32 + 8 * g);
      } else {
        float e0 = E.ea[(size_t)rr * 2], e1 = E.ea[(size_t)rr * 2 + 1];
#pragma unroll
        for (int s = 0; s < 4; ++s) {
          s16x8 a;
#pragma unroll
          for (int i = 0; i < 8; ++i) {
            int k = s * 32 + 8 * g + i;
            float h = e0 * ldsC1[k] + e1 * ldsC1[128 + k] + ldsC1[256 + k];
            h = 0.5f * h * (1.f + erff(h * 0.70710678118f));
            a[i] = (short)f2bf(h);
          }
          Af[mt][s] = a;
        }
      }
    }

    f32x4 acc[2][4];
#pragma unroll
    for (int mt = 0; mt < 2; ++mt)
#pragma unroll
      for (int nb = 0; nb < 4; ++nb) { acc[mt][nb][0] = 0.f; acc[mt][nb][1] = 0.f; acc[mt][nb][2] = 0.f; acc[mt][nb][3] = 0.f; }

#pragma unroll
    for (int mt = 0; mt < 2; ++mt)
#pragma unroll
      for (int s = 0; s < 4; ++s)
#pragma unroll
        for (int nb = 0; nb < 4; ++nb)
          acc[mt][nb] = __builtin_amdgcn_mfma_f32_16x16x32_bf16(Af[mt][s], Bf[s][nb], acc[mt][nb], 0, 0, 0);

#pragma unroll
    for (int mt = 0; mt < 2; ++mt)
#pragma unroll
      for (int nb = 0; nb < 4; ++nb) {
        int col = colHalf + nb * 16 + c;
        float bv = E.bias ? E.bias[col] : 0.f;
#pragma unroll
        for (int jj = 0; jj < 4; ++jj) {
          int row = rb + mt * 16 + 4 * g + jj;
          if (row < M) {
            float v = acc[mt][nb][jj] + bv;
            if (E.act == 1) v = 1.f / (1.f + expf(-v));
            if (E.outbf16) ((unsigned short*)E.out)[(size_t)row * 128 + col] = f2bf(v);
            else ((float*)E.out)[(size_t)row * 128 + col] = v;
          }
        }
      }
  }
}

// ---------------- folded attention weights: wv[t][128][16] = Wx@attn per (type, vec) ----------------
// per type t: cols 0-3 = src rel A, 4-7 = src rel B, 8-11 = dst rel A, 12-15 = dst rel B
__global__ void wvbuild_kernel(const float* Wsrc, const float* Wdst, const float* bsrc, const float* bdst,
                               const float* attn, unsigned short* wv, float* bw, int l) {
  static const int RELT[3][4] = {{0, 2, 1, 3}, {3, 4, 2, 5}, {1, 5, 0, 4}};
  int t = blockIdx.x >> 4, col = blockIdx.x & 15;
  int b = col >> 2, h = col & 3;
  int r = RELT[t][b];
  bool isSrc = b < 2;
  const float* W = (isSrc ? Wsrc : Wdst) + (size_t)(l * 6 + r) * 16384;
  const float* bias = (isSrc ? bsrc : bdst) + (size_t)(l * 6 + r) * 128;
  const float* at = attn + (size_t)(l * 6 + r) * 128 + h * 32;
  int k = threadIdx.x;
  float acc = 0.f;
  for (int dh = 0; dh < 32; ++dh) acc += W[k * 128 + h * 32 + dh] * at[dh];
  wv[((size_t)t * 128 + k) * 16 + col] = f2bf(acc);
  if (k == 0) {
    float bacc = 0.f;
    for (int dh = 0; dh < 32; ++dh) bacc += bias[h * 32 + dh] * at[dh];
    bw[t * 16 + col] = bacc;
  }
}

// av16[row][16] = xs_bf[row] @ wv[type(row)] + bw  (MFMA 16x16x32, wave per 16 rows)
__global__ __launch_bounds__(256) void advec_kernel(const unsigned short* xs_bf,
                                                    const unsigned short* wv, const float* bw, float* av16) {
  int rb0 = blockIdx.x * 64 + (threadIdx.x >> 6) * 16;
  if (rb0 >= NTOT) return;
  int lane = threadIdx.x & 63, g = lane >> 4, c = lane & 15;
  int t = rb0 >= (NC_ + ND_) ? 2 : (rb0 >= NC_ ? 1 : 0);
  const unsigned short* wvt = wv + (size_t)t * 2048;
  s16x8 Bf[4];
#pragma unroll
  for (int s = 0; s < 4; ++s) {
    s16x8 bfr;
#pragma unroll
    for (int i = 0; i < 8; ++i) bfr[i] = (short)wvt[(s * 32 + 8 * g + i) * 16 + c];
    Bf[s] = bfr;
  }
  f32x4 acc; acc[0] = 0.f; acc[1] = 0.f; acc[2] = 0.f; acc[3] = 0.f;
  const unsigned short* ap = xs_bf + (size_t)(rb0 + c) * 128;
#pragma unroll
  for (int s = 0; s < 4; ++s) {
    s16x8 a = *reinterpret_cast<const s16x8*>(ap + s * 32 + 8 * g);
    acc = __builtin_amdgcn_mfma_f32_16x16x32_bf16(a, Bf[s], acc, 0, 0, 0);
  }
  float bv = bw[t * 16 + c];
#pragma unroll
  for (int jj = 0; jj < 4; ++jj)
    av16[(size_t)(rb0 + 4 * g + jj) * 16 + c] = acc[jj] + bv;
}

// ---------------- CSR build ----------------
struct CSRParams {
  const int* dst[6];
  int* cnt; int* rowp; int* cursor; int* col;
  int ndst[6];
};

__global__ __launch_bounds__(256) void hist_kernel(CSRParams P) {
  int gt = blockIdx.x * blockDim.x + threadIdx.x;
  int n = gridDim.x * blockDim.x;
  for (int idx = gt; idx < 6 * EE; idx += n) {
    int rel = idx / EE, i = idx - rel * EE;
    atomicAdd(&P.cnt[rel * 50000 + P.dst[rel][i]], 1);
  }
}

__global__ __launch_bounds__(1024) void scan_kernel(CSRParams P) {
  int rel = blockIdx.x;
  int n = P.ndst[rel];
  const int* c = P.cnt + rel * 50000;
  int* rp = P.rowp + rel * 50001;
  int* cur = P.cursor + rel * 50000;
  __shared__ int part[1024];
  int tid = threadIdx.x;
  int chunk = (n + 1023) / 1024;
  int lo = tid * chunk, hi = lo + chunk;
  if (hi > n) hi = n;
  int s = 0;
  for (int j = lo; j < hi; ++j) s += c[j];
  part[tid] = s;
  __syncthreads();
  if (tid == 0) {
    int acc = 0;
    for (int k = 0; k < 1024; ++k) { int v = part[k]; part[k] = acc; acc += v; }
    rp[n] = acc;
  }
  __syncthreads();
  int acc = part[tid];
  for (int j = lo; j < hi; ++j) { rp[j] = acc; cur[j] = acc; acc += c[j]; }
}

__global__ __launch_bounds__(256) void scatter_kernel(CSRParams P) {
  int gt = blockIdx.x * blockDim.x + threadIdx.x;
  int n = gridDim.x * blockDim.x;
  for (int idx = gt; idx < 6 * EE; idx += n) {
    int rel = idx / EE, i = idx - rel * EE;
    int d = P.dst[rel][i];
    int pos = atomicAdd(&P.cursor[rel * 50000 + d], 1);
    P.col[rel * EE + pos] = i;
  }
}

// ---------------- fused per-dst aggregation (gather; 4 edges in flight) ----------------
struct AggRel {
  const int* src; const int* col; const int* rowp;
  const float* asv;   // av16 + rowbase_src*16 + sblk*4 (stride 16)
  const float* adv;   // av16 + rowbase_dst*16 + dblk*4 (stride 16)
  const unsigned short* hs;
  const int* ea;
  int gtype;          // 0 none, 1 gtab rel0, 2 gtab rel1, 3 G buffer
};
struct AggGroup { int n; unsigned short* aggbf; AggRel rel[2]; };
struct AggParams {
  AggGroup grp[2]; int ngrp;
  const float* gtab; const unsigned short* G;
};

__global__ __launch_bounds__(256) void agg_kernel(AggParams P) {
  int wid = (blockIdx.x * 256 + threadIdx.x) >> 6;
  int lane = threadIdx.x & 63;
  int q = lane & 15, e4 = lane >> 4, h = q >> 2;
  int gi = 0, node = wid;
  if (node >= P.grp[0].n) {
    node -= P.grp[0].n; gi = 1;
    if (gi >= P.ngrp || node >= P.grp[1].n) return;
  }
  const AggGroup& Gr = P.grp[gi];
  float acc[8];
#pragma unroll
  for (int j = 0; j < 8; ++j) acc[j] = 0.f;

  for (int rs = 0; rs < 2; ++rs) {
    const AggRel& R = Gr.rel[rs];
    int rp = R.rowp[node], re = R.rowp[node + 1];
    if (rp == re) continue;
    float4 ad4 = *reinterpret_cast<const float4*>(R.adv + (size_t)node * 16);

    float m0 = -1e30f, m1 = -1e30f, m2 = -1e30f, m3 = -1e30f;
    float s0 = 0.f, s1 = 0.f, s2 = 0.f, s3 = 0.f;
    int deg = re - rp;

    if (deg <= 64) {
      float e0 = -1e30f, e1 = -1e30f, e2 = -1e30f, e3 = -1e30f;
      int k = rp + lane;
      bool ok = k < re;
      if (ok) {
        int i = R.col[k];
        int si = R.src[i];
        float4 s4 = *reinterpret_cast<const float4*>(R.asv + (size_t)si * 16);
        e0 = s4.x + ad4.x; e0 = e0 > 0.f ? e0 : 0.2f * e0;
        e1 = s4.y + ad4.y; e1 = e1 > 0.f ? e1 : 0.2f * e1;
        e2 = s4.z + ad4.z; e2 = e2 > 0.f ? e2 : 0.2f * e2;
        e3 = s4.w + ad4.w; e3 = e3 > 0.f ? e3 : 0.2f * e3;
      }
      m0 = e0; m1 = e1; m2 = e2; m3 = e3;
#pragma unroll
      for (int d = 1; d < 64; d <<= 1) {
        m0 = fmaxf(m0, __shfl_xor(m0, d));
        m1 = fmaxf(m1, __shfl_xor(m1, d));
        m2 = fmaxf(m2, __shfl_xor(m2, d));
        m3 = fmaxf(m3, __shfl_xor(m3, d));
      }
      s0 = ok ? __expf(e0 - m0) : 0.f;
      s1 = ok ? __expf(e1 - m1) : 0.f;
      s2 = ok ? __expf(e2 - m2) : 0.f;
      s3 = ok ? __expf(e3 - m3) : 0.f;
#pragma unroll
      for (int d = 1; d < 64; d <<= 1) {
        s0 += __shfl_xor(s0, d);
        s1 += __shfl_xor(s1, d);
        s2 += __shfl_xor(s2, d);
        s3 += __shfl_xor(s3, d);
      }
    } else {
      for (int b = rp; b < re; b += 64) {
        int k = b + lane;
        if (k < re) {
          int i = R.col[k];
          int si = R.src[i];
          float4 s4 = *reinterpret_cast<const float4*>(R.asv + (size_t)si * 16);
          float e0 = s4.x + ad4.x; e0 = e0 > 0.f ? e0 : 0.2f * e0;
          float e1 = s4.y + ad4.y; e1 = e1 > 0.f ? e1 : 0.2f * e1;
          float e2 = s4.z + ad4.z; e2 = e2 > 0.f ? e2 : 0.2f * e2;
          float e3 = s4.w + ad4.w; e3 = e3 > 0.f ? e3 : 0.2f * e3;
          m0 = fmaxf(m0, e0); m1 = fmaxf(m1, e1); m2 = fmaxf(m2, e2); m3 = fmaxf(m3, e3);
        }
      }
#pragma unroll
      for (int d = 1; d < 64; d <<= 1) {
        m0 = fmaxf(m0, __shfl_xor(m0, d));
        m1 = fmaxf(m1, __shfl_xor(m1, d));
        m2 = fmaxf(m2, __shfl_xor(m2, d));
        m3 = fmaxf(m3, __shfl_xor(m3, d));
      }
      for (int b = rp; b < re; b += 64) {
        int k = b + lane;
        if (k < re) {
          int i = R.col[k];
          int si = R.src[i];
          float4 s4 = *reinterpret_cast<const float4*>(R.asv + (size_t)si * 16);
          float e0 = s4.x + ad4.x; e0 = e0 > 0.f ? e0 : 0.2f * e0;
          float e1 = s4.y + ad4.y; e1 = e1 > 0.f ? e1 : 0.2f * e1;
          float e2 = s4.z + ad4.z; e2 = e2 > 0.f ? e2 : 0.2f * e2;
          float e3 = s4.w + ad4.w; e3 = e3 > 0.f ? e3 : 0.2f * e3;
          s0 += __expf(e0 - m0); s1 += __expf(e1 - m1); s2 += __expf(e2 - m2); s3 += __expf(e3 - m3);
        }
      }
#pragma unroll
      for (int d = 1; d < 64; d <<= 1) {
        s0 += __shfl_xor(s0, d);
        s1 += __shfl_xor(s1, d);
        s2 += __shfl_xor(s2, d);
        s3 += __shfl_xor(s3, d);
      }
    }

    float mh = sel4(m0, m1, m2, m3, h);
    float invh = 1.f / (sel4(s0, s1, s2, s3, h) + 1e-16f);
    float adh = sel4(ad4.x, ad4.y, ad4.z, ad4.w, h);

    int nit = (deg + 3) >> 2;
    for (int it = 0; it < nit; ++it) {
      int k = rp + it * 4 + e4;
      bool valid = k < re;
      int kk = valid ? k : re - 1;
      int i = R.col[kk];
      int si = R.src[i];
      float eh = R.asv[(size_t)si * 16 + h] + adh;
      eh = eh > 0.f ? eh : 0.2f * eh;
      float alpha = valid ? __expf(eh - mh) * invh : 0.f;
      s16x8 ms = *reinterpret_cast<const s16x8*>(R.hs + (size_t)si * 128 + 8 * q);
      if (R.gtype == 0) {
#pragma unroll
        for (int j = 0; j < 8; ++j) acc[j] += alpha * bf2f((unsigned short)ms[j]);
      } else if (R.gtype == 3) {
        s16x8 gq = *reinterpret_cast<const s16x8*>(P.G + (size_t)i * 128 + 8 * q);
#pragma unroll
        for (int j = 0; j < 8; ++j) acc[j] += alpha * bf2f((unsigned short)ms[j]) * bf2f((unsigned short)gq[j]);
      } else {
        int a = R.ea[(size_t)i * 2], s2i = R.ea[(size_t)i * 2 + 1];
        const float* gp = P.gtab + (size_t)((R.gtype - 1) * 50 + a * 5 + s2i) * 128 + 8 * q;
        float4 g0 = *reinterpret_cast<const float4*>(gp);
        float4 g1 = *reinterpret_cast<const float4*>(gp + 4);
        acc[0] += alpha * bf2f((unsigned short)ms[0]) * g0.x;
        acc[1] += alpha * bf2f((unsigned short)ms[1]) * g0.y;
        acc[2] += alpha * bf2f((unsigned short)ms[2]) * g0.z;
        acc[3] += alpha * bf2f((unsigned short)ms[3]) * g0.w;
        acc[4] += alpha * bf2f((unsigned short)ms[4]) * g1.x;
        acc[5] += alpha * bf2f((unsigned short)ms[5]) * g1.y;
        acc[6] += alpha * bf2f((unsigned short)ms[6]) * g1.z;
        acc[7] += alpha * bf2f((unsigned short)ms[7]) * g1.w;
      }
    }
  }
#pragma unroll
  for (int j = 0; j < 8; ++j) {
    acc[j] += __shfl_xor(acc[j], 16);
    acc[j] += __shfl_xor(acc[j], 32);
  }
  if (e4 == 0) {
    s16x8 o;
#pragma unroll
    for (int j = 0; j < 8; ++j) o[j] = (short)f2bf(acc[j]);
    *reinterpret_cast<s16x8*>(Gr.aggbf + (size_t)node * 128 + 8 * q) = o;
  }
}

// categorical gate table
__global__ void gatetab_kernel(const float* at_emb, const float* as_emb,
                               const float* Wcat, const float* bcat, float* gtab, int l) {
  int rel = blockIdx.x / 50, combo = blockIdx.x % 50;
  int a = combo / 5, s2 = combo % 5;
  int d = threadIdx.x;
  const float* Wb = Wcat + (size_t)(l * 2 + rel) * 64 * 128;
  float acc = bcat[(size_t)(l * 2 + rel) * 128 + d];
  const float* ae = at_emb + (size_t)(l * 10 + a) * 32;
  const float* se = as_emb + (size_t)(l * 5 + s2) * 32;
  for (int k = 0; k < 32; ++k) acc += ae[k] * Wb[k * 128 + d];
  for (int k = 0; k < 32; ++k) acc += se[k] * Wb[(32 + k) * 128 + d];
  gtab[(size_t)(rel * 50 + combo) * 128 + d] = 1.f / (1.f + expf(-acc));
}

// LayerNorm(xs + tmp) -> xs (f32) and xs_bf (bf16)
__global__ __launch_bounds__(256) void ln_kernel(float* xs, unsigned short* xs_bf, const float* tmp,
                                                 const float* g_base, const float* b_base) {
  int wid = (blockIdx.x * blockDim.x + threadIdx.x) >> 6;
  int lane = threadIdx.x & 63;
  int nw = (gridDim.x * blockDim.x) >> 6;
  for (int row = wid; row < NTOT; row += nw) {
    int t = row < NC_ ? 0 : (row < NC_ + ND_ ? 1 : 2);
    size_t ro = (size_t)row * 128 + 2 * lane;
    float2 x = *reinterpret_cast<const float2*>(xs + ro);
    float2 tv = *reinterpret_cast<const float2*>(tmp + ro);
    float a = x.x + tv.x, b = x.y + tv.y;
    float s = a + b;
#pragma unroll
    for (int m = 1; m <= 32; m <<= 1) s += __shfl_xor(s, m);
    float mu = s * 0.0078125f;
    float da = a - mu, db = b - mu;
    float v = da * da + db * db;
#pragma unroll
    for (int m = 1; m <= 32; m <<= 1) v += __shfl_xor(v, m);
    float rs = rsqrtf(v * 0.0078125f + 1e-5f);
    float2 gg = *reinterpret_cast<const float2*>(g_base + t * 128 + 2 * lane);
    float2 bb = *reinterpret_cast<const float2*>(b_base + t * 128 + 2 * lane);
    float2 o;
    o.x = da * rs * gg.x + bb.x;
    o.y = db * rs * gg.y + bb.y;
    *reinterpret_cast<float2*>(xs + ro) = o;
    ushort2 ob; ob.x = f2bf(o.x); ob.y = f2bf(o.y);
    *reinterpret_cast<ushort2*>(xs_bf + ro) = ob;
  }
}

// init: xs (f32) + xs_bf (bf16) from the three embedding tables
__global__ __launch_bounds__(256) void cvt_init_kernel(const float* emb_c, const float* emb_d, const float* emb_g,
                                                       float* xs, unsigned short* xs_bf) {
  int i = blockIdx.x * 256 + threadIdx.x;
  if (i >= NTOT * 64) return;
  int row = i >> 6;
  int cpos = (i & 63) * 2;
  const float* src;
  if (row < NC_) src = emb_c + (size_t)row * 128;
  else if (row < NC_ + ND_) src = emb_d + (size_t)(row - NC_) * 128;
  else src = emb_g + (size_t)(row - NC_ - ND_) * 128;
  float2 v = *reinterpret_cast<const float2*>(src + cpos);
  *reinterpret_cast<float2*>(xs + (size_t)row * 128 + cpos) = v;
  ushort2 ob; ob.x = f2bf(v.x); ob.y = f2bf(v.y);
  *reinterpret_cast<ushort2*>(xs_bf + (size_t)row * 128 + cpos) = ob;
}

__global__ __launch_bounds__(256) void pair_kernel(const float* Y, const float* x1,
                                                   const int* ps, const int* pd, float* out) {
  int wid = (blockIdx.x * blockDim.x + threadIdx.x) >> 6;
  int lane = threadIdx.x & 63;
  int nw = (gridDim.x * blockDim.x) >> 6;
  for (int p = wid; p < PP_; p += nw) {
    int ai = ps[p], bi = pd[p];
    float2 y = *reinterpret_cast<const float2*>(Y + (size_t)ai * 128 + 2 * lane);
    float2 x = *reinterpret_cast<const float2*>(x1 + (size_t)bi * 128 + 2 * lane);
    float s = y.x * x.x + y.y * x.y;
#pragma unroll
    for (int m = 1; m <= 32; m <<= 1) s += __shfl_xor(s, m);
    if (lane == 0) out[p] = s;
  }
}

__global__ void fill_kernel(float* out, int n, float v) {
  int i = blockIdx.x * blockDim.x + threadIdx.x;
  if (i < n) out[i] = v;
}

// ---------------- host ----------------
extern "C" void kernel_launch(void* const* d_in, const int* in_sizes, int n_in,
                              void* d_out, int out_size, void* d_ws, size_t ws_size,
                              hipStream_t stream) {
  (void)in_sizes; (void)n_in;
  const float* emb_c = (const float*)d_in[0];
  const float* emb_d = (const float*)d_in[1];
  const float* emb_g = (const float*)d_in[2];
  const float* Wsrc  = (const float*)d_in[3];
  const float* bsrc  = (const float*)d_in[4];
  const float* Wdst  = (const float*)d_in[5];
  const float* bdst  = (const float*)d_in[6];
  const float* attn  = (const float*)d_in[7];
  const float* Wout  = (const float*)d_in[8];
  const float* bout  = (const float*)d_in[9];
  const float* ln_g  = (const float*)d_in[10];
  const float* ln_b  = (const float*)d_in[11];
  const float* at_emb = (const float*)d_in[12];
  const float* as_emb = (const float*)d_in[13];
  const float* Wcat  = (const float*)d_in[14];
  const float* bcat  = (const float*)d_in[15];
  const float* Wc1   = (const float*)d_in[16];
  const float* bc1   = (const float*)d_in[17];
  const float* Wc2   = (const float*)d_in[18];
  const float* bc2   = (const float*)d_in[19];
  const float* W_cd  = (const float*)d_in[20];
  const float* ea4   = (const float*)d_in[21];
  const float* ea5   = (const float*)d_in[22];
  const int* srcs[6] = {(const int*)d_in[23], (const int*)d_in[25], (const int*)d_in[27],
                        (const int*)d_in[29], (const int*)d_in[31], (const int*)d_in[33]};
  const int* dsts[6] = {(const int*)d_in[24], (const int*)d_in[26], (const int*)d_in[28],
                        (const int*)d_in[30], (const int*)d_in[32], (const int*)d_in[34]};
  const int* ea0 = (const int*)d_in[35];
  const int* ea1 = (const int*)d_in[36];
  const int* pair_src = (const int*)d_in[37];
  const int* pair_dst = (const int*)d_in[38];

  static const int ST_[6] = {0, 2, 0, 1, 1, 2};
  static const int DT_[6] = {2, 0, 1, 0, 2, 1};
  static const int NT_[3] = {NC_, ND_, NG_};
  static const int HSOFF[6] = {0, 50000, 80000, 130000, 150000, 170000};
  static const int SBLK[6] = {0, 0, 1, 0, 1, 1};
  static const int DBLK[6] = {2, 2, 2, 3, 3, 3};
  static const int rowbase[3] = {0, 50000, 70000};

  // workspace carve (~220 MB)
  size_t off = 0;
  auto alloc = [&](size_t bytes) { off = (off + 255) & ~(size_t)255; size_t o = off; off += bytes; return o; };
  size_t o_xs   = alloc((size_t)NTOT * 512);          // f32 node states
  size_t o_xsbf = alloc((size_t)NTOT * 256);          // bf16 node states (GEMM A)
  size_t o_agbf = alloc((size_t)NTOT * 256);          // bf16 agg
  size_t o_hs   = alloc((size_t)200000 * 256);        // bf16 src proj | tmp f32 | Y f32
  size_t o_G    = alloc((size_t)200000 * 256);        // bf16 gates (G4 then G5)
  size_t o_av   = alloc((size_t)NTOT * 64);           // av16 f32 [NTOT][16]
  size_t o_wv   = alloc((size_t)3 * 128 * 16 * 2);
  size_t o_bw   = alloc((size_t)3 * 16 * 4);
  size_t o_gtab = alloc((size_t)100 * 512);
  size_t o_cnt  = alloc((size_t)6 * 50000 * 4);
  size_t o_rowp = alloc((size_t)6 * 50001 * 4);
  size_t o_cur  = alloc((size_t)6 * 50000 * 4);
  size_t o_col  = alloc((size_t)6 * EE * 4);
  if (off > ws_size) {
    fill_kernel<<<(PP_ + 255) / 256, 256, 0, stream>>>((float*)d_out, out_size, 1.0e6f);
    return;
  }

  char* ws = (char*)d_ws;
  float* xs = (float*)(ws + o_xs);
  unsigned short* xs_bf = (unsigned short*)(ws + o_xsbf);
  unsigned short* agg_bf = (unsigned short*)(ws + o_agbf);
  unsigned short* hs = (unsigned short*)(ws + o_hs);
  float* tmp = (float*)(ws + o_hs);                   // alias
  float* Y = (float*)(ws + o_hs);                     // alias (after tmp dead)
  unsigned short* G = (unsigned short*)(ws + o_G);
  float* av16 = (float*)(ws + o_av);
  unsigned short* wv = (unsigned short*)(ws + o_wv);
  float* bw = (float*)(ws + o_bw);
  float* gtab = (float*)(ws + o_gtab);
  int* cnt = (int*)(ws + o_cnt);
  int* rowp = (int*)(ws + o_rowp);
  int* cursor = (int*)(ws + o_cur);
  int* col = (int*)(ws + o_col);

  cvt_init_kernel<<<(NTOT * 64 + 255) / 256, 256, 0, stream>>>(emb_c, emb_d, emb_g, xs, xs_bf);

  // ---- CSR build ----
  hipMemsetAsync(cnt, 0, (size_t)6 * 50000 * 4, stream);
  CSRParams cp{};
  for (int r = 0; r < 6; ++r) { cp.dst[r] = dsts[r]; cp.ndst[r] = NT_[DT_[r]]; }
  cp.cnt = cnt; cp.rowp = rowp; cp.cursor = cursor; cp.col = col;
  hist_kernel<<<2048, 256, 0, stream>>>(cp);
  scan_kernel<<<6, 1024, 0, stream>>>(cp);
  scatter_kernel<<<2048, 256, 0, stream>>>(cp);

  for (int l = 0; l < 2; ++l) {
    gatetab_kernel<<<100, 128, 0, stream>>>(at_emb, as_emb, Wcat, bcat, gtab, l);
    wvbuild_kernel<<<48, 128, 0, stream>>>(Wsrc, Wdst, bsrc, bdst, attn, wv, bw, l);

    // 6 src projections -> hs (bf16)
    GParams gp{};
    for (int r = 0; r < 6; ++r) {
      int st = ST_[r];
      gp.e[r] = {xs_bf + (size_t)rowbase[st] * 128, Wsrc + (size_t)(l * 6 + r) * 16384,
                 bsrc + (size_t)(l * 6 + r) * 128, (void*)(hs + (size_t)HSOFF[r] * 128),
                 nullptr, nullptr, nullptr, NT_[st], 0, 0, 1};
    }
    gemm128<<<dim3(98, 6), 256, 0, stream>>>(gp);

    // all as/ad in one MFMA pass
    advec_kernel<<<(NTOT + 63) / 64, 256, 0, stream>>>(xs_bf, wv, bw, av16);

    // G4 gate
    GParams g4{};
    g4.e[0] = {nullptr, Wc2 + (size_t)(l * 2 + 0) * 16384, bc2 + (size_t)(l * 2 + 0) * 128, (void*)G,
               ea4, Wc1 + (size_t)(l * 2 + 0) * 256, bc1 + (size_t)(l * 2 + 0) * 128, EE, 2, 1, 1};
    gemm128<<<dim3(391, 1), 256, 0, stream>>>(g4);

    auto mkrel = [&](int r) {
      AggRel R;
      R.src = srcs[r]; R.col = col + (size_t)r * EE; R.rowp = rowp + (size_t)r * 50001;
      R.asv = av16 + (size_t)rowbase[ST_[r]] * 16 + SBLK[r] * 4;
      R.adv = av16 + (size_t)rowbase[DT_[r]] * 16 + DBLK[r] * 4;
      R.hs = hs + (size_t)HSOFF[r] * 128;
      R.ea = (r == 0) ? ea0 : (r == 1) ? ea1 : nullptr;
      R.gtype = (r == 0) ? 1 : (r == 1) ? 2 : (r >= 4) ? 3 : 0;
      return R;
    };

    // agg A: dst type 2 (rels 0,4 - uses G4) + dst type 0 (rels 1,3)
    AggParams pa{};
    pa.grp[0].n = NG_; pa.grp[0].aggbf = agg_bf + (size_t)rowbase[2] * 128;
    pa.grp[0].rel[0] = mkrel(0); pa.grp[0].rel[1] = mkrel(4);
    pa.grp[1].n = NC_; pa.grp[1].aggbf = agg_bf + (size_t)rowbase[0] * 128;
    pa.grp[1].rel[0] = mkrel(1); pa.grp[1].rel[1] = mkrel(3);
    pa.ngrp = 2; pa.gtab = gtab; pa.G = G;
    agg_kernel<<<(NG_ + NC_) / 4, 256, 0, stream>>>(pa);

    // G5 gate (same buffer)
    GParams g5{};
    g5.e[0] = {nullptr, Wc2 + (size_t)(l * 2 + 1) * 16384, bc2 + (size_t)(l * 2 + 1) * 128, (void*)G,
               ea5, Wc1 + (size_t)(l * 2 + 1) * 256, bc1 + (size_t)(l * 2 + 1) * 128, EE, 2, 1, 1};
    gemm128<<<dim3(391, 1), 256, 0, stream>>>(g5);

    // agg B: dst type 1 (rels 2,5 - uses G5)
    AggParams pb{};
    pb.grp[0].n = ND_; pb.grp[0].aggbf = agg_bf + (size_t)rowbase[1] * 128;
    pb.grp[0].rel[0] = mkrel(2); pb.grp[0].rel[1] = mkrel(5);
    pb.grp[1].n = 0; pb.grp[1].aggbf = nullptr;
    pb.grp[1].rel[0] = mkrel(2); pb.grp[1].rel[1] = mkrel(5);
    pb.ngrp = 1; pb.gtab = gtab; pb.G = G;
    agg_kernel<<<(ND_) / 4, 256, 0, stream>>>(pb);

    // tmp = agg_bf @ Wout + bout (f32; tmp aliases hs, dead after agg)
    GParams gw{};
    for (int t = 0; t < 3; ++t)
      gw.e[t] = {agg_bf + (size_t)rowbase[t] * 128, Wout + (size_t)(l * 3 + t) * 16384,
                 bout + (size_t)(l * 3 + t) * 128, (void*)(tmp + (size_t)rowbase[t] * 128),
                 nullptr, nullptr, nullptr, NT_[t], 0, 0, 0};
    gemm128<<<dim3(98, 3), 256, 0, stream>>>(gw);

    ln_kernel<<<2048, 256, 0, stream>>>(xs, xs_bf, tmp, ln_g + (size_t)l * 384, ln_b + (size_t)l * 384);
  }

  // Y = xs0 @ W_cd (f32; Y aliases hs/tmp region, dead now)
  GParams gy{};
  gy.e[0] = {xs_bf, W_cd, nullptr, (void*)Y, nullptr, nullptr, nullptr, NC_, 0, 0, 0};
  gemm128<<<dim3(98, 1), 256, 0, stream>>>(gy);

  pair_kernel<<<2048, 256, 0, stream>>>(Y, xs + (size_t)NC_ * 128, pair_src, pair_dst, (float*)d_out);
}

// Round 5
// 1677.084 us; speedup vs baseline: 3.8718x; 1.1379x over previous
//
#include <hip/hip_runtime.h>

typedef short s16x8 __attribute__((ext_vector_type(8)));
typedef float f32x4 __attribute__((ext_vector_type(4)));

#define DEV __device__ __forceinline__

static constexpr int NC_ = 50000, ND_ = 20000, NG_ = 30000;
static constexpr int EE = 200000, PP_ = 200000;
static constexpr int NTOT = NC_ + ND_ + NG_;   // 100000

DEV unsigned short f2bf(float f) {
  unsigned u = __float_as_uint(f);
  u = u + 0x7FFFu + ((u >> 16) & 1u);
  return (unsigned short)(u >> 16);
}
DEV float bf2f(unsigned short h) { return __uint_as_float(((unsigned)h) << 16); }
DEV float sel4(float a, float b, float c, float d, int h) {
  float lo = (h & 1) ? b : a;
  float hi = (h & 1) ? d : c;
  return (h & 2) ? hi : lo;
}
// tanh-approx gelu, max abs err ~3e-4 (bf16 noise is 100x larger)
DEV float gelu_f(float x) {
  float y = 0.7978845608f * (x + 0.044715f * x * x * x);
  float t = 1.f - 2.f / (1.f + __expf(2.f * y));
  return 0.5f * x * (1.f + t);
}

// ---------------- batched 128x128 GEMM (MFMA bf16, bf16 A) ----------------
// amode 0: A = bf16 global rows.  amode 2: A[row,k] = gelu(ea[row,0]*Wc1[0,k]+ea[row,1]*Wc1[1,k]+bc1[k])
struct GEntry {
  const unsigned short* A; const float* W; const float* bias; void* out;
  const float* ea; const float* Wc1; const float* bc1;
  int M; int amode; int act; int outbf16;
};
struct GParams { GEntry e[8]; };

__global__ __launch_bounds__(256) void gemm128(GParams P) {
  GEntry E = P.e[blockIdx.y];
  const int M = E.M;
  const int chunk = blockIdx.x * 512;
  if (chunk >= M) return;

  __shared__ __align__(16) unsigned short ldsW[128 * 128];
  __shared__ float ldsC1[3 * 128];

  const int tid = threadIdx.x;
  for (int it = tid; it < 16384; it += 256) {
    int k = it >> 7, n = it & 127;
    ldsW[n * 128 + (k ^ ((n & 7) << 3))] = f2bf(E.W[it]);
  }
  if (E.amode == 2 && tid < 128) {
    ldsC1[tid] = E.Wc1[tid];
    ldsC1[128 + tid] = E.Wc1[128 + tid];
    ldsC1[256 + tid] = E.bc1[tid];
  }
  __syncthreads();

  const int w = tid >> 6, lane = tid & 63, g = lane >> 4, c = lane & 15;
  const int colHalf = (w & 1) * 64;
  const int rowHalf = (w >> 1) * 32;

  s16x8 Bf[4][4];
#pragma unroll
  for (int s = 0; s < 4; ++s)
#pragma unroll
    for (int nb = 0; nb < 4; ++nb) {
      int n = colHalf + nb * 16 + c;
      int idx = n * 128 + ((s * 32 + 8 * g) ^ ((n & 7) << 3));
      Bf[s][nb] = *reinterpret_cast<const s16x8*>(&ldsW[idx]);
    }

  for (int itr = 0; itr < 8; ++itr) {
    if (chunk + itr * 64 >= M) break;
    const int rb = chunk + itr * 64 + rowHalf;

    s16x8 Af[2][4];
#pragma unroll
    for (int mt = 0; mt < 2; ++mt) {
      int row = rb + mt * 16 + c;
      int rr = row < M ? row : M - 1;
      if (E.amode == 0) {
        const unsigned short* ap = E.A + (size_t)rr * 128;
#pragma unroll
        for (int s = 0; s < 4; ++s)
          Af[mt][s] = *reinterpret_cast<const s16x8*>(ap + s * 32 + 8 * g);
      } else {
        float e0 = E.ea[(size_t)rr * 2], e1 = E.ea[(size_t)rr * 2 + 1];
#pragma unroll
        for (int s = 0; s < 4; ++s) {
          s16x8 a;
#pragma unroll
          for (int i = 0; i < 8; ++i) {
            int k = s * 32 + 8 * g + i;
            float h = e0 * ldsC1[k] + e1 * ldsC1[128 + k] + ldsC1[256 + k];
            a[i] = (short)f2bf(gelu_f(h));
          }
          Af[mt][s] = a;
        }
      }
    }

    f32x4 acc[2][4];
#pragma unroll
    for (int mt = 0; mt < 2; ++mt)
#pragma unroll
      for (int nb = 0; nb < 4; ++nb) { acc[mt][nb][0] = 0.f; acc[mt][nb][1] = 0.f; acc[mt][nb][2] = 0.f; acc[mt][nb][3] = 0.f; }

#pragma unroll
    for (int mt = 0; mt < 2; ++mt)
#pragma unroll
      for (int s = 0; s < 4; ++s)
#pragma unroll
        for (int nb = 0; nb < 4; ++nb)
          acc[mt][nb] = __builtin_amdgcn_mfma_f32_16x16x32_bf16(Af[mt][s], Bf[s][nb], acc[mt][nb], 0, 0, 0);

#pragma unroll
    for (int mt = 0; mt < 2; ++mt)
#pragma unroll
      for (int nb = 0; nb < 4; ++nb) {
        int col = colHalf + nb * 16 + c;
        float bv = E.bias ? E.bias[col] : 0.f;
#pragma unroll
        for (int jj = 0; jj < 4; ++jj) {
          int row = rb + mt * 16 + 4 * g + jj;
          if (row < M) {
            float v = acc[mt][nb][jj] + bv;
            if (E.act == 1) v = 1.f / (1.f + __expf(-v));
            if (E.outbf16) ((unsigned short*)E.out)[(size_t)row * 128 + col] = f2bf(v);
            else ((float*)E.out)[(size_t)row * 128 + col] = v;
          }
        }
      }
  }
}

// ---------------- folded attention weights ----------------
__global__ void wvbuild_kernel(const float* Wsrc, const float* Wdst, const float* bsrc, const float* bdst,
                               const float* attn, unsigned short* wv, float* bw, int l) {
  static const int RELT[3][4] = {{0, 2, 1, 3}, {3, 4, 2, 5}, {1, 5, 0, 4}};
  int t = blockIdx.x >> 4, col = blockIdx.x & 15;
  int b = col >> 2, h = col & 3;
  int r = RELT[t][b];
  bool isSrc = b < 2;
  const float* W = (isSrc ? Wsrc : Wdst) + (size_t)(l * 6 + r) * 16384;
  const float* bias = (isSrc ? bsrc : bdst) + (size_t)(l * 6 + r) * 128;
  const float* at = attn + (size_t)(l * 6 + r) * 128 + h * 32;
  int k = threadIdx.x;
  float acc = 0.f;
  for (int dh = 0; dh < 32; ++dh) acc += W[k * 128 + h * 32 + dh] * at[dh];
  wv[((size_t)t * 128 + k) * 16 + col] = f2bf(acc);
  if (k == 0) {
    float bacc = 0.f;
    for (int dh = 0; dh < 32; ++dh) bacc += bias[h * 32 + dh] * at[dh];
    bw[t * 16 + col] = bacc;
  }
}

// av16[row][16] = xs_bf[row] @ wv[type(row)] + bw
__global__ __launch_bounds__(256) void advec_kernel(const unsigned short* xs_bf,
                                                    const unsigned short* wv, const float* bw, float* av16) {
  int rb0 = blockIdx.x * 64 + (threadIdx.x >> 6) * 16;
  if (rb0 >= NTOT) return;
  int lane = threadIdx.x & 63, g = lane >> 4, c = lane & 15;
  int t = rb0 >= (NC_ + ND_) ? 2 : (rb0 >= NC_ ? 1 : 0);
  const unsigned short* wvt = wv + (size_t)t * 2048;
  s16x8 Bf[4];
#pragma unroll
  for (int s = 0; s < 4; ++s) {
    s16x8 bfr;
#pragma unroll
    for (int i = 0; i < 8; ++i) bfr[i] = (short)wvt[(s * 32 + 8 * g + i) * 16 + c];
    Bf[s] = bfr;
  }
  f32x4 acc; acc[0] = 0.f; acc[1] = 0.f; acc[2] = 0.f; acc[3] = 0.f;
  const unsigned short* ap = xs_bf + (size_t)(rb0 + c) * 128;
#pragma unroll
  for (int s = 0; s < 4; ++s) {
    s16x8 a = *reinterpret_cast<const s16x8*>(ap + s * 32 + 8 * g);
    acc = __builtin_amdgcn_mfma_f32_16x16x32_bf16(a, Bf[s], acc, 0, 0, 0);
  }
  float bv = bw[t * 16 + c];
#pragma unroll
  for (int jj = 0; jj < 4; ++jj)
    av16[(size_t)(rb0 + 4 * g + jj) * 16 + c] = acc[jj] + bv;
}

// ---------------- CSR build ----------------
struct CSRParams {
  const int* dst[6];
  int* cnt; int* rowp; int* cursor; int* col;
  int ndst[6];
};

__global__ __launch_bounds__(256) void hist_kernel(CSRParams P) {
  int gt = blockIdx.x * blockDim.x + threadIdx.x;
  int n = gridDim.x * blockDim.x;
  for (int idx = gt; idx < 6 * EE; idx += n) {
    int rel = idx / EE, i = idx - rel * EE;
    atomicAdd(&P.cnt[rel * 50000 + P.dst[rel][i]], 1);
  }
}

__global__ __launch_bounds__(1024) void scan_kernel(CSRParams P) {
  int rel = blockIdx.x;
  int n = P.ndst[rel];
  const int* c = P.cnt + rel * 50000;
  int* rp = P.rowp + rel * 50001;
  int* cur = P.cursor + rel * 50000;
  __shared__ int part[1024];
  int tid = threadIdx.x;
  int chunk = (n + 1023) / 1024;
  int lo = tid * chunk, hi = lo + chunk;
  if (hi > n) hi = n;
  int s = 0;
  for (int j = lo; j < hi; ++j) s += c[j];
  part[tid] = s;
  __syncthreads();
  if (tid == 0) {
    int acc = 0;
    for (int k = 0; k < 1024; ++k) { int v = part[k]; part[k] = acc; acc += v; }
    rp[n] = acc;
  }
  __syncthreads();
  int acc = part[tid];
  for (int j = lo; j < hi; ++j) { rp[j] = acc; cur[j] = acc; acc += c[j]; }
}

__global__ __launch_bounds__(256) void scatter_kernel(CSRParams P) {
  int gt = blockIdx.x * blockDim.x + threadIdx.x;
  int n = gridDim.x * blockDim.x;
  for (int idx = gt; idx < 6 * EE; idx += n) {
    int rel = idx / EE, i = idx - rel * EE;
    int d = P.dst[rel][i];
    int pos = atomicAdd(&P.cursor[rel * 50000 + d], 1);
    P.col[rel * EE + pos] = i;
  }
}

// ---------------- fused per-dst aggregation (gather; shuffle-fed inner loop) ----------------
struct AggRel {
  const int* src; const int* col; const int* rowp;
  const float* asv;   // stride-16 rows
  const float* adv;
  const unsigned short* hs;
  const int* ea;
  int gtype;          // 0 none, 1 gtab rel0, 2 gtab rel1, 3 G buffer
};
struct AggGroup { int n; unsigned short* aggbf; AggRel rel[2]; };
struct AggParams {
  AggGroup grp[2]; int ngrp;
  const float* gtab; const unsigned short* G;
};

__global__ __launch_bounds__(256) void agg_kernel(AggParams P) {
  int wid = (blockIdx.x * 256 + threadIdx.x) >> 6;
  int lane = threadIdx.x & 63;
  int q = lane & 15, e4 = lane >> 4, h = q >> 2;
  int gi = 0, node = wid;
  if (node >= P.grp[0].n) {
    node -= P.grp[0].n; gi = 1;
    if (gi >= P.ngrp || node >= P.grp[1].n) return;
  }
  const AggGroup& Gr = P.grp[gi];
  float acc[8];
#pragma unroll
  for (int j = 0; j < 8; ++j) acc[j] = 0.f;

  for (int rs = 0; rs < 2; ++rs) {
    const AggRel& R = Gr.rel[rs];
    int rp = R.rowp[node], re = R.rowp[node + 1];
    if (rp == re) continue;
    float4 ad4 = *reinterpret_cast<const float4*>(R.adv + (size_t)node * 16);
    int deg = re - rp;

    if (deg <= 64) {
      // phase 1: one edge per lane — gather once, keep everything in registers
      float e0 = -1e30f, e1 = -1e30f, e2 = -1e30f, e3 = -1e30f;
      int i_e = 0, si_e = 0, gx_e = 0;
      int k = rp + lane;
      bool ok = k < re;
      if (ok) {
        i_e = R.col[k];
        si_e = R.src[i_e];
        float4 s4 = *reinterpret_cast<const float4*>(R.asv + (size_t)si_e * 16);
        e0 = s4.x + ad4.x; e0 = e0 > 0.f ? e0 : 0.2f * e0;
        e1 = s4.y + ad4.y; e1 = e1 > 0.f ? e1 : 0.2f * e1;
        e2 = s4.z + ad4.z; e2 = e2 > 0.f ? e2 : 0.2f * e2;
        e3 = s4.w + ad4.w; e3 = e3 > 0.f ? e3 : 0.2f * e3;
        if (R.gtype == 1 || R.gtype == 2)
          gx_e = R.ea[(size_t)i_e * 2] * 5 + R.ea[(size_t)i_e * 2 + 1];
      }
      float m0 = e0, m1 = e1, m2 = e2, m3 = e3;
#pragma unroll
      for (int d = 1; d < 64; d <<= 1) {
        m0 = fmaxf(m0, __shfl_xor(m0, d));
        m1 = fmaxf(m1, __shfl_xor(m1, d));
        m2 = fmaxf(m2, __shfl_xor(m2, d));
        m3 = fmaxf(m3, __shfl_xor(m3, d));
      }
      float s0 = ok ? __expf(e0 - m0) : 0.f;
      float s1 = ok ? __expf(e1 - m1) : 0.f;
      float s2 = ok ? __expf(e2 - m2) : 0.f;
      float s3 = ok ? __expf(e3 - m3) : 0.f;
#pragma unroll
      for (int d = 1; d < 64; d <<= 1) {
        s0 += __shfl_xor(s0, d);
        s1 += __shfl_xor(s1, d);
        s2 += __shfl_xor(s2, d);
        s3 += __shfl_xor(s3, d);
      }
      float mh = sel4(m0, m1, m2, m3, h);
      float invh = 1.f / (sel4(s0, s1, s2, s3, h) + 1e-16f);

      // phase 2: 4 edges/iter; indices + scores arrive by shuffle, only hs/gate rows touch memory
      int nit = (deg + 3) >> 2;
      for (int it = 0; it < nit; ++it) {
        int j = it * 4 + e4;
        bool valid = j < deg;
        int sij = __shfl(si_e, j);
        int ij = __shfl(i_e, j);
        float v0 = __shfl(e0, j), v1 = __shfl(e1, j), v2 = __shfl(e2, j), v3 = __shfl(e3, j);
        float ehj = sel4(v0, v1, v2, v3, h);
        float alpha = valid ? __expf(ehj - mh) * invh : 0.f;
        s16x8 ms = *reinterpret_cast<const s16x8*>(R.hs + (size_t)sij * 128 + 8 * q);
        if (R.gtype == 0) {
#pragma unroll
          for (int j2 = 0; j2 < 8; ++j2) acc[j2] += alpha * bf2f((unsigned short)ms[j2]);
        } else if (R.gtype == 3) {
          s16x8 gq = *reinterpret_cast<const s16x8*>(P.G + (size_t)ij * 128 + 8 * q);
#pragma unroll
          for (int j2 = 0; j2 < 8; ++j2) acc[j2] += alpha * bf2f((unsigned short)ms[j2]) * bf2f((unsigned short)gq[j2]);
        } else {
          int gxj = __shfl(gx_e, j);
          const float* gp = P.gtab + (size_t)((R.gtype - 1) * 50 + gxj) * 128 + 8 * q;
          float4 g0 = *reinterpret_cast<const float4*>(gp);
          float4 g1 = *reinterpret_cast<const float4*>(gp + 4);
          acc[0] += alpha * bf2f((unsigned short)ms[0]) * g0.x;
          acc[1] += alpha * bf2f((unsigned short)ms[1]) * g0.y;
          acc[2] += alpha * bf2f((unsigned short)ms[2]) * g0.z;
          acc[3] += alpha * bf2f((unsigned short)ms[3]) * g0.w;
          acc[4] += alpha * bf2f((unsigned short)ms[4]) * g1.x;
          acc[5] += alpha * bf2f((unsigned short)ms[5]) * g1.y;
          acc[6] += alpha * bf2f((unsigned short)ms[6]) * g1.z;
          acc[7] += alpha * bf2f((unsigned short)ms[7]) * g1.w;
        }
      }
    } else {
      // rare high-degree fallback (original path)
      float m0 = -1e30f, m1 = -1e30f, m2 = -1e30f, m3 = -1e30f;
      float s0 = 0.f, s1 = 0.f, s2 = 0.f, s3 = 0.f;
      for (int b = rp; b < re; b += 64) {
        int k = b + lane;
        if (k < re) {
          int i = R.col[k];
          int si = R.src[i];
          float4 s4 = *reinterpret_cast<const float4*>(R.asv + (size_t)si * 16);
          float e0 = s4.x + ad4.x; e0 = e0 > 0.f ? e0 : 0.2f * e0;
          float e1 = s4.y + ad4.y; e1 = e1 > 0.f ? e1 : 0.2f * e1;
          float e2 = s4.z + ad4.z; e2 = e2 > 0.f ? e2 : 0.2f * e2;
          float e3 = s4.w + ad4.w; e3 = e3 > 0.f ? e3 : 0.2f * e3;
          m0 = fmaxf(m0, e0); m1 = fmaxf(m1, e1); m2 = fmaxf(m2, e2); m3 = fmaxf(m3, e3);
        }
      }
#pragma unroll
      for (int d = 1; d < 64; d <<= 1) {
        m0 = fmaxf(m0, __shfl_xor(m0, d));
        m1 = fmaxf(m1, __shfl_xor(m1, d));
        m2 = fmaxf(m2, __shfl_xor(m2, d));
        m3 = fmaxf(m3, __shfl_xor(m3, d));
      }
      for (int b = rp; b < re; b += 64) {
        int k = b + lane;
        if (k < re) {
          int i = R.col[k];
          int si = R.src[i];
          float4 s4 = *reinterpret_cast<const float4*>(R.asv + (size_t)si * 16);
          float e0 = s4.x + ad4.x; e0 = e0 > 0.f ? e0 : 0.2f * e0;
          float e1 = s4.y + ad4.y; e1 = e1 > 0.f ? e1 : 0.2f * e1;
          float e2 = s4.z + ad4.z; e2 = e2 > 0.f ? e2 : 0.2f * e2;
          float e3 = s4.w + ad4.w; e3 = e3 > 0.f ? e3 : 0.2f * e3;
          s0 += __expf(e0 - m0); s1 += __expf(e1 - m1); s2 += __expf(e2 - m2); s3 += __expf(e3 - m3);
        }
      }
#pragma unroll
      for (int d = 1; d < 64; d <<= 1) {
        s0 += __shfl_xor(s0, d);
        s1 += __shfl_xor(s1, d);
        s2 += __shfl_xor(s2, d);
        s3 += __shfl_xor(s3, d);
      }
      float mh = sel4(m0, m1, m2, m3, h);
      float invh = 1.f / (sel4(s0, s1, s2, s3, h) + 1e-16f);
      float adh = sel4(ad4.x, ad4.y, ad4.z, ad4.w, h);
      int nit = (deg + 3) >> 2;
      for (int it = 0; it < nit; ++it) {
        int k = rp + it * 4 + e4;
        bool valid = k < re;
        int kk = valid ? k : re - 1;
        int i = R.col[kk];
        int si = R.src[i];
        float eh = R.asv[(size_t)si * 16 + h] + adh;
        eh = eh > 0.f ? eh : 0.2f * eh;
        float alpha = valid ? __expf(eh - mh) * invh : 0.f;
        s16x8 ms = *reinterpret_cast<const s16x8*>(R.hs + (size_t)si * 128 + 8 * q);
        if (R.gtype == 0) {
#pragma unroll
          for (int j2 = 0; j2 < 8; ++j2) acc[j2] += alpha * bf2f((unsigned short)ms[j2]);
        } else if (R.gtype == 3) {
          s16x8 gq = *reinterpret_cast<const s16x8*>(P.G + (size_t)i * 128 + 8 * q);
#pragma unroll
          for (int j2 = 0; j2 < 8; ++j2) acc[j2] += alpha * bf2f((unsigned short)ms[j2]) * bf2f((unsigned short)gq[j2]);
        } else {
          int a = R.ea[(size_t)i * 2], s2i = R.ea[(size_t)i * 2 + 1];
          const float* gp = P.gtab + (size_t)((R.gtype - 1) * 50 + a * 5 + s2i) * 128 + 8 * q;
          float4 g0 = *reinterpret_cast<const float4*>(gp);
          float4 g1 = *reinterpret_cast<const float4*>(gp + 4);
          acc[0] += alpha * bf2f((unsigned short)ms[0]) * g0.x;
          acc[1] += alpha * bf2f((unsigned short)ms[1]) * g0.y;
          acc[2] += alpha * bf2f((unsigned short)ms[2]) * g0.z;
          acc[3] += alpha * bf2f((unsigned short)ms[3]) * g0.w;
          acc[4] += alpha * bf2f((unsigned short)ms[4]) * g1.x;
          acc[5] += alpha * bf2f((unsigned short)ms[5]) * g1.y;
          acc[6] += alpha * bf2f((unsigned short)ms[6]) * g1.z;
          acc[7] += alpha * bf2f((unsigned short)ms[7]) * g1.w;
        }
      }
    }
  }
#pragma unroll
  for (int j = 0; j < 8; ++j) {
    acc[j] += __shfl_xor(acc[j], 16);
    acc[j] += __shfl_xor(acc[j], 32);
  }
  if (e4 == 0) {
    s16x8 o;
#pragma unroll
    for (int j = 0; j < 8; ++j) o[j] = (short)f2bf(acc[j]);
    *reinterpret_cast<s16x8*>(Gr.aggbf + (size_t)node * 128 + 8 * q) = o;
  }
}

// categorical gate table
__global__ void gatetab_kernel(const float* at_emb, const float* as_emb,
                               const float* Wcat, const float* bcat, float* gtab, int l) {
  int rel = blockIdx.x / 50, combo = blockIdx.x % 50;
  int a = combo / 5, s2 = combo % 5;
  int d = threadIdx.x;
  const float* Wb = Wcat + (size_t)(l * 2 + rel) * 64 * 128;
  float acc = bcat[(size_t)(l * 2 + rel) * 128 + d];
  const float* ae = at_emb + (size_t)(l * 10 + a) * 32;
  const float* se = as_emb + (size_t)(l * 5 + s2) * 32;
  for (int k = 0; k < 32; ++k) acc += ae[k] * Wb[k * 128 + d];
  for (int k = 0; k < 32; ++k) acc += se[k] * Wb[(32 + k) * 128 + d];
  gtab[(size_t)(rel * 50 + combo) * 128 + d] = 1.f / (1.f + __expf(-acc));
}

// LayerNorm(xs + tmp) -> xs (f32) and xs_bf (bf16)
__global__ __launch_bounds__(256) void ln_kernel(float* xs, unsigned short* xs_bf, const float* tmp,
                                                 const float* g_base, const float* b_base) {
  int wid = (blockIdx.x * blockDim.x + threadIdx.x) >> 6;
  int lane = threadIdx.x & 63;
  int nw = (gridDim.x * blockDim.x) >> 6;
  for (int row = wid; row < NTOT; row += nw) {
    int t = row < NC_ ? 0 : (row < NC_ + ND_ ? 1 : 2);
    size_t ro = (size_t)row * 128 + 2 * lane;
    float2 x = *reinterpret_cast<const float2*>(xs + ro);
    float2 tv = *reinterpret_cast<const float2*>(tmp + ro);
    float a = x.x + tv.x, b = x.y + tv.y;
    float s = a + b;
#pragma unroll
    for (int m = 1; m <= 32; m <<= 1) s += __shfl_xor(s, m);
    float mu = s * 0.0078125f;
    float da = a - mu, db = b - mu;
    float v = da * da + db * db;
#pragma unroll
    for (int m = 1; m <= 32; m <<= 1) v += __shfl_xor(v, m);
    float rs = rsqrtf(v * 0.0078125f + 1e-5f);
    float2 gg = *reinterpret_cast<const float2*>(g_base + t * 128 + 2 * lane);
    float2 bb = *reinterpret_cast<const float2*>(b_base + t * 128 + 2 * lane);
    float2 o;
    o.x = da * rs * gg.x + bb.x;
    o.y = db * rs * gg.y + bb.y;
    *reinterpret_cast<float2*>(xs + ro) = o;
    ushort2 ob; ob.x = f2bf(o.x); ob.y = f2bf(o.y);
    *reinterpret_cast<ushort2*>(xs_bf + ro) = ob;
  }
}

// init: xs (f32) + xs_bf (bf16)
__global__ __launch_bounds__(256) void cvt_init_kernel(const float* emb_c, const float* emb_d, const float* emb_g,
                                                       float* xs, unsigned short* xs_bf) {
  int i = blockIdx.x * 256 + threadIdx.x;
  if (i >= NTOT * 64) return;
  int row = i >> 6;
  int cpos = (i & 63) * 2;
  const float* src;
  if (row < NC_) src = emb_c + (size_t)row * 128;
  else if (row < NC_ + ND_) src = emb_d + (size_t)(row - NC_) * 128;
  else src = emb_g + (size_t)(row - NC_ - ND_) * 128;
  float2 v = *reinterpret_cast<const float2*>(src + cpos);
  *reinterpret_cast<float2*>(xs + (size_t)row * 128 + cpos) = v;
  ushort2 ob; ob.x = f2bf(v.x); ob.y = f2bf(v.y);
  *reinterpret_cast<ushort2*>(xs_bf + (size_t)row * 128 + cpos) = ob;
}

// out[p] = dot(Y[ps[p]], x1[pd[p]]) — half-wave (32 lanes) per pair, float4 loads
__global__ __launch_bounds__(256) void pair_kernel(const float* Y, const float* x1,
                                                   const int* ps, const int* pd, float* out) {
  int hw = (blockIdx.x * blockDim.x + threadIdx.x) >> 5;
  int lane = threadIdx.x & 31;
  int nhw = (gridDim.x * blockDim.x) >> 5;
  for (int p = hw; p < PP_; p += nhw) {
    int ai = ps[p], bi = pd[p];
    float4 y = *reinterpret_cast<const float4*>(Y + (size_t)ai * 128 + 4 * lane);
    float4 x = *reinterpret_cast<const float4*>(x1 + (size_t)bi * 128 + 4 * lane);
    float s = y.x * x.x + y.y * x.y + y.z * x.z + y.w * x.w;
#pragma unroll
    for (int m = 1; m <= 16; m <<= 1) s += __shfl_xor(s, m, 32);
    if (lane == 0) out[p] = s;
  }
}

__global__ void fill_kernel(float* out, int n, float v) {
  int i = blockIdx.x * blockDim.x + threadIdx.x;
  if (i < n) out[i] = v;
}

// ---------------- host ----------------
extern "C" void kernel_launch(void* const* d_in, const int* in_sizes, int n_in,
                              void* d_out, int out_size, void* d_ws, size_t ws_size,
                              hipStream_t stream) {
  (void)in_sizes; (void)n_in;
  const float* emb_c = (const float*)d_in[0];
  const float* emb_d = (const float*)d_in[1];
  const float* emb_g = (const float*)d_in[2];
  const float* Wsrc  = (const float*)d_in[3];
  const float* bsrc  = (const float*)d_in[4];
  const float* Wdst  = (const float*)d_in[5];
  const float* bdst  = (const float*)d_in[6];
  const float* attn  = (const float*)d_in[7];
  const float* Wout  = (const float*)d_in[8];
  const float* bout  = (const float*)d_in[9];
  const float* ln_g  = (const float*)d_in[10];
  const float* ln_b  = (const float*)d_in[11];
  const float* at_emb = (const float*)d_in[12];
  const float* as_emb = (const float*)d_in[13];
  const float* Wcat  = (const float*)d_in[14];
  const float* bcat  = (const float*)d_in[15];
  const float* Wc1   = (const float*)d_in[16];
  const float* bc1   = (const float*)d_in[17];
  const float* Wc2   = (const float*)d_in[18];
  const float* bc2   = (const float*)d_in[19];
  const float* W_cd  = (const float*)d_in[20];
  const float* ea4   = (const float*)d_in[21];
  const float* ea5   = (const float*)d_in[22];
  const int* srcs[6] = {(const int*)d_in[23], (const int*)d_in[25], (const int*)d_in[27],
                        (const int*)d_in[29], (const int*)d_in[31], (const int*)d_in[33]};
  const int* dsts[6] = {(const int*)d_in[24], (const int*)d_in[26], (const int*)d_in[28],
                        (const int*)d_in[30], (const int*)d_in[32], (const int*)d_in[34]};
  const int* ea0 = (const int*)d_in[35];
  const int* ea1 = (const int*)d_in[36];
  const int* pair_src = (const int*)d_in[37];
  const int* pair_dst = (const int*)d_in[38];

  static const int ST_[6] = {0, 2, 0, 1, 1, 2};
  static const int DT_[6] = {2, 0, 1, 0, 2, 1};
  static const int NT_[3] = {NC_, ND_, NG_};
  static const int HSOFF[6] = {0, 50000, 80000, 130000, 150000, 170000};
  static const int SBLK[6] = {0, 0, 1, 0, 1, 1};
  static const int DBLK[6] = {2, 2, 2, 3, 3, 3};
  static const int rowbase[3] = {0, 50000, 70000};

  size_t off = 0;
  auto alloc = [&](size_t bytes) { off = (off + 255) & ~(size_t)255; size_t o = off; off += bytes; return o; };
  size_t o_xs   = alloc((size_t)NTOT * 512);
  size_t o_xsbf = alloc((size_t)NTOT * 256);
  size_t o_agbf = alloc((size_t)NTOT * 256);
  size_t o_hs   = alloc((size_t)200000 * 256);        // bf16 src proj | tmp f32 | Y f32
  size_t o_G    = alloc((size_t)200000 * 256);        // bf16 gates (G4 then G5)
  size_t o_av   = alloc((size_t)NTOT * 64);
  size_t o_wv   = alloc((size_t)3 * 128 * 16 * 2);
  size_t o_bw   = alloc((size_t)3 * 16 * 4);
  size_t o_gtab = alloc((size_t)100 * 512);
  size_t o_cnt  = alloc((size_t)6 * 50000 * 4);
  size_t o_rowp = alloc((size_t)6 * 50001 * 4);
  size_t o_cur  = alloc((size_t)6 * 50000 * 4);
  size_t o_col  = alloc((size_t)6 * EE * 4);
  if (off > ws_size) {
    fill_kernel<<<(PP_ + 255) / 256, 256, 0, stream>>>((float*)d_out, out_size, 1.0e6f);
    return;
  }

  char* ws = (char*)d_ws;
  float* xs = (float*)(ws + o_xs);
  unsigned short* xs_bf = (unsigned short*)(ws + o_xsbf);
  unsigned short* agg_bf = (unsigned short*)(ws + o_agbf);
  unsigned short* hs = (unsigned short*)(ws + o_hs);
  float* tmp = (float*)(ws + o_hs);
  float* Y = (float*)(ws + o_hs);
  unsigned short* G = (unsigned short*)(ws + o_G);
  float* av16 = (float*)(ws + o_av);
  unsigned short* wv = (unsigned short*)(ws + o_wv);
  float* bw = (float*)(ws + o_bw);
  float* gtab = (float*)(ws + o_gtab);
  int* cnt = (int*)(ws + o_cnt);
  int* rowp = (int*)(ws + o_rowp);
  int* cursor = (int*)(ws + o_cur);
  int* col = (int*)(ws + o_col);

  cvt_init_kernel<<<(NTOT * 64 + 255) / 256, 256, 0, stream>>>(emb_c, emb_d, emb_g, xs, xs_bf);

  hipMemsetAsync(cnt, 0, (size_t)6 * 50000 * 4, stream);
  CSRParams cp{};
  for (int r = 0; r < 6; ++r) { cp.dst[r] = dsts[r]; cp.ndst[r] = NT_[DT_[r]]; }
  cp.cnt = cnt; cp.rowp = rowp; cp.cursor = cursor; cp.col = col;
  hist_kernel<<<2048, 256, 0, stream>>>(cp);
  scan_kernel<<<6, 1024, 0, stream>>>(cp);
  scatter_kernel<<<2048, 256, 0, stream>>>(cp);

  for (int l = 0; l < 2; ++l) {
    gatetab_kernel<<<100, 128, 0, stream>>>(at_emb, as_emb, Wcat, bcat, gtab, l);
    wvbuild_kernel<<<48, 128, 0, stream>>>(Wsrc, Wdst, bsrc, bdst, attn, wv, bw, l);

    GParams gp{};
    for (int r = 0; r < 6; ++r) {
      int st = ST_[r];
      gp.e[r] = {xs_bf + (size_t)rowbase[st] * 128, Wsrc + (size_t)(l * 6 + r) * 16384,
                 bsrc + (size_t)(l * 6 + r) * 128, (void*)(hs + (size_t)HSOFF[r] * 128),
                 nullptr, nullptr, nullptr, NT_[st], 0, 0, 1};
    }
    gemm128<<<dim3(98, 6), 256, 0, stream>>>(gp);

    advec_kernel<<<(NTOT + 63) / 64, 256, 0, stream>>>(xs_bf, wv, bw, av16);

    GParams g4{};
    g4.e[0] = {nullptr, Wc2 + (size_t)(l * 2 + 0) * 16384, bc2 + (size_t)(l * 2 + 0) * 128, (void*)G,
               ea4, Wc1 + (size_t)(l * 2 + 0) * 256, bc1 + (size_t)(l * 2 + 0) * 128, EE, 2, 1, 1};
    gemm128<<<dim3(391, 1), 256, 0, stream>>>(g4);

    auto mkrel = [&](int r) {
      AggRel R;
      R.src = srcs[r]; R.col = col + (size_t)r * EE; R.rowp = rowp + (size_t)r * 50001;
      R.asv = av16 + (size_t)rowbase[ST_[r]] * 16 + SBLK[r] * 4;
      R.adv = av16 + (size_t)rowbase[DT_[r]] * 16 + DBLK[r] * 4;
      R.hs = hs + (size_t)HSOFF[r] * 128;
      R.ea = (r == 0) ? ea0 : (r == 1) ? ea1 : nullptr;
      R.gtype = (r == 0) ? 1 : (r == 1) ? 2 : (r >= 4) ? 3 : 0;
      return R;
    };

    AggParams pa{};
    pa.grp[0].n = NG_; pa.grp[0].aggbf = agg_bf + (size_t)rowbase[2] * 128;
    pa.grp[0].rel[0] = mkrel(0); pa.grp[0].rel[1] = mkrel(4);
    pa.grp[1].n = NC_; pa.grp[1].aggbf = agg_bf + (size_t)rowbase[0] * 128;
    pa.grp[1].rel[0] = mkrel(1); pa.grp[1].rel[1] = mkrel(3);
    pa.ngrp = 2; pa.gtab = gtab; pa.G = G;
    agg_kernel<<<(NG_ + NC_) / 4, 256, 0, stream>>>(pa);

    GParams g5{};
    g5.e[0] = {nullptr, Wc2 + (size_t)(l * 2 + 1) * 16384, bc2 + (size_t)(l * 2 + 1) * 128, (void*)G,
               ea5, Wc1 + (size_t)(l * 2 + 1) * 256, bc1 + (size_t)(l * 2 + 1) * 128, EE, 2, 1, 1};
    gemm128<<<dim3(391, 1), 256, 0, stream>>>(g5);

    AggParams pb{};
    pb.grp[0].n = ND_; pb.grp[0].aggbf = agg_bf + (size_t)rowbase[1] * 128;
    pb.grp[0].rel[0] = mkrel(2); pb.grp[0].rel[1] = mkrel(5);
    pb.grp[1].n = 0; pb.grp[1].aggbf = nullptr;
    pb.grp[1].rel[0] = mkrel(2); pb.grp[1].rel[1] = mkrel(5);
    pb.ngrp = 1; pb.gtab = gtab; pb.G = G;
    agg_kernel<<<(ND_) / 4, 256, 0, stream>>>(pb);

    GParams gw{};
    for (int t = 0; t < 3; ++t)
      gw.e[t] = {agg_bf + (size_t)rowbase[t] * 128, Wout + (size_t)(l * 3 + t) * 16384,
                 bout + (size_t)(l * 3 + t) * 128, (void*)(tmp + (size_t)rowbase[t] * 128),
                 nullptr, nullptr, nullptr, NT_[t], 0, 0, 0};
    gemm128<<<dim3(98, 3), 256, 0, stream>>>(gw);

    ln_kernel<<<2048, 256, 0, stream>>>(xs, xs_bf, tmp, ln_g + (size_t)l * 384, ln_b + (size_t)l * 384);
  }

  GParams gy{};
  gy.e[0] = {xs_bf, W_cd, nullptr, (void*)Y, nullptr, nullptr, nullptr, NC_, 0, 0, 0};
  gemm128<<<dim3(98, 1), 256, 0, stream>>>(gy);

  pair_kernel<<<2048, 256, 0, stream>>>(Y, xs + (size_t)NC_ * 128, pair_src, pair_dst, (float*)d_out);
}

// Round 7
// 1459.452 us; speedup vs baseline: 4.4491x; 1.1491x over previous
//
#include <hip/hip_runtime.h>

typedef short s16x8 __attribute__((ext_vector_type(8)));
typedef float f32x4 __attribute__((ext_vector_type(4)));

#define DEV __device__ __forceinline__

static constexpr int NC_ = 50000, ND_ = 20000, NG_ = 30000;
static constexpr int EE = 200000, PP_ = 200000;
static constexpr int NTOT = NC_ + ND_ + NG_;   // 100000

DEV unsigned short f2bf(float f) {
  unsigned u = __float_as_uint(f);
  u = u + 0x7FFFu + ((u >> 16) & 1u);
  return (unsigned short)(u >> 16);
}
DEV float bf2f(unsigned short h) { return __uint_as_float(((unsigned)h) << 16); }
DEV float sel4(float a, float b, float c, float d, int h) {
  float lo = (h & 1) ? b : a;
  float hi = (h & 1) ? d : c;
  return (h & 2) ? hi : lo;
}
// tanh-approx gelu, max abs err ~3e-4
DEV float gelu_f(float x) {
  float y = 0.7978845608f * (x + 0.044715f * x * x * x);
  float t = 1.f - 2.f / (1.f + __expf(2.f * y));
  return 0.5f * x * (1.f + t);
}

// ---------------- weight prepack: f32 [k][n] -> bf16 fragment-linear ----------------
// frag (s, nbb) of lane (g,c): elements k=s*32+8g+j, n=nbb*16+c at idx ((s*8+nbb)*64+lane)*8+j
struct PackParams { const float* src[23]; unsigned short* dst; };
__global__ __launch_bounds__(256) void pack_kernel(PackParams P) {
  int m = blockIdx.x;
  const float* S = P.src[m];
  unsigned short* D = P.dst + (size_t)m * 16384;
  for (int idx = threadIdx.x; idx < 16384; idx += 256) {
    int j = idx & 7;
    int lane = (idx >> 3) & 63;
    int snb = idx >> 9;
    int s = snb >> 3, nbb = snb & 7;
    int k = s * 32 + 8 * (lane >> 4) + j;
    int n = nbb * 16 + (lane & 15);
    D[idx] = f2bf(S[k * 128 + n]);
  }
}

// ---------------- flattened batched 128-col GEMM (no LDS for W) ----------------
// amode 0: A = bf16 rows.  amode 2: A[row,k] = gelu(ea[row,0]*Wc1[0,k]+ea[row,1]*Wc1[1,k]+bc1[k])
struct GEntry2 {
  const unsigned short* A; const unsigned short* Wp; const float* bias; void* out;
  const float* ea; const float* Wc1; const float* bc1;
  int M; int amode; int act; int outbf16; int blk0;
};
struct GParams2 { GEntry2 e[8]; int nent; };

__global__ __launch_bounds__(256) void gemm2(GParams2 P) {
  int bx = blockIdx.x;
  int ei = 0;
  while (ei + 1 < P.nent && bx >= P.e[ei + 1].blk0) ++ei;
  GEntry2 E = P.e[ei];
  const int M = E.M;
  const int row0 = (bx - E.blk0) * 128;
  if (row0 >= M) return;

  const int tid = threadIdx.x;
  const int w = tid >> 6, lane = tid & 63, g = lane >> 4, c = lane & 15;
  const int colHalf = (w & 1) * 64;
  const int rowHalf = (w >> 1) * 32;

  __shared__ float ldsC1[384];
  if (E.amode == 2) {
    if (tid < 128) {
      ldsC1[tid] = E.Wc1[tid];
      ldsC1[128 + tid] = E.Wc1[128 + tid];
      ldsC1[256 + tid] = E.bc1[tid];
    }
    __syncthreads();
  }

  // B fragments: coalesced 16B/lane from fragment-linear Wp
  s16x8 Bf[4][4];
#pragma unroll
  for (int s = 0; s < 4; ++s)
#pragma unroll
    for (int nb = 0; nb < 4; ++nb) {
      int nbb = (w & 1) * 4 + nb;
      Bf[s][nb] = *reinterpret_cast<const s16x8*>(E.Wp + ((size_t)(s * 8 + nbb) * 64 + lane) * 8);
    }

#pragma unroll
  for (int itr = 0; itr < 2; ++itr) {
    if (row0 + itr * 64 >= M) break;
    const int rb = row0 + itr * 64 + rowHalf;

    s16x8 Af[2][4];
#pragma unroll
    for (int mt = 0; mt < 2; ++mt) {
      int row = rb + mt * 16 + c;
      int rr = row < M ? row : M - 1;
      if (E.amode == 0) {
        const unsigned short* ap = E.A + (size_t)rr * 128;
#pragma unroll
        for (int s = 0; s < 4; ++s)
          Af[mt][s] = *reinterpret_cast<const s16x8*>(ap + s * 32 + 8 * g);
      } else {
        float e0 = E.ea[(size_t)rr * 2], e1 = E.ea[(size_t)rr * 2 + 1];
#pragma unroll
        for (int s = 0; s < 4; ++s) {
          s16x8 a;
#pragma unroll
          for (int i = 0; i < 8; ++i) {
            int k = s * 32 + 8 * g + i;
            float h = e0 * ldsC1[k] + e1 * ldsC1[128 + k] + ldsC1[256 + k];
            a[i] = (short)f2bf(gelu_f(h));
          }
          Af[mt][s] = a;
        }
      }
    }

    f32x4 acc[2][4];
#pragma unroll
    for (int mt = 0; mt < 2; ++mt)
#pragma unroll
      for (int nb = 0; nb < 4; ++nb) { acc[mt][nb][0] = 0.f; acc[mt][nb][1] = 0.f; acc[mt][nb][2] = 0.f; acc[mt][nb][3] = 0.f; }

#pragma unroll
    for (int mt = 0; mt < 2; ++mt)
#pragma unroll
      for (int s = 0; s < 4; ++s)
#pragma unroll
        for (int nb = 0; nb < 4; ++nb)
          acc[mt][nb] = __builtin_amdgcn_mfma_f32_16x16x32_bf16(Af[mt][s], Bf[s][nb], acc[mt][nb], 0, 0, 0);

#pragma unroll
    for (int mt = 0; mt < 2; ++mt)
#pragma unroll
      for (int nb = 0; nb < 4; ++nb) {
        int col = colHalf + nb * 16 + c;
        float bv = E.bias ? E.bias[col] : 0.f;
#pragma unroll
        for (int jj = 0; jj < 4; ++jj) {
          int row = rb + mt * 16 + 4 * g + jj;
          if (row < M) {
            float v = acc[mt][nb][jj] + bv;
            if (E.act == 1) v = 1.f / (1.f + __expf(-v));
            if (E.outbf16) ((unsigned short*)E.out)[(size_t)row * 128 + col] = f2bf(v);
            else ((float*)E.out)[(size_t)row * 128 + col] = v;
          }
        }
      }
  }
}

// ---------------- folded attention weights ----------------
__global__ void wvbuild_kernel(const float* Wsrc, const float* Wdst, const float* bsrc, const float* bdst,
                               const float* attn, unsigned short* wv, float* bw, int l) {
  static const int RELT[3][4] = {{0, 2, 1, 3}, {3, 4, 2, 5}, {1, 5, 0, 4}};
  int t = blockIdx.x >> 4, col = blockIdx.x & 15;
  int b = col >> 2, h = col & 3;
  int r = RELT[t][b];
  bool isSrc = b < 2;
  const float* W = (isSrc ? Wsrc : Wdst) + (size_t)(l * 6 + r) * 16384;
  const float* bias = (isSrc ? bsrc : bdst) + (size_t)(l * 6 + r) * 128;
  const float* at = attn + (size_t)(l * 6 + r) * 128 + h * 32;
  int k = threadIdx.x;
  float acc = 0.f;
  for (int dh = 0; dh < 32; ++dh) acc += W[k * 128 + h * 32 + dh] * at[dh];
  wv[((size_t)t * 128 + k) * 16 + col] = f2bf(acc);
  if (k == 0) {
    float bacc = 0.f;
    for (int dh = 0; dh < 32; ++dh) bacc += bias[h * 32 + dh] * at[dh];
    bw[t * 16 + col] = bacc;
  }
}

// av16[row][16] = xs_bf[row] @ wv[type(row)] + bw
__global__ __launch_bounds__(256) void advec_kernel(const unsigned short* xs_bf,
                                                    const unsigned short* wv, const float* bw, float* av16) {
  int rb0 = blockIdx.x * 64 + (threadIdx.x >> 6) * 16;
  if (rb0 >= NTOT) return;
  int lane = threadIdx.x & 63, g = lane >> 4, c = lane & 15;
  int t = rb0 >= (NC_ + ND_) ? 2 : (rb0 >= NC_ ? 1 : 0);
  const unsigned short* wvt = wv + (size_t)t * 2048;
  s16x8 Bf[4];
#pragma unroll
  for (int s = 0; s < 4; ++s) {
    s16x8 bfr;
#pragma unroll
    for (int i = 0; i < 8; ++i) bfr[i] = (short)wvt[(s * 32 + 8 * g + i) * 16 + c];
    Bf[s] = bfr;
  }
  f32x4 acc; acc[0] = 0.f; acc[1] = 0.f; acc[2] = 0.f; acc[3] = 0.f;
  const unsigned short* ap = xs_bf + (size_t)(rb0 + c) * 128;
#pragma unroll
  for (int s = 0; s < 4; ++s) {
    s16x8 a = *reinterpret_cast<const s16x8*>(ap + s * 32 + 8 * g);
    acc = __builtin_amdgcn_mfma_f32_16x16x32_bf16(a, Bf[s], acc, 0, 0, 0);
  }
  float bv = bw[t * 16 + c];
#pragma unroll
  for (int jj = 0; jj < 4; ++jj)
    av16[(size_t)(rb0 + 4 * g + jj) * 16 + c] = acc[jj] + bv;
}

// ---------------- CSR build ----------------
struct CSRParams {
  const int* dst[6];
  int* cnt; int* rowp; int* cursor; int* col;
  int ndst[6];
};

__global__ __launch_bounds__(256) void hist_kernel(CSRParams P) {
  int gt = blockIdx.x * blockDim.x + threadIdx.x;
  int n = gridDim.x * blockDim.x;
  for (int idx = gt; idx < 6 * EE; idx += n) {
    int rel = idx / EE, i = idx - rel * EE;
    atomicAdd(&P.cnt[rel * 50000 + P.dst[rel][i]], 1);
  }
}

__global__ __launch_bounds__(1024) void scan_kernel(CSRParams P) {
  int rel = blockIdx.x;
  int n = P.ndst[rel];
  const int* c = P.cnt + rel * 50000;
  int* rp = P.rowp + rel * 50001;
  int* cur = P.cursor + rel * 50000;
  __shared__ int part[1024];
  int tid = threadIdx.x;
  int chunk = (n + 1023) / 1024;
  int lo = tid * chunk, hi = lo + chunk;
  if (hi > n) hi = n;
  int s = 0;
  for (int j = lo; j < hi; ++j) s += c[j];
  part[tid] = s;
  __syncthreads();
  if (tid == 0) {
    int acc = 0;
    for (int k = 0; k < 1024; ++k) { int v = part[k]; part[k] = acc; acc += v; }
    rp[n] = acc;
  }
  __syncthreads();
  int acc = part[tid];
  for (int j = lo; j < hi; ++j) { rp[j] = acc; cur[j] = acc; acc += c[j]; }
}

__global__ __launch_bounds__(256) void scatter_kernel(CSRParams P) {
  int gt = blockIdx.x * blockDim.x + threadIdx.x;
  int n = gridDim.x * blockDim.x;
  for (int idx = gt; idx < 6 * EE; idx += n) {
    int rel = idx / EE, i = idx - rel * EE;
    int d = P.dst[rel][i];
    int pos = atomicAdd(&P.cursor[rel * 50000 + d], 1);
    P.col[rel * EE + pos] = i;
  }
}

// ---------------- fused per-dst aggregation ----------------
struct AggRel {
  const int* src; const int* col; const int* rowp;
  const float* asv; const float* adv;
  const unsigned short* hs;
  const int* ea;
  int gtype;          // 0 none, 1 gtab rel0, 2 gtab rel1, 3 G buffer
};
struct AggGroup { int n; unsigned short* aggbf; AggRel rel[2]; };
struct AggParams {
  AggGroup grp[2]; int ngrp;
  const float* gtab; const unsigned short* G;
};

__global__ __launch_bounds__(256) void agg_kernel(AggParams P) {
  int wid = (blockIdx.x * 256 + threadIdx.x) >> 6;
  int lane = threadIdx.x & 63;
  int q = lane & 15, e4 = lane >> 4, h = q >> 2;
  int gi = 0, node = wid;
  if (node >= P.grp[0].n) {
    node -= P.grp[0].n; gi = 1;
    if (gi >= P.ngrp || node >= P.grp[1].n) return;
  }
  const AggGroup& Gr = P.grp[gi];
  float acc[8];
#pragma unroll
  for (int j = 0; j < 8; ++j) acc[j] = 0.f;

  for (int rs = 0; rs < 2; ++rs) {
    const AggRel& R = Gr.rel[rs];
    int rp = R.rowp[node], re = R.rowp[node + 1];
    if (rp == re) continue;
    float4 ad4 = *reinterpret_cast<const float4*>(R.adv + (size_t)node * 16);
    int deg = re - rp;

    if (deg <= 64) {
      float e0 = -1e30f, e1 = -1e30f, e2 = -1e30f, e3 = -1e30f;
      int i_e = 0, si_e = 0, gx_e = 0;
      int k = rp + lane;
      bool ok = k < re;
      if (ok) {
        i_e = R.col[k];
        si_e = R.src[i_e];
        float4 s4 = *reinterpret_cast<const float4*>(R.asv + (size_t)si_e * 16);
        e0 = s4.x + ad4.x; e0 = e0 > 0.f ? e0 : 0.2f * e0;
        e1 = s4.y + ad4.y; e1 = e1 > 0.f ? e1 : 0.2f * e1;
        e2 = s4.z + ad4.z; e2 = e2 > 0.f ? e2 : 0.2f * e2;
        e3 = s4.w + ad4.w; e3 = e3 > 0.f ? e3 : 0.2f * e3;
        if (R.gtype == 1 || R.gtype == 2)
          gx_e = R.ea[(size_t)i_e * 2] * 5 + R.ea[(size_t)i_e * 2 + 1];
      }
      float m0 = e0, m1 = e1, m2 = e2, m3 = e3;
#pragma unroll
      for (int d = 1; d < 64; d <<= 1) {
        m0 = fmaxf(m0, __shfl_xor(m0, d));
        m1 = fmaxf(m1, __shfl_xor(m1, d));
        m2 = fmaxf(m2, __shfl_xor(m2, d));
        m3 = fmaxf(m3, __shfl_xor(m3, d));
      }
      float s0 = ok ? __expf(e0 - m0) : 0.f;
      float s1 = ok ? __expf(e1 - m1) : 0.f;
      float s2 = ok ? __expf(e2 - m2) : 0.f;
      float s3 = ok ? __expf(e3 - m3) : 0.f;
#pragma unroll
      for (int d = 1; d < 64; d <<= 1) {
        s0 += __shfl_xor(s0, d);
        s1 += __shfl_xor(s1, d);
        s2 += __shfl_xor(s2, d);
        s3 += __shfl_xor(s3, d);
      }
      float mh = sel4(m0, m1, m2, m3, h);
      float invh = 1.f / (sel4(s0, s1, s2, s3, h) + 1e-16f);

      int nit = (deg + 3) >> 2;
      for (int it = 0; it < nit; ++it) {
        int j = it * 4 + e4;
        bool valid = j < deg;
        int sij = __shfl(si_e, j);
        int ij = __shfl(i_e, j);
        float v0 = __shfl(e0, j), v1 = __shfl(e1, j), v2 = __shfl(e2, j), v3 = __shfl(e3, j);
        float ehj = sel4(v0, v1, v2, v3, h);
        float alpha = valid ? __expf(ehj - mh) * invh : 0.f;
        s16x8 ms = *reinterpret_cast<const s16x8*>(R.hs + (size_t)sij * 128 + 8 * q);
        if (R.gtype == 0) {
#pragma unroll
          for (int j2 = 0; j2 < 8; ++j2) acc[j2] += alpha * bf2f((unsigned short)ms[j2]);
        } else if (R.gtype == 3) {
          s16x8 gq = *reinterpret_cast<const s16x8*>(P.G + (size_t)ij * 128 + 8 * q);
#pragma unroll
          for (int j2 = 0; j2 < 8; ++j2) acc[j2] += alpha * bf2f((unsigned short)ms[j2]) * bf2f((unsigned short)gq[j2]);
        } else {
          int gxj = __shfl(gx_e, j);
          const float* gp = P.gtab + (size_t)((R.gtype - 1) * 50 + gxj) * 128 + 8 * q;
          float4 g0 = *reinterpret_cast<const float4*>(gp);
          float4 g1 = *reinterpret_cast<const float4*>(gp + 4);
          acc[0] += alpha * bf2f((unsigned short)ms[0]) * g0.x;
          acc[1] += alpha * bf2f((unsigned short)ms[1]) * g0.y;
          acc[2] += alpha * bf2f((unsigned short)ms[2]) * g0.z;
          acc[3] += alpha * bf2f((unsigned short)ms[3]) * g0.w;
          acc[4] += alpha * bf2f((unsigned short)ms[4]) * g1.x;
          acc[5] += alpha * bf2f((unsigned short)ms[5]) * g1.y;
          acc[6] += alpha * bf2f((unsigned short)ms[6]) * g1.z;
          acc[7] += alpha * bf2f((unsigned short)ms[7]) * g1.w;
        }
      }
    } else {
      float m0 = -1e30f, m1 = -1e30f, m2 = -1e30f, m3 = -1e30f;
      float s0 = 0.f, s1 = 0.f, s2 = 0.f, s3 = 0.f;
      for (int b = rp; b < re; b += 64) {
        int k = b + lane;
        if (k < re) {
          int i = R.col[k];
          int si = R.src[i];
          float4 s4 = *reinterpret_cast<const float4*>(R.asv + (size_t)si * 16);
          float e0 = s4.x + ad4.x; e0 = e0 > 0.f ? e0 : 0.2f * e0;
          float e1 = s4.y + ad4.y; e1 = e1 > 0.f ? e1 : 0.2f * e1;
          float e2 = s4.z + ad4.z; e2 = e2 > 0.f ? e2 : 0.2f * e2;
          float e3 = s4.w + ad4.w; e3 = e3 > 0.f ? e3 : 0.2f * e3;
          m0 = fmaxf(m0, e0); m1 = fmaxf(m1, e1); m2 = fmaxf(m2, e2); m3 = fmaxf(m3, e3);
        }
      }
#pragma unroll
      for (int d = 1; d < 64; d <<= 1) {
        m0 = fmaxf(m0, __shfl_xor(m0, d));
        m1 = fmaxf(m1, __shfl_xor(m1, d));
        m2 = fmaxf(m2, __shfl_xor(m2, d));
        m3 = fmaxf(m3, __shfl_xor(m3, d));
      }
      for (int b = rp; b < re; b += 64) {
        int k = b + lane;
        if (k < re) {
          int i = R.col[k];
          int si = R.src[i];
          float4 s4 = *reinterpret_cast<const float4*>(R.asv + (size_t)si * 16);
          float e0 = s4.x + ad4.x; e0 = e0 > 0.f ? e0 : 0.2f * e0;
          float e1 = s4.y + ad4.y; e1 = e1 > 0.f ? e1 : 0.2f * e1;
          float e2 = s4.z + ad4.z; e2 = e2 > 0.f ? e2 : 0.2f * e2;
          float e3 = s4.w + ad4.w; e3 = e3 > 0.f ? e3 : 0.2f * e3;
          s0 += __expf(e0 - m0); s1 += __expf(e1 - m1); s2 += __expf(e2 - m2); s3 += __expf(e3 - m3);
        }
      }
#pragma unroll
      for (int d = 1; d < 64; d <<= 1) {
        s0 += __shfl_xor(s0, d);
        s1 += __shfl_xor(s1, d);
        s2 += __shfl_xor(s2, d);
        s3 += __shfl_xor(s3, d);
      }
      float mh = sel4(m0, m1, m2, m3, h);
      float invh = 1.f / (sel4(s0, s1, s2, s3, h) + 1e-16f);
      float adh = sel4(ad4.x, ad4.y, ad4.z, ad4.w, h);
      int nit = (deg + 3) >> 2;
      for (int it = 0; it < nit; ++it) {
        int k = rp + it * 4 + e4;
        bool valid = k < re;
        int kk = valid ? k : re - 1;
        int i = R.col[kk];
        int si = R.src[i];
        float eh = R.asv[(size_t)si * 16 + h] + adh;
        eh = eh > 0.f ? eh : 0.2f * eh;
        float alpha = valid ? __expf(eh - mh) * invh : 0.f;
        s16x8 ms = *reinterpret_cast<const s16x8*>(R.hs + (size_t)si * 128 + 8 * q);
        if (R.gtype == 0) {
#pragma unroll
          for (int j2 = 0; j2 < 8; ++j2) acc[j2] += alpha * bf2f((unsigned short)ms[j2]);
        } else if (R.gtype == 3) {
          s16x8 gq = *reinterpret_cast<const s16x8*>(P.G + (size_t)i * 128 + 8 * q);
#pragma unroll
          for (int j2 = 0; j2 < 8; ++j2) acc[j2] += alpha * bf2f((unsigned short)ms[j2]) * bf2f((unsigned short)gq[j2]);
        } else {
          int a = R.ea[(size_t)i * 2], s2i = R.ea[(size_t)i * 2 + 1];
          const float* gp = P.gtab + (size_t)((R.gtype - 1) * 50 + a * 5 + s2i) * 128 + 8 * q;
          float4 g0 = *reinterpret_cast<const float4*>(gp);
          float4 g1 = *reinterpret_cast<const float4*>(gp + 4);
          acc[0] += alpha * bf2f((unsigned short)ms[0]) * g0.x;
          acc[1] += alpha * bf2f((unsigned short)ms[1]) * g0.y;
          acc[2] += alpha * bf2f((unsigned short)ms[2]) * g0.z;
          acc[3] += alpha * bf2f((unsigned short)ms[3]) * g0.w;
          acc[4] += alpha * bf2f((unsigned short)ms[4]) * g1.x;
          acc[5] += alpha * bf2f((unsigned short)ms[5]) * g1.y;
          acc[6] += alpha * bf2f((unsigned short)ms[6]) * g1.z;
          acc[7] += alpha * bf2f((unsigned short)ms[7]) * g1.w;
        }
      }
    }
  }
#pragma unroll
  for (int j = 0; j < 8; ++j) {
    acc[j] += __shfl_xor(acc[j], 16);
    acc[j] += __shfl_xor(acc[j], 32);
  }
  if (e4 == 0) {
    s16x8 o;
#pragma unroll
    for (int j = 0; j < 8; ++j) o[j] = (short)f2bf(acc[j]);
    *reinterpret_cast<s16x8*>(Gr.aggbf + (size_t)node * 128 + 8 * q) = o;
  }
}

// categorical gate table
__global__ void gatetab_kernel(const float* at_emb, const float* as_emb,
                               const float* Wcat, const float* bcat, float* gtab, int l) {
  int rel = blockIdx.x / 50, combo = blockIdx.x % 50;
  int a = combo / 5, s2 = combo % 5;
  int d = threadIdx.x;
  const float* Wb = Wcat + (size_t)(l * 2 + rel) * 64 * 128;
  float acc = bcat[(size_t)(l * 2 + rel) * 128 + d];
  const float* ae = at_emb + (size_t)(l * 10 + a) * 32;
  const float* se = as_emb + (size_t)(l * 5 + s2) * 32;
  for (int k = 0; k < 32; ++k) acc += ae[k] * Wb[k * 128 + d];
  for (int k = 0; k < 32; ++k) acc += se[k] * Wb[(32 + k) * 128 + d];
  gtab[(size_t)(rel * 50 + combo) * 128 + d] = 1.f / (1.f + __expf(-acc));
}

// LayerNorm(xs + tmp) -> xs (f32) and xs_bf (bf16)
__global__ __launch_bounds__(256) void ln_kernel(float* xs, unsigned short* xs_bf, const float* tmp,
                                                 const float* g_base, const float* b_base) {
  int wid = (blockIdx.x * blockDim.x + threadIdx.x) >> 6;
  int lane = threadIdx.x & 63;
  int nw = (gridDim.x * blockDim.x) >> 6;
  for (int row = wid; row < NTOT; row += nw) {
    int t = row < NC_ ? 0 : (row < NC_ + ND_ ? 1 : 2);
    size_t ro = (size_t)row * 128 + 2 * lane;
    float2 x = *reinterpret_cast<const float2*>(xs + ro);
    float2 tv = *reinterpret_cast<const float2*>(tmp + ro);
    float a = x.x + tv.x, b = x.y + tv.y;
    float s = a + b;
#pragma unroll
    for (int m = 1; m <= 32; m <<= 1) s += __shfl_xor(s, m);
    float mu = s * 0.0078125f;
    float da = a - mu, db = b - mu;
    float v = da * da + db * db;
#pragma unroll
    for (int m = 1; m <= 32; m <<= 1) v += __shfl_xor(v, m);
    float rs = rsqrtf(v * 0.0078125f + 1e-5f);
    float2 gg = *reinterpret_cast<const float2*>(g_base + t * 128 + 2 * lane);
    float2 bb = *reinterpret_cast<const float2*>(b_base + t * 128 + 2 * lane);
    float2 o;
    o.x = da * rs * gg.x + bb.x;
    o.y = db * rs * gg.y + bb.y;
    *reinterpret_cast<float2*>(xs + ro) = o;
    ushort2 ob; ob.x = f2bf(o.x); ob.y = f2bf(o.y);
    *reinterpret_cast<ushort2*>(xs_bf + ro) = ob;
  }
}

// init: xs (f32) + xs_bf (bf16)
__global__ __launch_bounds__(256) void cvt_init_kernel(const float* emb_c, const float* emb_d, const float* emb_g,
                                                       float* xs, unsigned short* xs_bf) {
  int i = blockIdx.x * 256 + threadIdx.x;
  if (i >= NTOT * 64) return;
  int row = i >> 6;
  int cpos = (i & 63) * 2;
  const float* src;
  if (row < NC_) src = emb_c + (size_t)row * 128;
  else if (row < NC_ + ND_) src = emb_d + (size_t)(row - NC_) * 128;
  else src = emb_g + (size_t)(row - NC_ - ND_) * 128;
  float2 v = *reinterpret_cast<const float2*>(src + cpos);
  *reinterpret_cast<float2*>(xs + (size_t)row * 128 + cpos) = v;
  ushort2 ob; ob.x = f2bf(v.x); ob.y = f2bf(v.y);
  *reinterpret_cast<ushort2*>(xs_bf + (size_t)row * 128 + cpos) = ob;
}

// out[p] = dot(Ybf[ps[p]], x1bf[pd[p]]) — half-wave per pair, bf16 gathers
__global__ __launch_bounds__(256) void pair_kernel(const unsigned short* Ybf, const unsigned short* x1bf,
                                                   const int* ps, const int* pd, float* out) {
  int hw = (blockIdx.x * blockDim.x + threadIdx.x) >> 5;
  int lane = threadIdx.x & 31;
  int nhw = (gridDim.x * blockDim.x) >> 5;
  for (int p = hw; p < PP_; p += nhw) {
    int ai = ps[p], bi = pd[p];
    ushort4 y = *reinterpret_cast<const ushort4*>(Ybf + (size_t)ai * 128 + 4 * lane);
    ushort4 x = *reinterpret_cast<const ushort4*>(x1bf + (size_t)bi * 128 + 4 * lane);
    float s = bf2f(y.x) * bf2f(x.x) + bf2f(y.y) * bf2f(x.y) +
              bf2f(y.z) * bf2f(x.z) + bf2f(y.w) * bf2f(x.w);
#pragma unroll
    for (int m = 1; m <= 16; m <<= 1) s += __shfl_xor(s, m, 32);
    if (lane == 0) out[p] = s;
  }
}

__global__ void fill_kernel(float* out, int n, float v) {
  int i = blockIdx.x * blockDim.x + threadIdx.x;
  if (i < n) out[i] = v;
}

// ---------------- host ----------------
extern "C" void kernel_launch(void* const* d_in, const int* in_sizes, int n_in,
                              void* d_out, int out_size, void* d_ws, size_t ws_size,
                              hipStream_t stream) {
  (void)in_sizes; (void)n_in;
  const float* emb_c = (const float*)d_in[0];
  const float* emb_d = (const float*)d_in[1];
  const float* emb_g = (const float*)d_in[2];
  const float* Wsrc  = (const float*)d_in[3];
  const float* bsrc  = (const float*)d_in[4];
  const float* Wdst  = (const float*)d_in[5];
  const float* bdst  = (const float*)d_in[6];
  const float* attn  = (const float*)d_in[7];
  const float* Wout  = (const float*)d_in[8];
  const float* bout  = (const float*)d_in[9];
  const float* ln_g  = (const float*)d_in[10];
  const float* ln_b  = (const float*)d_in[11];
  const float* at_emb = (const float*)d_in[12];
  const float* as_emb = (const float*)d_in[13];
  const float* Wcat  = (const float*)d_in[14];
  const float* bcat  = (const float*)d_in[15];
  const float* Wc1   = (const float*)d_in[16];
  const float* bc1   = (const float*)d_in[17];
  const float* Wc2   = (const float*)d_in[18];
  const float* bc2   = (const float*)d_in[19];
  const float* W_cd  = (const float*)d_in[20];
  const float* ea4   = (const float*)d_in[21];
  const float* ea5   = (const float*)d_in[22];
  const int* srcs[6] = {(const int*)d_in[23], (const int*)d_in[25], (const int*)d_in[27],
                        (const int*)d_in[29], (const int*)d_in[31], (const int*)d_in[33]};
  const int* dsts[6] = {(const int*)d_in[24], (const int*)d_in[26], (const int*)d_in[28],
                        (const int*)d_in[30], (const int*)d_in[32], (const int*)d_in[34]};
  const int* ea0 = (const int*)d_in[35];
  const int* ea1 = (const int*)d_in[36];
  const int* pair_src = (const int*)d_in[37];
  const int* pair_dst = (const int*)d_in[38];

  static const int ST_[6] = {0, 2, 0, 1, 1, 2};
  static const int DT_[6] = {2, 0, 1, 0, 2, 1};
  static const int NT_[3] = {NC_, ND_, NG_};
  static const int HSOFF[6] = {0, 50000, 80000, 130000, 150000, 170000};
  static const int SBLK[6] = {0, 0, 1, 0, 1, 1};
  static const int DBLK[6] = {2, 2, 2, 3, 3, 3};
  static const int rowbase[3] = {0, 50000, 70000};

  size_t off = 0;
  auto alloc = [&](size_t bytes) { off = (off + 255) & ~(size_t)255; size_t o = off; off += bytes; return o; };
  size_t o_xs    = alloc((size_t)NTOT * 512);
  size_t o_xsbf  = alloc((size_t)NTOT * 256);
  size_t o_agbf  = alloc((size_t)NTOT * 256);
  size_t o_hs    = alloc((size_t)200000 * 256);       // bf16 src proj | tmp f32 | Y bf16
  size_t o_G     = alloc((size_t)200000 * 256);       // bf16 gates (G4 then G5)
  size_t o_av    = alloc((size_t)NTOT * 64);
  size_t o_wv    = alloc((size_t)3 * 128 * 16 * 2);
  size_t o_bw    = alloc((size_t)3 * 16 * 4);
  size_t o_gtab  = alloc((size_t)100 * 512);
  size_t o_wpack = alloc((size_t)23 * 16384 * 2);
  size_t o_cnt   = alloc((size_t)6 * 50000 * 4);
  size_t o_rowp  = alloc((size_t)6 * 50001 * 4);
  size_t o_cur   = alloc((size_t)6 * 50000 * 4);
  size_t o_col   = alloc((size_t)6 * EE * 4);
  if (off > ws_size) {
    fill_kernel<<<(PP_ + 255) / 256, 256, 0, stream>>>((float*)d_out, out_size, 1.0e6f);
    return;
  }

  char* ws = (char*)d_ws;
  float* xs = (float*)(ws + o_xs);
  unsigned short* xs_bf = (unsigned short*)(ws + o_xsbf);
  unsigned short* agg_bf = (unsigned short*)(ws + o_agbf);
  unsigned short* hs = (unsigned short*)(ws + o_hs);
  float* tmp = (float*)(ws + o_hs);
  unsigned short* Ybf = (unsigned short*)(ws + o_hs);
  unsigned short* G = (unsigned short*)(ws + o_G);
  float* av16 = (float*)(ws + o_av);
  unsigned short* wv = (unsigned short*)(ws + o_wv);
  float* bw = (float*)(ws + o_bw);
  float* gtab = (float*)(ws + o_gtab);
  unsigned short* wpack = (unsigned short*)(ws + o_wpack);
  int* cnt = (int*)(ws + o_cnt);
  int* rowp = (int*)(ws + o_rowp);
  int* cursor = (int*)(ws + o_cur);
  int* col = (int*)(ws + o_col);

  // prepack all weights (layout: l*11 + {0-5 proj, 6-7 Wc2, 8-10 Wout}; 22 = W_cd)
  PackParams pk{};
  for (int l = 0; l < 2; ++l) {
    for (int r = 0; r < 6; ++r) pk.src[l * 11 + r] = Wsrc + (size_t)(l * 6 + r) * 16384;
    for (int k = 0; k < 2; ++k) pk.src[l * 11 + 6 + k] = Wc2 + (size_t)(l * 2 + k) * 16384;
    for (int t = 0; t < 3; ++t) pk.src[l * 11 + 8 + t] = Wout + (size_t)(l * 3 + t) * 16384;
  }
  pk.src[22] = W_cd;
  pk.dst = wpack;
  pack_kernel<<<23, 256, 0, stream>>>(pk);

  cvt_init_kernel<<<(NTOT * 64 + 255) / 256, 256, 0, stream>>>(emb_c, emb_d, emb_g, xs, xs_bf);

  hipMemsetAsync(cnt, 0, (size_t)6 * 50000 * 4, stream);
  CSRParams cp{};
  for (int r = 0; r < 6; ++r) { cp.dst[r] = dsts[r]; cp.ndst[r] = NT_[DT_[r]]; }
  cp.cnt = cnt; cp.rowp = rowp; cp.cursor = cursor; cp.col = col;
  hist_kernel<<<2048, 256, 0, stream>>>(cp);
  scan_kernel<<<6, 1024, 0, stream>>>(cp);
  scatter_kernel<<<2048, 256, 0, stream>>>(cp);

  auto nb = [](int M) { return (M + 127) / 128; };

  for (int l = 0; l < 2; ++l) {
    gatetab_kernel<<<100, 128, 0, stream>>>(at_emb, as_emb, Wcat, bcat, gtab, l);
    wvbuild_kernel<<<48, 128, 0, stream>>>(Wsrc, Wdst, bsrc, bdst, attn, wv, bw, l);

    // one dispatch: 6 projections + G4 gate
    GParams2 gp{};
    int blk = 0;
    for (int r = 0; r < 6; ++r) {
      int st = ST_[r];
      gp.e[r] = {xs_bf + (size_t)rowbase[st] * 128, wpack + (size_t)(l * 11 + r) * 16384,
                 bsrc + (size_t)(l * 6 + r) * 128, (void*)(hs + (size_t)HSOFF[r] * 128),
                 nullptr, nullptr, nullptr, NT_[st], 0, 0, 1, blk};
      blk += nb(NT_[st]);
    }
    gp.e[6] = {nullptr, wpack + (size_t)(l * 11 + 6) * 16384, bc2 + (size_t)(l * 2 + 0) * 128, (void*)G,
               ea4, Wc1 + (size_t)(l * 2 + 0) * 256, bc1 + (size_t)(l * 2 + 0) * 128, EE, 2, 1, 1, blk};
    blk += nb(EE);
    gp.nent = 7;
    gemm2<<<blk, 256, 0, stream>>>(gp);

    advec_kernel<<<(NTOT + 63) / 64, 256, 0, stream>>>(xs_bf, wv, bw, av16);

    auto mkrel = [&](int r) {
      AggRel R;
      R.src = srcs[r]; R.col = col + (size_t)r * EE; R.rowp = rowp + (size_t)r * 50001;
      R.asv = av16 + (size_t)rowbase[ST_[r]] * 16 + SBLK[r] * 4;
      R.adv = av16 + (size_t)rowbase[DT_[r]] * 16 + DBLK[r] * 4;
      R.hs = hs + (size_t)HSOFF[r] * 128;
      R.ea = (r == 0) ? ea0 : (r == 1) ? ea1 : nullptr;
      R.gtype = (r == 0) ? 1 : (r == 1) ? 2 : (r >= 4) ? 3 : 0;
      return R;
    };

    AggParams pa{};
    pa.grp[0].n = NG_; pa.grp[0].aggbf = agg_bf + (size_t)rowbase[2] * 128;
    pa.grp[0].rel[0] = mkrel(0); pa.grp[0].rel[1] = mkrel(4);
    pa.grp[1].n = NC_; pa.grp[1].aggbf = agg_bf + (size_t)rowbase[0] * 128;
    pa.grp[1].rel[0] = mkrel(1); pa.grp[1].rel[1] = mkrel(3);
    pa.ngrp = 2; pa.gtab = gtab; pa.G = G;
    agg_kernel<<<(NG_ + NC_) / 4, 256, 0, stream>>>(pa);

    // G5 gate (reuses G buffer after agg A consumed G4)
    GParams2 g5{};
    g5.e[0] = {nullptr, wpack + (size_t)(l * 11 + 7) * 16384, bc2 + (size_t)(l * 2 + 1) * 128, (void*)G,
               ea5, Wc1 + (size_t)(l * 2 + 1) * 256, bc1 + (size_t)(l * 2 + 1) * 128, EE, 2, 1, 1, 0};
    g5.nent = 1;
    gemm2<<<nb(EE), 256, 0, stream>>>(g5);

    AggParams pb{};
    pb.grp[0].n = ND_; pb.grp[0].aggbf = agg_bf + (size_t)rowbase[1] * 128;
    pb.grp[0].rel[0] = mkrel(2); pb.grp[0].rel[1] = mkrel(5);
    pb.grp[1].n = 0; pb.grp[1].aggbf = nullptr;
    pb.grp[1].rel[0] = mkrel(2); pb.grp[1].rel[1] = mkrel(5);
    pb.ngrp = 1; pb.gtab = gtab; pb.G = G;
    agg_kernel<<<(ND_) / 4, 256, 0, stream>>>(pb);

    // Wout (3 entries, one dispatch) -> tmp f32 (aliases hs, dead after agg)
    GParams2 gw{};
    blk = 0;
    for (int t = 0; t < 3; ++t) {
      gw.e[t] = {agg_bf + (size_t)rowbase[t] * 128, wpack + (size_t)(l * 11 + 8 + t) * 16384,
                 bout + (size_t)(l * 3 + t) * 128, (void*)(tmp + (size_t)rowbase[t] * 128),
                 nullptr, nullptr, nullptr, NT_[t], 0, 0, 0, blk};
      blk += nb(NT_[t]);
    }
    gw.nent = 3;
    gemm2<<<blk, 256, 0, stream>>>(gw);

    ln_kernel<<<2048, 256, 0, stream>>>(xs, xs_bf, tmp, ln_g + (size_t)l * 384, ln_b + (size_t)l * 384);
  }

  // Y = xs0 @ W_cd -> bf16 (aliases hs/tmp region, dead now)
  GParams2 gy{};
  gy.e[0] = {xs_bf, wpack + (size_t)22 * 16384, nullptr, (void*)Ybf,
             nullptr, nullptr, nullptr, NC_, 0, 0, 1, 0};
  gy.nent = 1;
  gemm2<<<nb(NC_), 256, 0, stream>>>(gy);

  pair_kernel<<<2048, 256, 0, stream>>>(Ybf, xs_bf + (size_t)NC_ * 128, pair_src, pair_dst, (float*)d_out);
}

// Round 8
// 1376.059 us; speedup vs baseline: 4.7188x; 1.0606x over previous
//
#include <hip/hip_runtime.h>

typedef short s16x8 __attribute__((ext_vector_type(8)));
typedef float f32x4 __attribute__((ext_vector_type(4)));

#define DEV __device__ __forceinline__

static constexpr int NC_ = 50000, ND_ = 20000, NG_ = 30000;
static constexpr int EE = 200000, PP_ = 200000;
static constexpr int NTOT = NC_ + ND_ + NG_;   // 100000

DEV unsigned short f2bf(float f) {
  unsigned u = __float_as_uint(f);
  u = u + 0x7FFFu + ((u >> 16) & 1u);
  return (unsigned short)(u >> 16);
}
DEV float bf2f(unsigned short h) { return __uint_as_float(((unsigned)h) << 16); }
DEV float sel4(float a, float b, float c, float d, int h) {
  float lo = (h & 1) ? b : a;
  float hi = (h & 1) ? d : c;
  return (h & 2) ? hi : lo;
}
DEV float fast_rcp(float x) {
#if __has_builtin(__builtin_amdgcn_rcpf)
  return __builtin_amdgcn_rcpf(x);
#else
  return 1.f / x;
#endif
}
// sigmoid-form gelu x*sigmoid(1.702x): max abs err ~0.02; downstream gate err ~0.005 << 0.73 margin
DEV float gelu_fast(float x) { return x * fast_rcp(1.f + __expf(-1.702f * x)); }
DEV float sigmoid_fast(float x) { return fast_rcp(1.f + __expf(-x)); }

// ---------------- weight prepack: f32 [k][n] -> bf16 fragment-linear ----------------
// frag (s, nbb) of lane (g,c): elements k=s*32+8g+j, n=nbb*16+c at idx ((s*8+nbb)*64+lane)*8+j
struct PackParams { const float* src[23]; unsigned short* dst; };
__global__ __launch_bounds__(256) void pack_kernel(PackParams P) {
  int m = blockIdx.x;
  const float* S = P.src[m];
  unsigned short* D = P.dst + (size_t)m * 16384;
  for (int idx = threadIdx.x; idx < 16384; idx += 256) {
    int j = idx & 7;
    int lane = (idx >> 3) & 63;
    int snb = idx >> 9;
    int s = snb >> 3, nbb = snb & 7;
    int k = s * 32 + 8 * (lane >> 4) + j;
    int n = nbb * 16 + (lane & 15);
    D[idx] = f2bf(S[k * 128 + n]);
  }
}

// ---------------- flattened batched 128-col GEMM (fragment-linear W, no LDS-W) ----------------
// amode 0: A = bf16 rows.  amode 2: A-tile generated cooperatively in LDS:
//   A[row,k] = gelu(ea[row,0]*Wc1[0,k]+ea[row,1]*Wc1[1,k]+bc1[k]), each element computed ONCE.
struct GEntry2 {
  const unsigned short* A; const unsigned short* Wp; const float* bias; void* out;
  const float* ea; const float* Wc1; const float* bc1;
  int M; int amode; int act; int outbf16; int blk0;
};
struct GParams2 { GEntry2 e[8]; int nent; };

__global__ __launch_bounds__(256) void gemm2(GParams2 P) {
  int bx = blockIdx.x;
  int ei = 0;
  while (ei + 1 < P.nent && bx >= P.e[ei + 1].blk0) ++ei;
  GEntry2 E = P.e[ei];
  const int M = E.M;
  const int row0 = (bx - E.blk0) * 128;
  if (row0 >= M) return;

  const int tid = threadIdx.x;
  const int w = tid >> 6, lane = tid & 63, g = lane >> 4, c = lane & 15;
  const int colHalf = (w & 1) * 64;
  const int rowHalf = (w >> 1) * 32;

  __shared__ __align__(16) unsigned short ldsA[128 * 128];   // 32KB A-tile (amode2)
  __shared__ float ldsC1[384];

  if (E.amode == 2) {
    if (tid < 128) {
      ldsC1[tid] = E.Wc1[tid];
      ldsC1[128 + tid] = E.Wc1[128 + tid];
      ldsC1[256 + tid] = E.bc1[tid];
    }
    __syncthreads();
    // cooperative tile generation: each element once, swizzled store
    for (int i = tid; i < 16384; i += 256) {
      int r = i >> 7, colx = i & 127;
      int row = row0 + r;
      int rr = row < M ? row : M - 1;
      float e0 = E.ea[(size_t)rr * 2], e1 = E.ea[(size_t)rr * 2 + 1];
      float h = e0 * ldsC1[colx] + e1 * ldsC1[128 + colx] + ldsC1[256 + colx];
      unsigned short hv = f2bf(gelu_fast(h));
      int cb = (colx * 2) ^ ((r & 7) << 4);
      *reinterpret_cast<unsigned short*>(reinterpret_cast<char*>(ldsA) + r * 256 + cb) = hv;
    }
    __syncthreads();
  }

  // B fragments: coalesced 16B/lane from fragment-linear Wp
  s16x8 Bf[4][4];
#pragma unroll
  for (int s = 0; s < 4; ++s)
#pragma unroll
    for (int nb = 0; nb < 4; ++nb) {
      int nbb = (w & 1) * 4 + nb;
      Bf[s][nb] = *reinterpret_cast<const s16x8*>(E.Wp + ((size_t)(s * 8 + nbb) * 64 + lane) * 8);
    }

#pragma unroll
  for (int itr = 0; itr < 2; ++itr) {
    if (row0 + itr * 64 >= M) break;
    const int rb = row0 + itr * 64 + rowHalf;

    s16x8 Af[2][4];
#pragma unroll
    for (int mt = 0; mt < 2; ++mt) {
      if (E.amode == 0) {
        int row = rb + mt * 16 + c;
        int rr = row < M ? row : M - 1;
        const unsigned short* ap = E.A + (size_t)rr * 128;
#pragma unroll
        for (int s = 0; s < 4; ++s)
          Af[mt][s] = *reinterpret_cast<const s16x8*>(ap + s * 32 + 8 * g);
      } else {
        int r = itr * 64 + rowHalf + mt * 16 + c;   // local tile row
#pragma unroll
        for (int s = 0; s < 4; ++s) {
          int cb = (64 * s + 16 * g) ^ ((r & 7) << 4);
          Af[mt][s] = *reinterpret_cast<const s16x8*>(reinterpret_cast<char*>(ldsA) + r * 256 + cb);
        }
      }
    }

    f32x4 acc[2][4];
#pragma unroll
    for (int mt = 0; mt < 2; ++mt)
#pragma unroll
      for (int nb = 0; nb < 4; ++nb) { acc[mt][nb][0] = 0.f; acc[mt][nb][1] = 0.f; acc[mt][nb][2] = 0.f; acc[mt][nb][3] = 0.f; }

#pragma unroll
    for (int mt = 0; mt < 2; ++mt)
#pragma unroll
      for (int s = 0; s < 4; ++s)
#pragma unroll
        for (int nb = 0; nb < 4; ++nb)
          acc[mt][nb] = __builtin_amdgcn_mfma_f32_16x16x32_bf16(Af[mt][s], Bf[s][nb], acc[mt][nb], 0, 0, 0);

#pragma unroll
    for (int mt = 0; mt < 2; ++mt)
#pragma unroll
      for (int nb = 0; nb < 4; ++nb) {
        int col = colHalf + nb * 16 + c;
        float bv = E.bias ? E.bias[col] : 0.f;
#pragma unroll
        for (int jj = 0; jj < 4; ++jj) {
          int row = rb + mt * 16 + 4 * g + jj;
          if (row < M) {
            float v = acc[mt][nb][jj] + bv;
            if (E.act == 1) v = sigmoid_fast(v);
            if (E.outbf16) ((unsigned short*)E.out)[(size_t)row * 128 + col] = f2bf(v);
            else ((float*)E.out)[(size_t)row * 128 + col] = v;
          }
        }
      }
  }
}

// ---------------- folded attention weights ----------------
__global__ void wvbuild_kernel(const float* Wsrc, const float* Wdst, const float* bsrc, const float* bdst,
                               const float* attn, unsigned short* wv, float* bw, int l) {
  static const int RELT[3][4] = {{0, 2, 1, 3}, {3, 4, 2, 5}, {1, 5, 0, 4}};
  int t = blockIdx.x >> 4, col = blockIdx.x & 15;
  int b = col >> 2, h = col & 3;
  int r = RELT[t][b];
  bool isSrc = b < 2;
  const float* W = (isSrc ? Wsrc : Wdst) + (size_t)(l * 6 + r) * 16384;
  const float* bias = (isSrc ? bsrc : bdst) + (size_t)(l * 6 + r) * 128;
  const float* at = attn + (size_t)(l * 6 + r) * 128 + h * 32;
  int k = threadIdx.x;
  float acc = 0.f;
  for (int dh = 0; dh < 32; ++dh) acc += W[k * 128 + h * 32 + dh] * at[dh];
  wv[((size_t)t * 128 + k) * 16 + col] = f2bf(acc);
  if (k == 0) {
    float bacc = 0.f;
    for (int dh = 0; dh < 32; ++dh) bacc += bias[h * 32 + dh] * at[dh];
    bw[t * 16 + col] = bacc;
  }
}

// av16[row][16] = xs_bf[row] @ wv[type(row)] + bw
__global__ __launch_bounds__(256) void advec_kernel(const unsigned short* xs_bf,
                                                    const unsigned short* wv, const float* bw, float* av16) {
  int rb0 = blockIdx.x * 64 + (threadIdx.x >> 6) * 16;
  if (rb0 >= NTOT) return;
  int lane = threadIdx.x & 63, g = lane >> 4, c = lane & 15;
  int t = rb0 >= (NC_ + ND_) ? 2 : (rb0 >= NC_ ? 1 : 0);
  const unsigned short* wvt = wv + (size_t)t * 2048;
  s16x8 Bf[4];
#pragma unroll
  for (int s = 0; s < 4; ++s) {
    s16x8 bfr;
#pragma unroll
    for (int i = 0; i < 8; ++i) bfr[i] = (short)wvt[(s * 32 + 8 * g + i) * 16 + c];
    Bf[s] = bfr;
  }
  f32x4 acc; acc[0] = 0.f; acc[1] = 0.f; acc[2] = 0.f; acc[3] = 0.f;
  const unsigned short* ap = xs_bf + (size_t)(rb0 + c) * 128;
#pragma unroll
  for (int s = 0; s < 4; ++s) {
    s16x8 a = *reinterpret_cast<const s16x8*>(ap + s * 32 + 8 * g);
    acc = __builtin_amdgcn_mfma_f32_16x16x32_bf16(a, Bf[s], acc, 0, 0, 0);
  }
  float bv = bw[t * 16 + c];
#pragma unroll
  for (int jj = 0; jj < 4; ++jj)
    av16[(size_t)(rb0 + 4 * g + jj) * 16 + c] = acc[jj] + bv;
}

// ---------------- CSR build ----------------
struct CSRParams {
  const int* dst[6];
  int* cnt; int* rowp; int* cursor; int* col;
  int ndst[6];
};

__global__ __launch_bounds__(256) void hist_kernel(CSRParams P) {
  int gt = blockIdx.x * blockDim.x + threadIdx.x;
  int n = gridDim.x * blockDim.x;
  for (int idx = gt; idx < 6 * EE; idx += n) {
    int rel = idx / EE, i = idx - rel * EE;
    atomicAdd(&P.cnt[rel * 50000 + P.dst[rel][i]], 1);
  }
}

__global__ __launch_bounds__(1024) void scan_kernel(CSRParams P) {
  int rel = blockIdx.x;
  int n = P.ndst[rel];
  const int* c = P.cnt + rel * 50000;
  int* rp = P.rowp + rel * 50001;
  int* cur = P.cursor + rel * 50000;
  __shared__ int part[1024];
  int tid = threadIdx.x;
  int chunk = (n + 1023) / 1024;
  int lo = tid * chunk, hi = lo + chunk;
  if (hi > n) hi = n;
  int s = 0;
  for (int j = lo; j < hi; ++j) s += c[j];
  part[tid] = s;
  __syncthreads();
  if (tid == 0) {
    int acc = 0;
    for (int k = 0; k < 1024; ++k) { int v = part[k]; part[k] = acc; acc += v; }
    rp[n] = acc;
  }
  __syncthreads();
  int acc = part[tid];
  for (int j = lo; j < hi; ++j) { rp[j] = acc; cur[j] = acc; acc += c[j]; }
}

__global__ __launch_bounds__(256) void scatter_kernel(CSRParams P) {
  int gt = blockIdx.x * blockDim.x + threadIdx.x;
  int n = gridDim.x * blockDim.x;
  for (int idx = gt; idx < 6 * EE; idx += n) {
    int rel = idx / EE, i = idx - rel * EE;
    int d = P.dst[rel][i];
    int pos = atomicAdd(&P.cursor[rel * 50000 + d], 1);
    P.col[rel * EE + pos] = i;
  }
}

// ---------------- fused per-dst aggregation ----------------
struct AggRel {
  const int* src; const int* col; const int* rowp;
  const float* asv; const float* adv;
  const unsigned short* hs;
  const int* ea;
  int gtype;          // 0 none, 1 gtab rel0, 2 gtab rel1, 3 G buffer
};
struct AggGroup { int n; unsigned short* aggbf; AggRel rel[2]; };
struct AggParams {
  AggGroup grp[2]; int ngrp;
  const float* gtab; const unsigned short* G;
};

__global__ __launch_bounds__(256) void agg_kernel(AggParams P) {
  int wid = (blockIdx.x * 256 + threadIdx.x) >> 6;
  int lane = threadIdx.x & 63;
  int q = lane & 15, e4 = lane >> 4, h = q >> 2;
  int gi = 0, node = wid;
  if (node >= P.grp[0].n) {
    node -= P.grp[0].n; gi = 1;
    if (gi >= P.ngrp || node >= P.grp[1].n) return;
  }
  const AggGroup& Gr = P.grp[gi];
  float acc[8];
#pragma unroll
  for (int j = 0; j < 8; ++j) acc[j] = 0.f;

  for (int rs = 0; rs < 2; ++rs) {
    const AggRel& R = Gr.rel[rs];
    int rp = R.rowp[node], re = R.rowp[node + 1];
    if (rp == re) continue;
    float4 ad4 = *reinterpret_cast<const float4*>(R.adv + (size_t)node * 16);
    int deg = re - rp;

    if (deg <= 64) {
      float e0 = -1e30f, e1 = -1e30f, e2 = -1e30f, e3 = -1e30f;
      int i_e = 0, si_e = 0, gx_e = 0;
      int k = rp + lane;
      bool ok = k < re;
      if (ok) {
        i_e = R.col[k];
        si_e = R.src[i_e];
        float4 s4 = *reinterpret_cast<const float4*>(R.asv + (size_t)si_e * 16);
        e0 = s4.x + ad4.x; e0 = e0 > 0.f ? e0 : 0.2f * e0;
        e1 = s4.y + ad4.y; e1 = e1 > 0.f ? e1 : 0.2f * e1;
        e2 = s4.z + ad4.z; e2 = e2 > 0.f ? e2 : 0.2f * e2;
        e3 = s4.w + ad4.w; e3 = e3 > 0.f ? e3 : 0.2f * e3;
        if (R.gtype == 1 || R.gtype == 2)
          gx_e = R.ea[(size_t)i_e * 2] * 5 + R.ea[(size_t)i_e * 2 + 1];
      }
      float m0 = e0, m1 = e1, m2 = e2, m3 = e3;
#pragma unroll
      for (int d = 1; d < 64; d <<= 1) {
        m0 = fmaxf(m0, __shfl_xor(m0, d));
        m1 = fmaxf(m1, __shfl_xor(m1, d));
        m2 = fmaxf(m2, __shfl_xor(m2, d));
        m3 = fmaxf(m3, __shfl_xor(m3, d));
      }
      float s0 = ok ? __expf(e0 - m0) : 0.f;
      float s1 = ok ? __expf(e1 - m1) : 0.f;
      float s2 = ok ? __expf(e2 - m2) : 0.f;
      float s3 = ok ? __expf(e3 - m3) : 0.f;
#pragma unroll
      for (int d = 1; d < 64; d <<= 1) {
        s0 += __shfl_xor(s0, d);
        s1 += __shfl_xor(s1, d);
        s2 += __shfl_xor(s2, d);
        s3 += __shfl_xor(s3, d);
      }
      float mh = sel4(m0, m1, m2, m3, h);
      float invh = 1.f / (sel4(s0, s1, s2, s3, h) + 1e-16f);

      int nit = (deg + 3) >> 2;
      for (int it = 0; it < nit; ++it) {
        int j = it * 4 + e4;
        bool valid = j < deg;
        int sij = __shfl(si_e, j);
        int ij = __shfl(i_e, j);
        float v0 = __shfl(e0, j), v1 = __shfl(e1, j), v2 = __shfl(e2, j), v3 = __shfl(e3, j);
        float ehj = sel4(v0, v1, v2, v3, h);
        float alpha = valid ? __expf(ehj - mh) * invh : 0.f;
        s16x8 ms = *reinterpret_cast<const s16x8*>(R.hs + (size_t)sij * 128 + 8 * q);
        if (R.gtype == 0) {
#pragma unroll
          for (int j2 = 0; j2 < 8; ++j2) acc[j2] += alpha * bf2f((unsigned short)ms[j2]);
        } else if (R.gtype == 3) {
          s16x8 gq = *reinterpret_cast<const s16x8*>(P.G + (size_t)ij * 128 + 8 * q);
#pragma unroll
          for (int j2 = 0; j2 < 8; ++j2) acc[j2] += alpha * bf2f((unsigned short)ms[j2]) * bf2f((unsigned short)gq[j2]);
        } else {
          int gxj = __shfl(gx_e, j);
          const float* gp = P.gtab + (size_t)((R.gtype - 1) * 50 + gxj) * 128 + 8 * q;
          float4 g0 = *reinterpret_cast<const float4*>(gp);
          float4 g1 = *reinterpret_cast<const float4*>(gp + 4);
          acc[0] += alpha * bf2f((unsigned short)ms[0]) * g0.x;
          acc[1] += alpha * bf2f((unsigned short)ms[1]) * g0.y;
          acc[2] += alpha * bf2f((unsigned short)ms[2]) * g0.z;
          acc[3] += alpha * bf2f((unsigned short)ms[3]) * g0.w;
          acc[4] += alpha * bf2f((unsigned short)ms[4]) * g1.x;
          acc[5] += alpha * bf2f((unsigned short)ms[5]) * g1.y;
          acc[6] += alpha * bf2f((unsigned short)ms[6]) * g1.z;
          acc[7] += alpha * bf2f((unsigned short)ms[7]) * g1.w;
        }
      }
    } else {
      float m0 = -1e30f, m1 = -1e30f, m2 = -1e30f, m3 = -1e30f;
      float s0 = 0.f, s1 = 0.f, s2 = 0.f, s3 = 0.f;
      for (int b = rp; b < re; b += 64) {
        int k = b + lane;
        if (k < re) {
          int i = R.col[k];
          int si = R.src[i];
          float4 s4 = *reinterpret_cast<const float4*>(R.asv + (size_t)si * 16);
          float e0 = s4.x + ad4.x; e0 = e0 > 0.f ? e0 : 0.2f * e0;
          float e1 = s4.y + ad4.y; e1 = e1 > 0.f ? e1 : 0.2f * e1;
          float e2 = s4.z + ad4.z; e2 = e2 > 0.f ? e2 : 0.2f * e2;
          float e3 = s4.w + ad4.w; e3 = e3 > 0.f ? e3 : 0.2f * e3;
          m0 = fmaxf(m0, e0); m1 = fmaxf(m1, e1); m2 = fmaxf(m2, e2); m3 = fmaxf(m3, e3);
        }
      }
#pragma unroll
      for (int d = 1; d < 64; d <<= 1) {
        m0 = fmaxf(m0, __shfl_xor(m0, d));
        m1 = fmaxf(m1, __shfl_xor(m1, d));
        m2 = fmaxf(m2, __shfl_xor(m2, d));
        m3 = fmaxf(m3, __shfl_xor(m3, d));
      }
      for (int b = rp; b < re; b += 64) {
        int k = b + lane;
        if (k < re) {
          int i = R.col[k];
          int si = R.src[i];
          float4 s4 = *reinterpret_cast<const float4*>(R.asv + (size_t)si * 16);
          float e0 = s4.x + ad4.x; e0 = e0 > 0.f ? e0 : 0.2f * e0;
          float e1 = s4.y + ad4.y; e1 = e1 > 0.f ? e1 : 0.2f * e1;
          float e2 = s4.z + ad4.z; e2 = e2 > 0.f ? e2 : 0.2f * e2;
          float e3 = s4.w + ad4.w; e3 = e3 > 0.f ? e3 : 0.2f * e3;
          s0 += __expf(e0 - m0); s1 += __expf(e1 - m1); s2 += __expf(e2 - m2); s3 += __expf(e3 - m3);
        }
      }
#pragma unroll
      for (int d = 1; d < 64; d <<= 1) {
        s0 += __shfl_xor(s0, d);
        s1 += __shfl_xor(s1, d);
        s2 += __shfl_xor(s2, d);
        s3 += __shfl_xor(s3, d);
      }
      float mh = sel4(m0, m1, m2, m3, h);
      float invh = 1.f / (sel4(s0, s1, s2, s3, h) + 1e-16f);
      float adh = sel4(ad4.x, ad4.y, ad4.z, ad4.w, h);
      int nit = (deg + 3) >> 2;
      for (int it = 0; it < nit; ++it) {
        int k = rp + it * 4 + e4;
        bool valid = k < re;
        int kk = valid ? k : re - 1;
        int i = R.col[kk];
        int si = R.src[i];
        float eh = R.asv[(size_t)si * 16 + h] + adh;
        eh = eh > 0.f ? eh : 0.2f * eh;
        float alpha = valid ? __expf(eh - mh) * invh : 0.f;
        s16x8 ms = *reinterpret_cast<const s16x8*>(R.hs + (size_t)si * 128 + 8 * q);
        if (R.gtype == 0) {
#pragma unroll
          for (int j2 = 0; j2 < 8; ++j2) acc[j2] += alpha * bf2f((unsigned short)ms[j2]);
        } else if (R.gtype == 3) {
          s16x8 gq = *reinterpret_cast<const s16x8*>(P.G + (size_t)i * 128 + 8 * q);
#pragma unroll
          for (int j2 = 0; j2 < 8; ++j2) acc[j2] += alpha * bf2f((unsigned short)ms[j2]) * bf2f((unsigned short)gq[j2]);
        } else {
          int a = R.ea[(size_t)i * 2], s2i = R.ea[(size_t)i * 2 + 1];
          const float* gp = P.gtab + (size_t)((R.gtype - 1) * 50 + a * 5 + s2i) * 128 + 8 * q;
          float4 g0 = *reinterpret_cast<const float4*>(gp);
          float4 g1 = *reinterpret_cast<const float4*>(gp + 4);
          acc[0] += alpha * bf2f((unsigned short)ms[0]) * g0.x;
          acc[1] += alpha * bf2f((unsigned short)ms[1]) * g0.y;
          acc[2] += alpha * bf2f((unsigned short)ms[2]) * g0.z;
          acc[3] += alpha * bf2f((unsigned short)ms[3]) * g0.w;
          acc[4] += alpha * bf2f((unsigned short)ms[4]) * g1.x;
          acc[5] += alpha * bf2f((unsigned short)ms[5]) * g1.y;
          acc[6] += alpha * bf2f((unsigned short)ms[6]) * g1.z;
          acc[7] += alpha * bf2f((unsigned short)ms[7]) * g1.w;
        }
      }
    }
  }
#pragma unroll
  for (int j = 0; j < 8; ++j) {
    acc[j] += __shfl_xor(acc[j], 16);
    acc[j] += __shfl_xor(acc[j], 32);
  }
  if (e4 == 0) {
    s16x8 o;
#pragma unroll
    for (int j = 0; j < 8; ++j) o[j] = (short)f2bf(acc[j]);
    *reinterpret_cast<s16x8*>(Gr.aggbf + (size_t)node * 128 + 8 * q) = o;
  }
}

// categorical gate table
__global__ void gatetab_kernel(const float* at_emb, const float* as_emb,
                               const float* Wcat, const float* bcat, float* gtab, int l) {
  int rel = blockIdx.x / 50, combo = blockIdx.x % 50;
  int a = combo / 5, s2 = combo % 5;
  int d = threadIdx.x;
  const float* Wb = Wcat + (size_t)(l * 2 + rel) * 64 * 128;
  float acc = bcat[(size_t)(l * 2 + rel) * 128 + d];
  const float* ae = at_emb + (size_t)(l * 10 + a) * 32;
  const float* se = as_emb + (size_t)(l * 5 + s2) * 32;
  for (int k = 0; k < 32; ++k) acc += ae[k] * Wb[k * 128 + d];
  for (int k = 0; k < 32; ++k) acc += se[k] * Wb[(32 + k) * 128 + d];
  gtab[(size_t)(rel * 50 + combo) * 128 + d] = 1.f / (1.f + __expf(-acc));
}

// LayerNorm(xs + tmp) -> xs (f32) and xs_bf (bf16)
__global__ __launch_bounds__(256) void ln_kernel(float* xs, unsigned short* xs_bf, const float* tmp,
                                                 const float* g_base, const float* b_base) {
  int wid = (blockIdx.x * blockDim.x + threadIdx.x) >> 6;
  int lane = threadIdx.x & 63;
  int nw = (gridDim.x * blockDim.x) >> 6;
  for (int row = wid; row < NTOT; row += nw) {
    int t = row < NC_ ? 0 : (row < NC_ + ND_ ? 1 : 2);
    size_t ro = (size_t)row * 128 + 2 * lane;
    float2 x = *reinterpret_cast<const float2*>(xs + ro);
    float2 tv = *reinterpret_cast<const float2*>(tmp + ro);
    float a = x.x + tv.x, b = x.y + tv.y;
    float s = a + b;
#pragma unroll
    for (int m = 1; m <= 32; m <<= 1) s += __shfl_xor(s, m);
    float mu = s * 0.0078125f;
    float da = a - mu, db = b - mu;
    float v = da * da + db * db;
#pragma unroll
    for (int m = 1; m <= 32; m <<= 1) v += __shfl_xor(v, m);
    float rs = rsqrtf(v * 0.0078125f + 1e-5f);
    float2 gg = *reinterpret_cast<const float2*>(g_base + t * 128 + 2 * lane);
    float2 bb = *reinterpret_cast<const float2*>(b_base + t * 128 + 2 * lane);
    float2 o;
    o.x = da * rs * gg.x + bb.x;
    o.y = db * rs * gg.y + bb.y;
    *reinterpret_cast<float2*>(xs + ro) = o;
    ushort2 ob; ob.x = f2bf(o.x); ob.y = f2bf(o.y);
    *reinterpret_cast<ushort2*>(xs_bf + ro) = ob;
  }
}

// init: xs (f32) + xs_bf (bf16)
__global__ __launch_bounds__(256) void cvt_init_kernel(const float* emb_c, const float* emb_d, const float* emb_g,
                                                       float* xs, unsigned short* xs_bf) {
  int i = blockIdx.x * 256 + threadIdx.x;
  if (i >= NTOT * 64) return;
  int row = i >> 6;
  int cpos = (i & 63) * 2;
  const float* src;
  if (row < NC_) src = emb_c + (size_t)row * 128;
  else if (row < NC_ + ND_) src = emb_d + (size_t)(row - NC_) * 128;
  else src = emb_g + (size_t)(row - NC_ - ND_) * 128;
  float2 v = *reinterpret_cast<const float2*>(src + cpos);
  *reinterpret_cast<float2*>(xs + (size_t)row * 128 + cpos) = v;
  ushort2 ob; ob.x = f2bf(v.x); ob.y = f2bf(v.y);
  *reinterpret_cast<ushort2*>(xs_bf + (size_t)row * 128 + cpos) = ob;
}

// out[p] = dot(Ybf[ps[p]], x1bf[pd[p]]) — half-wave per pair, bf16 gathers
__global__ __launch_bounds__(256) void pair_kernel(const unsigned short* Ybf, const unsigned short* x1bf,
                                                   const int* ps, const int* pd, float* out) {
  int hw = (blockIdx.x * blockDim.x + threadIdx.x) >> 5;
  int lane = threadIdx.x & 31;
  int nhw = (gridDim.x * blockDim.x) >> 5;
  for (int p = hw; p < PP_; p += nhw) {
    int ai = ps[p], bi = pd[p];
    ushort4 y = *reinterpret_cast<const ushort4*>(Ybf + (size_t)ai * 128 + 4 * lane);
    ushort4 x = *reinterpret_cast<const ushort4*>(x1bf + (size_t)bi * 128 + 4 * lane);
    float s = bf2f(y.x) * bf2f(x.x) + bf2f(y.y) * bf2f(x.y) +
              bf2f(y.z) * bf2f(x.z) + bf2f(y.w) * bf2f(x.w);
#pragma unroll
    for (int m = 1; m <= 16; m <<= 1) s += __shfl_xor(s, m, 32);
    if (lane == 0) out[p] = s;
  }
}

__global__ void fill_kernel(float* out, int n, float v) {
  int i = blockIdx.x * blockDim.x + threadIdx.x;
  if (i < n) out[i] = v;
}

// ---------------- host ----------------
extern "C" void kernel_launch(void* const* d_in, const int* in_sizes, int n_in,
                              void* d_out, int out_size, void* d_ws, size_t ws_size,
                              hipStream_t stream) {
  (void)in_sizes; (void)n_in;
  const float* emb_c = (const float*)d_in[0];
  const float* emb_d = (const float*)d_in[1];
  const float* emb_g = (const float*)d_in[2];
  const float* Wsrc  = (const float*)d_in[3];
  const float* bsrc  = (const float*)d_in[4];
  const float* Wdst  = (const float*)d_in[5];
  const float* bdst  = (const float*)d_in[6];
  const float* attn  = (const float*)d_in[7];
  const float* Wout  = (const float*)d_in[8];
  const float* bout  = (const float*)d_in[9];
  const float* ln_g  = (const float*)d_in[10];
  const float* ln_b  = (const float*)d_in[11];
  const float* at_emb = (const float*)d_in[12];
  const float* as_emb = (const float*)d_in[13];
  const float* Wcat  = (const float*)d_in[14];
  const float* bcat  = (const float*)d_in[15];
  const float* Wc1   = (const float*)d_in[16];
  const float* bc1   = (const float*)d_in[17];
  const float* Wc2   = (const float*)d_in[18];
  const float* bc2   = (const float*)d_in[19];
  const float* W_cd  = (const float*)d_in[20];
  const float* ea4   = (const float*)d_in[21];
  const float* ea5   = (const float*)d_in[22];
  const int* srcs[6] = {(const int*)d_in[23], (const int*)d_in[25], (const int*)d_in[27],
                        (const int*)d_in[29], (const int*)d_in[31], (const int*)d_in[33]};
  const int* dsts[6] = {(const int*)d_in[24], (const int*)d_in[26], (const int*)d_in[28],
                        (const int*)d_in[30], (const int*)d_in[32], (const int*)d_in[34]};
  const int* ea0 = (const int*)d_in[35];
  const int* ea1 = (const int*)d_in[36];
  const int* pair_src = (const int*)d_in[37];
  const int* pair_dst = (const int*)d_in[38];

  static const int ST_[6] = {0, 2, 0, 1, 1, 2};
  static const int DT_[6] = {2, 0, 1, 0, 2, 1};
  static const int NT_[3] = {NC_, ND_, NG_};
  static const int HSOFF[6] = {0, 50000, 80000, 130000, 150000, 170000};
  static const int SBLK[6] = {0, 0, 1, 0, 1, 1};
  static const int DBLK[6] = {2, 2, 2, 3, 3, 3};
  static const int rowbase[3] = {0, 50000, 70000};

  size_t off = 0;
  auto alloc = [&](size_t bytes) { off = (off + 255) & ~(size_t)255; size_t o = off; off += bytes; return o; };
  size_t o_xs    = alloc((size_t)NTOT * 512);
  size_t o_xsbf  = alloc((size_t)NTOT * 256);
  size_t o_agbf  = alloc((size_t)NTOT * 256);
  size_t o_hs    = alloc((size_t)200000 * 256);       // bf16 src proj | tmp f32 | Y bf16
  size_t o_G     = alloc((size_t)200000 * 256);       // bf16 gates (G4 then G5)
  size_t o_av    = alloc((size_t)NTOT * 64);
  size_t o_wv    = alloc((size_t)3 * 128 * 16 * 2);
  size_t o_bw    = alloc((size_t)3 * 16 * 4);
  size_t o_gtab  = alloc((size_t)100 * 512);
  size_t o_wpack = alloc((size_t)23 * 16384 * 2);
  size_t o_cnt   = alloc((size_t)6 * 50000 * 4);
  size_t o_rowp  = alloc((size_t)6 * 50001 * 4);
  size_t o_cur   = alloc((size_t)6 * 50000 * 4);
  size_t o_col   = alloc((size_t)6 * EE * 4);
  if (off > ws_size) {
    fill_kernel<<<(PP_ + 255) / 256, 256, 0, stream>>>((float*)d_out, out_size, 1.0e6f);
    return;
  }

  char* ws = (char*)d_ws;
  float* xs = (float*)(ws + o_xs);
  unsigned short* xs_bf = (unsigned short*)(ws + o_xsbf);
  unsigned short* agg_bf = (unsigned short*)(ws + o_agbf);
  unsigned short* hs = (unsigned short*)(ws + o_hs);
  float* tmp = (float*)(ws + o_hs);
  unsigned short* Ybf = (unsigned short*)(ws + o_hs);
  unsigned short* G = (unsigned short*)(ws + o_G);
  float* av16 = (float*)(ws + o_av);
  unsigned short* wv = (unsigned short*)(ws + o_wv);
  float* bw = (float*)(ws + o_bw);
  float* gtab = (float*)(ws + o_gtab);
  unsigned short* wpack = (unsigned short*)(ws + o_wpack);
  int* cnt = (int*)(ws + o_cnt);
  int* rowp = (int*)(ws + o_rowp);
  int* cursor = (int*)(ws + o_cur);
  int* col = (int*)(ws + o_col);

  // prepack all weights (layout: l*11 + {0-5 proj, 6-7 Wc2, 8-10 Wout}; 22 = W_cd)
  PackParams pk{};
  for (int l = 0; l < 2; ++l) {
    for (int r = 0; r < 6; ++r) pk.src[l * 11 + r] = Wsrc + (size_t)(l * 6 + r) * 16384;
    for (int k = 0; k < 2; ++k) pk.src[l * 11 + 6 + k] = Wc2 + (size_t)(l * 2 + k) * 16384;
    for (int t = 0; t < 3; ++t) pk.src[l * 11 + 8 + t] = Wout + (size_t)(l * 3 + t) * 16384;
  }
  pk.src[22] = W_cd;
  pk.dst = wpack;
  pack_kernel<<<23, 256, 0, stream>>>(pk);

  cvt_init_kernel<<<(NTOT * 64 + 255) / 256, 256, 0, stream>>>(emb_c, emb_d, emb_g, xs, xs_bf);

  hipMemsetAsync(cnt, 0, (size_t)6 * 50000 * 4, stream);
  CSRParams cp{};
  for (int r = 0; r < 6; ++r) { cp.dst[r] = dsts[r]; cp.ndst[r] = NT_[DT_[r]]; }
  cp.cnt = cnt; cp.rowp = rowp; cp.cursor = cursor; cp.col = col;
  hist_kernel<<<2048, 256, 0, stream>>>(cp);
  scan_kernel<<<6, 1024, 0, stream>>>(cp);
  scatter_kernel<<<2048, 256, 0, stream>>>(cp);

  auto nb = [](int M) { return (M + 127) / 128; };

  for (int l = 0; l < 2; ++l) {
    gatetab_kernel<<<100, 128, 0, stream>>>(at_emb, as_emb, Wcat, bcat, gtab, l);
    wvbuild_kernel<<<48, 128, 0, stream>>>(Wsrc, Wdst, bsrc, bdst, attn, wv, bw, l);

    // one dispatch: 6 projections + G4 gate
    GParams2 gp{};
    int blk = 0;
    for (int r = 0; r < 6; ++r) {
      int st = ST_[r];
      gp.e[r] = {xs_bf + (size_t)rowbase[st] * 128, wpack + (size_t)(l * 11 + r) * 16384,
                 bsrc + (size_t)(l * 6 + r) * 128, (void*)(hs + (size_t)HSOFF[r] * 128),
                 nullptr, nullptr, nullptr, NT_[st], 0, 0, 1, blk};
      blk += nb(NT_[st]);
    }
    gp.e[6] = {nullptr, wpack + (size_t)(l * 11 + 6) * 16384, bc2 + (size_t)(l * 2 + 0) * 128, (void*)G,
               ea4, Wc1 + (size_t)(l * 2 + 0) * 256, bc1 + (size_t)(l * 2 + 0) * 128, EE, 2, 1, 1, blk};
    blk += nb(EE);
    gp.nent = 7;
    gemm2<<<blk, 256, 0, stream>>>(gp);

    advec_kernel<<<(NTOT + 63) / 64, 256, 0, stream>>>(xs_bf, wv, bw, av16);

    auto mkrel = [&](int r) {
      AggRel R;
      R.src = srcs[r]; R.col = col + (size_t)r * EE; R.rowp = rowp + (size_t)r * 50001;
      R.asv = av16 + (size_t)rowbase[ST_[r]] * 16 + SBLK[r] * 4;
      R.adv = av16 + (size_t)rowbase[DT_[r]] * 16 + DBLK[r] * 4;
      R.hs = hs + (size_t)HSOFF[r] * 128;
      R.ea = (r == 0) ? ea0 : (r == 1) ? ea1 : nullptr;
      R.gtype = (r == 0) ? 1 : (r == 1) ? 2 : (r >= 4) ? 3 : 0;
      return R;
    };

    AggParams pa{};
    pa.grp[0].n = NG_; pa.grp[0].aggbf = agg_bf + (size_t)rowbase[2] * 128;
    pa.grp[0].rel[0] = mkrel(0); pa.grp[0].rel[1] = mkrel(4);
    pa.grp[1].n = NC_; pa.grp[1].aggbf = agg_bf + (size_t)rowbase[0] * 128;
    pa.grp[1].rel[0] = mkrel(1); pa.grp[1].rel[1] = mkrel(3);
    pa.ngrp = 2; pa.gtab = gtab; pa.G = G;
    agg_kernel<<<(NG_ + NC_) / 4, 256, 0, stream>>>(pa);

    // G5 gate (reuses G buffer after agg A consumed G4)
    GParams2 g5{};
    g5.e[0] = {nullptr, wpack + (size_t)(l * 11 + 7) * 16384, bc2 + (size_t)(l * 2 + 1) * 128, (void*)G,
               ea5, Wc1 + (size_t)(l * 2 + 1) * 256, bc1 + (size_t)(l * 2 + 1) * 128, EE, 2, 1, 1, 0};
    g5.nent = 1;
    gemm2<<<nb(EE), 256, 0, stream>>>(g5);

    AggParams pb{};
    pb.grp[0].n = ND_; pb.grp[0].aggbf = agg_bf + (size_t)rowbase[1] * 128;
    pb.grp[0].rel[0] = mkrel(2); pb.grp[0].rel[1] = mkrel(5);
    pb.grp[1].n = 0; pb.grp[1].aggbf = nullptr;
    pb.grp[1].rel[0] = mkrel(2); pb.grp[1].rel[1] = mkrel(5);
    pb.ngrp = 1; pb.gtab = gtab; pb.G = G;
    agg_kernel<<<(ND_) / 4, 256, 0, stream>>>(pb);

    // Wout (3 entries, one dispatch) -> tmp f32 (aliases hs, dead after agg)
    GParams2 gw{};
    blk = 0;
    for (int t = 0; t < 3; ++t) {
      gw.e[t] = {agg_bf + (size_t)rowbase[t] * 128, wpack + (size_t)(l * 11 + 8 + t) * 16384,
                 bout + (size_t)(l * 3 + t) * 128, (void*)(tmp + (size_t)rowbase[t] * 128),
                 nullptr, nullptr, nullptr, NT_[t], 0, 0, 0, blk};
      blk += nb(NT_[t]);
    }
    gw.nent = 3;
    gemm2<<<blk, 256, 0, stream>>>(gw);

    ln_kernel<<<2048, 256, 0, stream>>>(xs, xs_bf, tmp, ln_g + (size_t)l * 384, ln_b + (size_t)l * 384);
  }

  // Y = xs0 @ W_cd -> bf16 (aliases hs/tmp region, dead now)
  GParams2 gy{};
  gy.e[0] = {xs_bf, wpack + (size_t)22 * 16384, nullptr, (void*)Ybf,
             nullptr, nullptr, nullptr, NC_, 0, 0, 1, 0};
  gy.nent = 1;
  gemm2<<<nb(NC_), 256, 0, stream>>>(gy);

  pair_kernel<<<2048, 256, 0, stream>>>(Ybf, xs_bf + (size_t)NC_ * 128, pair_src, pair_dst, (float*)d_out);
}

// Round 9
// 1230.884 us; speedup vs baseline: 5.2753x; 1.1179x over previous
//
#include <hip/hip_runtime.h>

typedef short s16x8 __attribute__((ext_vector_type(8)));
typedef float f32x4 __attribute__((ext_vector_type(4)));

#define DEV __device__ __forceinline__

static constexpr int NC_ = 50000, ND_ = 20000, NG_ = 30000;
static constexpr int EE = 200000, PP_ = 200000;
static constexpr int NTOT = NC_ + ND_ + NG_;   // 100000

DEV unsigned short f2bf(float f) {
  unsigned u = __float_as_uint(f);
  u = u + 0x7FFFu + ((u >> 16) & 1u);
  return (unsigned short)(u >> 16);
}
DEV float bf2f(unsigned short h) { return __uint_as_float(((unsigned)h) << 16); }
DEV float sel4(float a, float b, float c, float d, int h) {
  float lo = (h & 1) ? b : a;
  float hi = (h & 1) ? d : c;
  return (h & 2) ? hi : lo;
}
DEV float fast_rcp(float x) {
#if __has_builtin(__builtin_amdgcn_rcpf)
  return __builtin_amdgcn_rcpf(x);
#else
  return 1.f / x;
#endif
}
DEV float gelu_fast(float x) { return x * fast_rcp(1.f + __expf(-1.702f * x)); }
DEV float sigmoid_fast(float x) { return fast_rcp(1.f + __expf(-x)); }

// ---------------- weight prepack: f32 [k][n] -> bf16 fragment-linear ----------------
struct PackParams { const float* src[23]; unsigned short* dst; };
__global__ __launch_bounds__(256) void pack_kernel(PackParams P) {
  int m = blockIdx.x;
  const float* S = P.src[m];
  unsigned short* D = P.dst + (size_t)m * 16384;
  for (int idx = threadIdx.x; idx < 16384; idx += 256) {
    int j = idx & 7;
    int lane = (idx >> 3) & 63;
    int snb = idx >> 9;
    int s = snb >> 3, nbb = snb & 7;
    int k = s * 32 + 8 * (lane >> 4) + j;
    int n = nbb * 16 + (lane & 15);
    D[idx] = f2bf(S[k * 128 + n]);
  }
}

// ---------------- flattened batched 128-col GEMM ----------------
struct GEntry2 {
  const unsigned short* A; const unsigned short* Wp; const float* bias; void* out;
  const float* ea; const float* Wc1; const float* bc1;
  int M; int amode; int act; int outbf16; int blk0;
};
struct GParams2 { GEntry2 e[8]; int nent; };

__global__ __launch_bounds__(256) void gemm2(GParams2 P) {
  int bx = blockIdx.x;
  int ei = 0;
  while (ei + 1 < P.nent && bx >= P.e[ei + 1].blk0) ++ei;
  GEntry2 E = P.e[ei];
  const int M = E.M;
  const int row0 = (bx - E.blk0) * 128;
  if (row0 >= M) return;

  const int tid = threadIdx.x;
  const int w = tid >> 6, lane = tid & 63, g = lane >> 4, c = lane & 15;
  const int colHalf = (w & 1) * 64;
  const int rowHalf = (w >> 1) * 32;

  __shared__ __align__(16) unsigned short ldsA[128 * 128];
  __shared__ float ldsC1[384];

  if (E.amode == 2) {
    if (tid < 128) {
      ldsC1[tid] = E.Wc1[tid];
      ldsC1[128 + tid] = E.Wc1[128 + tid];
      ldsC1[256 + tid] = E.bc1[tid];
    }
    __syncthreads();
    for (int i = tid; i < 16384; i += 256) {
      int r = i >> 7, colx = i & 127;
      int row = row0 + r;
      int rr = row < M ? row : M - 1;
      float e0 = E.ea[(size_t)rr * 2], e1 = E.ea[(size_t)rr * 2 + 1];
      float h = e0 * ldsC1[colx] + e1 * ldsC1[128 + colx] + ldsC1[256 + colx];
      unsigned short hv = f2bf(gelu_fast(h));
      int cb = (colx * 2) ^ ((r & 7) << 4);
      *reinterpret_cast<unsigned short*>(reinterpret_cast<char*>(ldsA) + r * 256 + cb) = hv;
    }
    __syncthreads();
  }

  s16x8 Bf[4][4];
#pragma unroll
  for (int s = 0; s < 4; ++s)
#pragma unroll
    for (int nb = 0; nb < 4; ++nb) {
      int nbb = (w & 1) * 4 + nb;
      Bf[s][nb] = *reinterpret_cast<const s16x8*>(E.Wp + ((size_t)(s * 8 + nbb) * 64 + lane) * 8);
    }

#pragma unroll
  for (int itr = 0; itr < 2; ++itr) {
    if (row0 + itr * 64 >= M) break;
    const int rb = row0 + itr * 64 + rowHalf;

    s16x8 Af[2][4];
#pragma unroll
    for (int mt = 0; mt < 2; ++mt) {
      if (E.amode == 0) {
        int row = rb + mt * 16 + c;
        int rr = row < M ? row : M - 1;
        const unsigned short* ap = E.A + (size_t)rr * 128;
#pragma unroll
        for (int s = 0; s < 4; ++s)
          Af[mt][s] = *reinterpret_cast<const s16x8*>(ap + s * 32 + 8 * g);
      } else {
        int r = itr * 64 + rowHalf + mt * 16 + c;
#pragma unroll
        for (int s = 0; s < 4; ++s) {
          int cb = (64 * s + 16 * g) ^ ((r & 7) << 4);
          Af[mt][s] = *reinterpret_cast<const s16x8*>(reinterpret_cast<char*>(ldsA) + r * 256 + cb);
        }
      }
    }

    f32x4 acc[2][4];
#pragma unroll
    for (int mt = 0; mt < 2; ++mt)
#pragma unroll
      for (int nb = 0; nb < 4; ++nb) { acc[mt][nb][0] = 0.f; acc[mt][nb][1] = 0.f; acc[mt][nb][2] = 0.f; acc[mt][nb][3] = 0.f; }

#pragma unroll
    for (int mt = 0; mt < 2; ++mt)
#pragma unroll
      for (int s = 0; s < 4; ++s)
#pragma unroll
        for (int nb = 0; nb < 4; ++nb)
          acc[mt][nb] = __builtin_amdgcn_mfma_f32_16x16x32_bf16(Af[mt][s], Bf[s][nb], acc[mt][nb], 0, 0, 0);

#pragma unroll
    for (int mt = 0; mt < 2; ++mt)
#pragma unroll
      for (int nb = 0; nb < 4; ++nb) {
        int col = colHalf + nb * 16 + c;
        float bv = E.bias ? E.bias[col] : 0.f;
#pragma unroll
        for (int jj = 0; jj < 4; ++jj) {
          int row = rb + mt * 16 + 4 * g + jj;
          if (row < M) {
            float v = acc[mt][nb][jj] + bv;
            if (E.act == 1) v = sigmoid_fast(v);
            if (E.outbf16) ((unsigned short*)E.out)[(size_t)row * 128 + col] = f2bf(v);
            else ((float*)E.out)[(size_t)row * 128 + col] = v;
          }
        }
      }
  }
}

// ---------------- folded attention weights ----------------
__global__ void wvbuild_kernel(const float* Wsrc, const float* Wdst, const float* bsrc, const float* bdst,
                               const float* attn, unsigned short* wv, float* bw, int l) {
  static const int RELT[3][4] = {{0, 2, 1, 3}, {3, 4, 2, 5}, {1, 5, 0, 4}};
  int t = blockIdx.x >> 4, col = blockIdx.x & 15;
  int b = col >> 2, h = col & 3;
  int r = RELT[t][b];
  bool isSrc = b < 2;
  const float* W = (isSrc ? Wsrc : Wdst) + (size_t)(l * 6 + r) * 16384;
  const float* bias = (isSrc ? bsrc : bdst) + (size_t)(l * 6 + r) * 128;
  const float* at = attn + (size_t)(l * 6 + r) * 128 + h * 32;
  int k = threadIdx.x;
  float acc = 0.f;
  for (int dh = 0; dh < 32; ++dh) acc += W[k * 128 + h * 32 + dh] * at[dh];
  wv[((size_t)t * 128 + k) * 16 + col] = f2bf(acc);
  if (k == 0) {
    float bacc = 0.f;
    for (int dh = 0; dh < 32; ++dh) bacc += bias[h * 32 + dh] * at[dh];
    bw[t * 16 + col] = bacc;
  }
}

// av16[row][16] = xs_bf[row] @ wv[type(row)] + bw
__global__ __launch_bounds__(256) void advec_kernel(const unsigned short* xs_bf,
                                                    const unsigned short* wv, const float* bw, float* av16) {
  int rb0 = blockIdx.x * 64 + (threadIdx.x >> 6) * 16;
  if (rb0 >= NTOT) return;
  int lane = threadIdx.x & 63, g = lane >> 4, c = lane & 15;
  int t = rb0 >= (NC_ + ND_) ? 2 : (rb0 >= NC_ ? 1 : 0);
  const unsigned short* wvt = wv + (size_t)t * 2048;
  s16x8 Bf[4];
#pragma unroll
  for (int s = 0; s < 4; ++s) {
    s16x8 bfr;
#pragma unroll
    for (int i = 0; i < 8; ++i) bfr[i] = (short)wvt[(s * 32 + 8 * g + i) * 16 + c];
    Bf[s] = bfr;
  }
  f32x4 acc; acc[0] = 0.f; acc[1] = 0.f; acc[2] = 0.f; acc[3] = 0.f;
  const unsigned short* ap = xs_bf + (size_t)(rb0 + c) * 128;
#pragma unroll
  for (int s = 0; s < 4; ++s) {
    s16x8 a = *reinterpret_cast<const s16x8*>(ap + s * 32 + 8 * g);
    acc = __builtin_amdgcn_mfma_f32_16x16x32_bf16(a, Bf[s], acc, 0, 0, 0);
  }
  float bv = bw[t * 16 + c];
#pragma unroll
  for (int jj = 0; jj < 4; ++jj)
    av16[(size_t)(rb0 + 4 * g + jj) * 16 + c] = acc[jj] + bv;
}

// ---------------- CSR build ----------------
struct CSRParams {
  const int* dst[6];
  int* cnt; int* rowp; int* cursor; int* col;
  int ndst[6];
};

__global__ __launch_bounds__(256) void hist_kernel(CSRParams P) {
  int gt = blockIdx.x * blockDim.x + threadIdx.x;
  int n = gridDim.x * blockDim.x;
  for (int idx = gt; idx < 6 * EE; idx += n) {
    int rel = idx / EE, i = idx - rel * EE;
    atomicAdd(&P.cnt[rel * 50000 + P.dst[rel][i]], 1);
  }
}

__global__ __launch_bounds__(1024) void scan_kernel(CSRParams P) {
  int rel = blockIdx.x;
  int n = P.ndst[rel];
  const int* c = P.cnt + rel * 50000;
  int* rp = P.rowp + rel * 50001;
  int* cur = P.cursor + rel * 50000;
  __shared__ int part[1024];
  int tid = threadIdx.x;
  int chunk = (n + 1023) / 1024;
  int lo = tid * chunk, hi = lo + chunk;
  if (hi > n) hi = n;
  int s = 0;
  for (int j = lo; j < hi; ++j) s += c[j];
  part[tid] = s;
  __syncthreads();
  if (tid == 0) {
    int acc = 0;
    for (int k = 0; k < 1024; ++k) { int v = part[k]; part[k] = acc; acc += v; }
    rp[n] = acc;
  }
  __syncthreads();
  int acc = part[tid];
  for (int j = lo; j < hi; ++j) { rp[j] = acc; cur[j] = acc; acc += c[j]; }
}

__global__ __launch_bounds__(256) void scatter_kernel(CSRParams P) {
  int gt = blockIdx.x * blockDim.x + threadIdx.x;
  int n = gridDim.x * blockDim.x;
  for (int idx = gt; idx < 6 * EE; idx += n) {
    int rel = idx / EE, i = idx - rel * EE;
    int d = P.dst[rel][i];
    int pos = atomicAdd(&P.cursor[rel * 50000 + d], 1);
    P.col[rel * EE + pos] = i;
  }
}

// ---------------- fused per-dst aggregation: 16 lanes/node, 4 nodes/wave ----------------
struct AggRel {
  const int* src; const int* col; const int* rowp;
  const float* asv; const float* adv;
  const unsigned short* hs;
  const int* ea;
  const unsigned short* G;
  int gtype;          // 0 none, 1 gtab rel0, 2 gtab rel1, 3 G buffer
};
struct AggGroup { int n; unsigned short* aggbf; AggRel rel[2]; };
struct AggParams { AggGroup grp[3]; const float* gtab; };

__global__ __launch_bounds__(256) void agg_kernel(AggParams P) {
  int gnode = (blockIdx.x * 256 + threadIdx.x) >> 4;
  int sl = threadIdx.x & 15;      // sublane within node group
  int h = sl >> 2;                // head this lane's 8 dims belong to
  int gi, node;
  int n0 = P.grp[0].n, n1 = P.grp[1].n, n2 = P.grp[2].n;
  if (gnode < n0) { gi = 0; node = gnode; }
  else if (gnode < n0 + n1) { gi = 1; node = gnode - n0; }
  else if (gnode < n0 + n1 + n2) { gi = 2; node = gnode - n0 - n1; }
  else return;
  const AggGroup& Gr = P.grp[gi];
  float acc[8];
#pragma unroll
  for (int j = 0; j < 8; ++j) acc[j] = 0.f;

  for (int rs = 0; rs < 2; ++rs) {
    const AggRel& R = Gr.rel[rs];
    int rp = R.rowp[node], re = R.rowp[node + 1];
    if (rp == re) continue;
    float4 ad4 = *reinterpret_cast<const float4*>(R.adv + (size_t)node * 16);
    int deg = re - rp;

    if (deg <= 16) {
      // one edge per sublane; everything stays in registers
      float e0 = -1e30f, e1 = -1e30f, e2 = -1e30f, e3 = -1e30f;
      int i_e = 0, si_e = 0, gx_e = 0;
      bool ok = sl < deg;
      if (ok) {
        i_e = R.col[rp + sl];
        si_e = R.src[i_e];
        float4 s4 = *reinterpret_cast<const float4*>(R.asv + (size_t)si_e * 16);
        e0 = s4.x + ad4.x; e0 = e0 > 0.f ? e0 : 0.2f * e0;
        e1 = s4.y + ad4.y; e1 = e1 > 0.f ? e1 : 0.2f * e1;
        e2 = s4.z + ad4.z; e2 = e2 > 0.f ? e2 : 0.2f * e2;
        e3 = s4.w + ad4.w; e3 = e3 > 0.f ? e3 : 0.2f * e3;
        if (R.gtype == 1 || R.gtype == 2)
          gx_e = R.ea[(size_t)i_e * 2] * 5 + R.ea[(size_t)i_e * 2 + 1];
      }
      float m0 = e0, m1 = e1, m2 = e2, m3 = e3;
#pragma unroll
      for (int d = 1; d < 16; d <<= 1) {
        m0 = fmaxf(m0, __shfl_xor(m0, d));
        m1 = fmaxf(m1, __shfl_xor(m1, d));
        m2 = fmaxf(m2, __shfl_xor(m2, d));
        m3 = fmaxf(m3, __shfl_xor(m3, d));
      }
      float x0 = ok ? __expf(e0 - m0) : 0.f;
      float x1 = ok ? __expf(e1 - m1) : 0.f;
      float x2 = ok ? __expf(e2 - m2) : 0.f;
      float x3 = ok ? __expf(e3 - m3) : 0.f;
      float s0 = x0, s1 = x1, s2 = x2, s3 = x3;
#pragma unroll
      for (int d = 1; d < 16; d <<= 1) {
        s0 += __shfl_xor(s0, d);
        s1 += __shfl_xor(s1, d);
        s2 += __shfl_xor(s2, d);
        s3 += __shfl_xor(s3, d);
      }
      // per-lane alphas of its OWN edge for all 4 heads (exp already paid)
      float a0 = x0 * fast_rcp(s0 + 1e-16f);
      float a1 = x1 * fast_rcp(s1 + 1e-16f);
      float a2 = x2 * fast_rcp(s2 + 1e-16f);
      float a3 = x3 * fast_rcp(s3 + 1e-16f);

      for (int j = 0; j < deg; ++j) {
        int sij = __shfl(si_e, j, 16);
        float alpha = sel4(__shfl(a0, j, 16), __shfl(a1, j, 16),
                           __shfl(a2, j, 16), __shfl(a3, j, 16), h);
        s16x8 ms = *reinterpret_cast<const s16x8*>(R.hs + (size_t)sij * 128 + 8 * sl);
        if (R.gtype == 0) {
#pragma unroll
          for (int j2 = 0; j2 < 8; ++j2) acc[j2] += alpha * bf2f((unsigned short)ms[j2]);
        } else if (R.gtype == 3) {
          int ij = __shfl(i_e, j, 16);
          s16x8 gq = *reinterpret_cast<const s16x8*>(R.G + (size_t)ij * 128 + 8 * sl);
#pragma unroll
          for (int j2 = 0; j2 < 8; ++j2) acc[j2] += alpha * bf2f((unsigned short)ms[j2]) * bf2f((unsigned short)gq[j2]);
        } else {
          int gxj = __shfl(gx_e, j, 16);
          const float* gp = P.gtab + (size_t)((R.gtype - 1) * 50 + gxj) * 128 + 8 * sl;
          float4 g0 = *reinterpret_cast<const float4*>(gp);
          float4 g1 = *reinterpret_cast<const float4*>(gp + 4);
          acc[0] += alpha * bf2f((unsigned short)ms[0]) * g0.x;
          acc[1] += alpha * bf2f((unsigned short)ms[1]) * g0.y;
          acc[2] += alpha * bf2f((unsigned short)ms[2]) * g0.z;
          acc[3] += alpha * bf2f((unsigned short)ms[3]) * g0.w;
          acc[4] += alpha * bf2f((unsigned short)ms[4]) * g1.x;
          acc[5] += alpha * bf2f((unsigned short)ms[5]) * g1.y;
          acc[6] += alpha * bf2f((unsigned short)ms[6]) * g1.z;
          acc[7] += alpha * bf2f((unsigned short)ms[7]) * g1.w;
        }
      }
    } else {
      // rare high-degree: strided two-pass over 16 sublanes
      float m0 = -1e30f, m1 = -1e30f, m2 = -1e30f, m3 = -1e30f;
      for (int k = rp + sl; k < re; k += 16) {
        int i = R.col[k];
        int si = R.src[i];
        float4 s4 = *reinterpret_cast<const float4*>(R.asv + (size_t)si * 16);
        float e0 = s4.x + ad4.x; e0 = e0 > 0.f ? e0 : 0.2f * e0;
        float e1 = s4.y + ad4.y; e1 = e1 > 0.f ? e1 : 0.2f * e1;
        float e2 = s4.z + ad4.z; e2 = e2 > 0.f ? e2 : 0.2f * e2;
        float e3 = s4.w + ad4.w; e3 = e3 > 0.f ? e3 : 0.2f * e3;
        m0 = fmaxf(m0, e0); m1 = fmaxf(m1, e1); m2 = fmaxf(m2, e2); m3 = fmaxf(m3, e3);
      }
#pragma unroll
      for (int d = 1; d < 16; d <<= 1) {
        m0 = fmaxf(m0, __shfl_xor(m0, d));
        m1 = fmaxf(m1, __shfl_xor(m1, d));
        m2 = fmaxf(m2, __shfl_xor(m2, d));
        m3 = fmaxf(m3, __shfl_xor(m3, d));
      }
      float s0 = 0.f, s1 = 0.f, s2 = 0.f, s3 = 0.f;
      for (int k = rp + sl; k < re; k += 16) {
        int i = R.col[k];
        int si = R.src[i];
        float4 s4 = *reinterpret_cast<const float4*>(R.asv + (size_t)si * 16);
        float e0 = s4.x + ad4.x; e0 = e0 > 0.f ? e0 : 0.2f * e0;
        float e1 = s4.y + ad4.y; e1 = e1 > 0.f ? e1 : 0.2f * e1;
        float e2 = s4.z + ad4.z; e2 = e2 > 0.f ? e2 : 0.2f * e2;
        float e3 = s4.w + ad4.w; e3 = e3 > 0.f ? e3 : 0.2f * e3;
        s0 += __expf(e0 - m0); s1 += __expf(e1 - m1); s2 += __expf(e2 - m2); s3 += __expf(e3 - m3);
      }
#pragma unroll
      for (int d = 1; d < 16; d <<= 1) {
        s0 += __shfl_xor(s0, d);
        s1 += __shfl_xor(s1, d);
        s2 += __shfl_xor(s2, d);
        s3 += __shfl_xor(s3, d);
      }
      float mh = sel4(m0, m1, m2, m3, h);
      float invh = fast_rcp(sel4(s0, s1, s2, s3, h) + 1e-16f);
      float adh = sel4(ad4.x, ad4.y, ad4.z, ad4.w, h);
      for (int k = rp; k < re; ++k) {
        int i = R.col[k];                        // broadcast
        int si = R.src[i];
        float eh = R.asv[(size_t)si * 16 + h] + adh;
        eh = eh > 0.f ? eh : 0.2f * eh;
        float alpha = __expf(eh - mh) * invh;
        s16x8 ms = *reinterpret_cast<const s16x8*>(R.hs + (size_t)si * 128 + 8 * sl);
        if (R.gtype == 0) {
#pragma unroll
          for (int j2 = 0; j2 < 8; ++j2) acc[j2] += alpha * bf2f((unsigned short)ms[j2]);
        } else if (R.gtype == 3) {
          s16x8 gq = *reinterpret_cast<const s16x8*>(R.G + (size_t)i * 128 + 8 * sl);
#pragma unroll
          for (int j2 = 0; j2 < 8; ++j2) acc[j2] += alpha * bf2f((unsigned short)ms[j2]) * bf2f((unsigned short)gq[j2]);
        } else {
          int a = R.ea[(size_t)i * 2], s2i = R.ea[(size_t)i * 2 + 1];
          const float* gp = P.gtab + (size_t)((R.gtype - 1) * 50 + a * 5 + s2i) * 128 + 8 * sl;
          float4 g0 = *reinterpret_cast<const float4*>(gp);
          float4 g1 = *reinterpret_cast<const float4*>(gp + 4);
          acc[0] += alpha * bf2f((unsigned short)ms[0]) * g0.x;
          acc[1] += alpha * bf2f((unsigned short)ms[1]) * g0.y;
          acc[2] += alpha * bf2f((unsigned short)ms[2]) * g0.z;
          acc[3] += alpha * bf2f((unsigned short)ms[3]) * g0.w;
          acc[4] += alpha * bf2f((unsigned short)ms[4]) * g1.x;
          acc[5] += alpha * bf2f((unsigned short)ms[5]) * g1.y;
          acc[6] += alpha * bf2f((unsigned short)ms[6]) * g1.z;
          acc[7] += alpha * bf2f((unsigned short)ms[7]) * g1.w;
        }
      }
    }
  }
  s16x8 o;
#pragma unroll
  for (int j = 0; j < 8; ++j) o[j] = (short)f2bf(acc[j]);
  *reinterpret_cast<s16x8*>(Gr.aggbf + (size_t)node * 128 + 8 * sl) = o;
}

// categorical gate table
__global__ void gatetab_kernel(const float* at_emb, const float* as_emb,
                               const float* Wcat, const float* bcat, float* gtab, int l) {
  int rel = blockIdx.x / 50, combo = blockIdx.x % 50;
  int a = combo / 5, s2 = combo % 5;
  int d = threadIdx.x;
  const float* Wb = Wcat + (size_t)(l * 2 + rel) * 64 * 128;
  float acc = bcat[(size_t)(l * 2 + rel) * 128 + d];
  const float* ae = at_emb + (size_t)(l * 10 + a) * 32;
  const float* se = as_emb + (size_t)(l * 5 + s2) * 32;
  for (int k = 0; k < 32; ++k) acc += ae[k] * Wb[k * 128 + d];
  for (int k = 0; k < 32; ++k) acc += se[k] * Wb[(32 + k) * 128 + d];
  gtab[(size_t)(rel * 50 + combo) * 128 + d] = 1.f / (1.f + __expf(-acc));
}

// LayerNorm(xs_bf + tmp) -> xs_bf (bf16 state)
__global__ __launch_bounds__(256) void ln_kernel(unsigned short* xs_bf, const float* tmp,
                                                 const float* g_base, const float* b_base) {
  int wid = (blockIdx.x * blockDim.x + threadIdx.x) >> 6;
  int lane = threadIdx.x & 63;
  int nw = (gridDim.x * blockDim.x) >> 6;
  for (int row = wid; row < NTOT; row += nw) {
    int t = row < NC_ ? 0 : (row < NC_ + ND_ ? 1 : 2);
    size_t ro = (size_t)row * 128 + 2 * lane;
    ushort2 xb = *reinterpret_cast<const ushort2*>(xs_bf + ro);
    float2 tv = *reinterpret_cast<const float2*>(tmp + ro);
    float a = bf2f(xb.x) + tv.x, b = bf2f(xb.y) + tv.y;
    float s = a + b;
#pragma unroll
    for (int m = 1; m <= 32; m <<= 1) s += __shfl_xor(s, m);
    float mu = s * 0.0078125f;
    float da = a - mu, db = b - mu;
    float v = da * da + db * db;
#pragma unroll
    for (int m = 1; m <= 32; m <<= 1) v += __shfl_xor(v, m);
    float rs = rsqrtf(v * 0.0078125f + 1e-5f);
    float2 gg = *reinterpret_cast<const float2*>(g_base + t * 128 + 2 * lane);
    float2 bb = *reinterpret_cast<const float2*>(b_base + t * 128 + 2 * lane);
    ushort2 ob;
    ob.x = f2bf(da * rs * gg.x + bb.x);
    ob.y = f2bf(db * rs * gg.y + bb.y);
    *reinterpret_cast<ushort2*>(xs_bf + ro) = ob;
  }
}

// init: xs_bf (bf16) from the three embedding tables
__global__ __launch_bounds__(256) void cvt_init_kernel(const float* emb_c, const float* emb_d, const float* emb_g,
                                                       unsigned short* xs_bf) {
  int i = blockIdx.x * 256 + threadIdx.x;
  if (i >= NTOT * 64) return;
  int row = i >> 6;
  int cpos = (i & 63) * 2;
  const float* src;
  if (row < NC_) src = emb_c + (size_t)row * 128;
  else if (row < NC_ + ND_) src = emb_d + (size_t)(row - NC_) * 128;
  else src = emb_g + (size_t)(row - NC_ - ND_) * 128;
  float2 v = *reinterpret_cast<const float2*>(src + cpos);
  ushort2 ob; ob.x = f2bf(v.x); ob.y = f2bf(v.y);
  *reinterpret_cast<ushort2*>(xs_bf + (size_t)row * 128 + cpos) = ob;
}

// out[p] = dot(Ybf[ps[p]], x1bf[pd[p]])
__global__ __launch_bounds__(256) void pair_kernel(const unsigned short* Ybf, const unsigned short* x1bf,
                                                   const int* ps, const int* pd, float* out) {
  int hw = (blockIdx.x * blockDim.x + threadIdx.x) >> 5;
  int lane = threadIdx.x & 31;
  int nhw = (gridDim.x * blockDim.x) >> 5;
  for (int p = hw; p < PP_; p += nhw) {
    int ai = ps[p], bi = pd[p];
    ushort4 y = *reinterpret_cast<const ushort4*>(Ybf + (size_t)ai * 128 + 4 * lane);
    ushort4 x = *reinterpret_cast<const ushort4*>(x1bf + (size_t)bi * 128 + 4 * lane);
    float s = bf2f(y.x) * bf2f(x.x) + bf2f(y.y) * bf2f(x.y) +
              bf2f(y.z) * bf2f(x.z) + bf2f(y.w) * bf2f(x.w);
#pragma unroll
    for (int m = 1; m <= 16; m <<= 1) s += __shfl_xor(s, m, 32);
    if (lane == 0) out[p] = s;
  }
}

__global__ void fill_kernel(float* out, int n, float v) {
  int i = blockIdx.x * blockDim.x + threadIdx.x;
  if (i < n) out[i] = v;
}

// ---------------- host ----------------
extern "C" void kernel_launch(void* const* d_in, const int* in_sizes, int n_in,
                              void* d_out, int out_size, void* d_ws, size_t ws_size,
                              hipStream_t stream) {
  (void)in_sizes; (void)n_in;
  const float* emb_c = (const float*)d_in[0];
  const float* emb_d = (const float*)d_in[1];
  const float* emb_g = (const float*)d_in[2];
  const float* Wsrc  = (const float*)d_in[3];
  const float* bsrc  = (const float*)d_in[4];
  const float* Wdst  = (const float*)d_in[5];
  const float* bdst  = (const float*)d_in[6];
  const float* attn  = (const float*)d_in[7];
  const float* Wout  = (const float*)d_in[8];
  const float* bout  = (const float*)d_in[9];
  const float* ln_g  = (const float*)d_in[10];
  const float* ln_b  = (const float*)d_in[11];
  const float* at_emb = (const float*)d_in[12];
  const float* as_emb = (const float*)d_in[13];
  const float* Wcat  = (const float*)d_in[14];
  const float* bcat  = (const float*)d_in[15];
  const float* Wc1   = (const float*)d_in[16];
  const float* bc1   = (const float*)d_in[17];
  const float* Wc2   = (const float*)d_in[18];
  const float* bc2   = (const float*)d_in[19];
  const float* W_cd  = (const float*)d_in[20];
  const float* ea4   = (const float*)d_in[21];
  const float* ea5   = (const float*)d_in[22];
  const int* srcs[6] = {(const int*)d_in[23], (const int*)d_in[25], (const int*)d_in[27],
                        (const int*)d_in[29], (const int*)d_in[31], (const int*)d_in[33]};
  const int* dsts[6] = {(const int*)d_in[24], (const int*)d_in[26], (const int*)d_in[28],
                        (const int*)d_in[30], (const int*)d_in[32], (const int*)d_in[34]};
  const int* ea0 = (const int*)d_in[35];
  const int* ea1 = (const int*)d_in[36];
  const int* pair_src = (const int*)d_in[37];
  const int* pair_dst = (const int*)d_in[38];

  static const int ST_[6] = {0, 2, 0, 1, 1, 2};
  static const int NT_[3] = {NC_, ND_, NG_};
  static const int HSOFF[6] = {0, 50000, 80000, 130000, 150000, 170000};
  static const int SBLK[6] = {0, 0, 1, 0, 1, 1};
  static const int DBLK[6] = {2, 2, 2, 3, 3, 3};
  static const int DT_[6] = {2, 0, 1, 0, 2, 1};
  static const int rowbase[3] = {0, 50000, 70000};

  size_t off = 0;
  auto alloc = [&](size_t bytes) { off = (off + 255) & ~(size_t)255; size_t o = off; off += bytes; return o; };
  size_t o_xsbf  = alloc((size_t)NTOT * 256);         // bf16 node state (only copy)
  size_t o_agbf  = alloc((size_t)NTOT * 256);
  size_t o_hs    = alloc((size_t)200000 * 256);       // bf16 src proj | tmp f32 | Y bf16
  size_t o_G4    = alloc((size_t)200000 * 256);
  size_t o_G5    = alloc((size_t)200000 * 256);
  size_t o_av    = alloc((size_t)NTOT * 64);
  size_t o_wv    = alloc((size_t)3 * 128 * 16 * 2);
  size_t o_bw    = alloc((size_t)3 * 16 * 4);
  size_t o_gtab  = alloc((size_t)100 * 512);
  size_t o_wpack = alloc((size_t)23 * 16384 * 2);
  size_t o_cnt   = alloc((size_t)6 * 50000 * 4);
  size_t o_rowp  = alloc((size_t)6 * 50001 * 4);
  size_t o_cur   = alloc((size_t)6 * 50000 * 4);
  size_t o_col   = alloc((size_t)6 * EE * 4);
  if (off > ws_size) {
    fill_kernel<<<(PP_ + 255) / 256, 256, 0, stream>>>((float*)d_out, out_size, 1.0e6f);
    return;
  }

  char* ws = (char*)d_ws;
  unsigned short* xs_bf = (unsigned short*)(ws + o_xsbf);
  unsigned short* agg_bf = (unsigned short*)(ws + o_agbf);
  unsigned short* hs = (unsigned short*)(ws + o_hs);
  float* tmp = (float*)(ws + o_hs);
  unsigned short* Ybf = (unsigned short*)(ws + o_hs);
  unsigned short* G4 = (unsigned short*)(ws + o_G4);
  unsigned short* G5 = (unsigned short*)(ws + o_G5);
  float* av16 = (float*)(ws + o_av);
  unsigned short* wv = (unsigned short*)(ws + o_wv);
  float* bw = (float*)(ws + o_bw);
  float* gtab = (float*)(ws + o_gtab);
  unsigned short* wpack = (unsigned short*)(ws + o_wpack);
  int* cnt = (int*)(ws + o_cnt);
  int* rowp = (int*)(ws + o_rowp);
  int* cursor = (int*)(ws + o_cur);
  int* col = (int*)(ws + o_col);

  PackParams pk{};
  for (int l = 0; l < 2; ++l) {
    for (int r = 0; r < 6; ++r) pk.src[l * 11 + r] = Wsrc + (size_t)(l * 6 + r) * 16384;
    for (int k = 0; k < 2; ++k) pk.src[l * 11 + 6 + k] = Wc2 + (size_t)(l * 2 + k) * 16384;
    for (int t = 0; t < 3; ++t) pk.src[l * 11 + 8 + t] = Wout + (size_t)(l * 3 + t) * 16384;
  }
  pk.src[22] = W_cd;
  pk.dst = wpack;
  pack_kernel<<<23, 256, 0, stream>>>(pk);

  cvt_init_kernel<<<(NTOT * 64 + 255) / 256, 256, 0, stream>>>(emb_c, emb_d, emb_g, xs_bf);

  hipMemsetAsync(cnt, 0, (size_t)6 * 50000 * 4, stream);
  CSRParams cp{};
  for (int r = 0; r < 6; ++r) { cp.dst[r] = dsts[r]; cp.ndst[r] = NT_[DT_[r]]; }
  cp.cnt = cnt; cp.rowp = rowp; cp.cursor = cursor; cp.col = col;
  hist_kernel<<<2048, 256, 0, stream>>>(cp);
  scan_kernel<<<6, 1024, 0, stream>>>(cp);
  scatter_kernel<<<2048, 256, 0, stream>>>(cp);

  auto nb = [](int M) { return (M + 127) / 128; };

  for (int l = 0; l < 2; ++l) {
    gatetab_kernel<<<100, 128, 0, stream>>>(at_emb, as_emb, Wcat, bcat, gtab, l);
    wvbuild_kernel<<<48, 128, 0, stream>>>(Wsrc, Wdst, bsrc, bdst, attn, wv, bw, l);

    // one dispatch: 6 projections + G4 + G5
    GParams2 gp{};
    int blk = 0;
    for (int r = 0; r < 6; ++r) {
      int st = ST_[r];
      gp.e[r] = {xs_bf + (size_t)rowbase[st] * 128, wpack + (size_t)(l * 11 + r) * 16384,
                 bsrc + (size_t)(l * 6 + r) * 128, (void*)(hs + (size_t)HSOFF[r] * 128),
                 nullptr, nullptr, nullptr, NT_[st], 0, 0, 1, blk};
      blk += nb(NT_[st]);
    }
    gp.e[6] = {nullptr, wpack + (size_t)(l * 11 + 6) * 16384, bc2 + (size_t)(l * 2 + 0) * 128, (void*)G4,
               ea4, Wc1 + (size_t)(l * 2 + 0) * 256, bc1 + (size_t)(l * 2 + 0) * 128, EE, 2, 1, 1, blk};
    blk += nb(EE);
    gp.e[7] = {nullptr, wpack + (size_t)(l * 11 + 7) * 16384, bc2 + (size_t)(l * 2 + 1) * 128, (void*)G5,
               ea5, Wc1 + (size_t)(l * 2 + 1) * 256, bc1 + (size_t)(l * 2 + 1) * 128, EE, 2, 1, 1, blk};
    blk += nb(EE);
    gp.nent = 8;
    gemm2<<<blk, 256, 0, stream>>>(gp);

    advec_kernel<<<(NTOT + 63) / 64, 256, 0, stream>>>(xs_bf, wv, bw, av16);

    auto mkrel = [&](int r) {
      AggRel R;
      R.src = srcs[r]; R.col = col + (size_t)r * EE; R.rowp = rowp + (size_t)r * 50001;
      R.asv = av16 + (size_t)rowbase[ST_[r]] * 16 + SBLK[r] * 4;
      R.adv = av16 + (size_t)rowbase[DT_[r]] * 16 + DBLK[r] * 4;
      R.hs = hs + (size_t)HSOFF[r] * 128;
      R.ea = (r == 0) ? ea0 : (r == 1) ? ea1 : nullptr;
      R.G = (r == 4) ? G4 : (r == 5) ? G5 : nullptr;
      R.gtype = (r == 0) ? 1 : (r == 1) ? 2 : (r >= 4) ? 3 : 0;
      return R;
    };

    // single agg dispatch: all three dst-type groups
    AggParams pa{};
    pa.grp[0].n = NG_; pa.grp[0].aggbf = agg_bf + (size_t)rowbase[2] * 128;
    pa.grp[0].rel[0] = mkrel(0); pa.grp[0].rel[1] = mkrel(4);
    pa.grp[1].n = NC_; pa.grp[1].aggbf = agg_bf + (size_t)rowbase[0] * 128;
    pa.grp[1].rel[0] = mkrel(1); pa.grp[1].rel[1] = mkrel(3);
    pa.grp[2].n = ND_; pa.grp[2].aggbf = agg_bf + (size_t)rowbase[1] * 128;
    pa.grp[2].rel[0] = mkrel(2); pa.grp[2].rel[1] = mkrel(5);
    pa.gtab = gtab;
    agg_kernel<<<(NTOT * 16 + 255) / 256, 256, 0, stream>>>(pa);

    // Wout (3 entries) -> tmp f32 (aliases hs, dead after agg)
    GParams2 gw{};
    blk = 0;
    for (int t = 0; t < 3; ++t) {
      gw.e[t] = {agg_bf + (size_t)rowbase[t] * 128, wpack + (size_t)(l * 11 + 8 + t) * 16384,
                 bout + (size_t)(l * 3 + t) * 128, (void*)(tmp + (size_t)rowbase[t] * 128),
                 nullptr, nullptr, nullptr, NT_[t], 0, 0, 0, blk};
      blk += nb(NT_[t]);
    }
    gw.nent = 3;
    gemm2<<<blk, 256, 0, stream>>>(gw);

    ln_kernel<<<2048, 256, 0, stream>>>(xs_bf, tmp, ln_g + (size_t)l * 384, ln_b + (size_t)l * 384);
  }

  // Y = xs0 @ W_cd -> bf16
  GParams2 gy{};
  gy.e[0] = {xs_bf, wpack + (size_t)22 * 16384, nullptr, (void*)Ybf,
             nullptr, nullptr, nullptr, NC_, 0, 0, 1, 0};
  gy.nent = 1;
  gemm2<<<nb(NC_), 256, 0, stream>>>(gy);

  pair_kernel<<<2048, 256, 0, stream>>>(Ybf, xs_bf + (size_t)NC_ * 128, pair_src, pair_dst, (float*)d_out);
}

// Round 11
// 1187.938 us; speedup vs baseline: 5.4660x; 1.0362x over previous
//
#include <hip/hip_runtime.h>

typedef short s16x8 __attribute__((ext_vector_type(8)));
typedef float f32x4 __attribute__((ext_vector_type(4)));

#define DEV __device__ __forceinline__

static constexpr int NC_ = 50000, ND_ = 20000, NG_ = 30000;
static constexpr int EE = 200000, PP_ = 200000;
static constexpr int NTOT = NC_ + ND_ + NG_;   // 100000

DEV unsigned short f2bf(float f) {
  unsigned u = __float_as_uint(f);
  u = u + 0x7FFFu + ((u >> 16) & 1u);
  return (unsigned short)(u >> 16);
}
DEV float bf2f(unsigned short h) { return __uint_as_float(((unsigned)h) << 16); }
DEV float sel4(float a, float b, float c, float d, int h) {
  float lo = (h & 1) ? b : a;
  float hi = (h & 1) ? d : c;
  return (h & 2) ? hi : lo;
}
DEV float fast_rcp(float x) {
#if __has_builtin(__builtin_amdgcn_rcpf)
  return __builtin_amdgcn_rcpf(x);
#else
  return 1.f / x;
#endif
}
DEV float gelu_fast(float x) { return x * fast_rcp(1.f + __expf(-1.702f * x)); }
DEV float sigmoid_fast(float x) { return fast_rcp(1.f + __expf(-x)); }

// ---------------- weight prepack: f32 [k][n] -> bf16 fragment-linear ----------------
struct PackParams { const float* src[23]; unsigned short* dst; };
__global__ __launch_bounds__(256) void pack_kernel(PackParams P) {
  int m = blockIdx.x;
  const float* S = P.src[m];
  unsigned short* D = P.dst + (size_t)m * 16384;
  for (int idx = threadIdx.x; idx < 16384; idx += 256) {
    int j = idx & 7;
    int lane = (idx >> 3) & 63;
    int snb = idx >> 9;
    int s = snb >> 3, nbb = snb & 7;
    int k = s * 32 + 8 * (lane >> 4) + j;
    int n = nbb * 16 + (lane & 15);
    D[idx] = f2bf(S[k * 128 + n]);
  }
}

// ---------------- gate A-matrix generation: G[row][k] = gelu(e0*Wc1[0,k]+e1*Wc1[1,k]+bc1[k]) ----------------
__global__ __launch_bounds__(256) void gelugen_kernel(const float* ea4, const float* ea5,
                                                      const float* Wc1, const float* bc1,
                                                      unsigned short* G4, unsigned short* G5, int l) {
  __shared__ float w[2][3][128];
  if (threadIdx.x < 128) {
    for (int gate = 0; gate < 2; ++gate) {
      const float* W = Wc1 + (size_t)(l * 2 + gate) * 256;
      const float* b = bc1 + (size_t)(l * 2 + gate) * 128;
      w[gate][0][threadIdx.x] = W[threadIdx.x];
      w[gate][1][threadIdx.x] = W[128 + threadIdx.x];
      w[gate][2][threadIdx.x] = b[threadIdx.x];
    }
  }
  __syncthreads();
  int idx = blockIdx.x * 256 + threadIdx.x;
  int n = gridDim.x * 256;
  for (int t = idx; t < 2 * EE * 16; t += n) {     // 16 segments of 8 cols per row
    int gate = t >= EE * 16;
    int tt = gate ? t - EE * 16 : t;
    int row = tt >> 4, seg = tt & 15;
    const float* ea = gate ? ea5 : ea4;
    float e0 = ea[(size_t)row * 2], e1 = ea[(size_t)row * 2 + 1];
    s16x8 o;
#pragma unroll
    for (int j = 0; j < 8; ++j) {
      int k = seg * 8 + j;
      float h = e0 * w[gate][0][k] + e1 * w[gate][1][k] + w[gate][2][k];
      o[j] = (short)f2bf(gelu_fast(h));
    }
    *reinterpret_cast<s16x8*>((gate ? G5 : G4) + (size_t)row * 128 + seg * 8) = o;
  }
}

// ---------------- flattened batched 128-col GEMM (zero LDS, bf16 A, fragment-linear W) ----------------
struct GEntry2 {
  const unsigned short* A; const unsigned short* Wp; const float* bias; void* out;
  int M; int act; int outbf16; int blk0;
};
struct GParams2 { GEntry2 e[8]; int nent; };

__global__ __launch_bounds__(256) void gemm2(GParams2 P) {
  int bx = blockIdx.x;
  int ei = 0;
  while (ei + 1 < P.nent && bx >= P.e[ei + 1].blk0) ++ei;
  GEntry2 E = P.e[ei];
  const int M = E.M;
  const int row0 = (bx - E.blk0) * 128;
  if (row0 >= M) return;

  const int tid = threadIdx.x;
  const int w = tid >> 6, lane = tid & 63, g = lane >> 4, c = lane & 15;
  const int colHalf = (w & 1) * 64;
  const int rowHalf = (w >> 1) * 32;

  // B fragments: coalesced 16B/lane from fragment-linear Wp
  s16x8 Bf[4][4];
#pragma unroll
  for (int s = 0; s < 4; ++s)
#pragma unroll
    for (int nb = 0; nb < 4; ++nb) {
      int nbb = (w & 1) * 4 + nb;
      Bf[s][nb] = *reinterpret_cast<const s16x8*>(E.Wp + ((size_t)(s * 8 + nbb) * 64 + lane) * 8);
    }

#pragma unroll
  for (int itr = 0; itr < 2; ++itr) {
    if (row0 + itr * 64 >= M) break;
    const int rb = row0 + itr * 64 + rowHalf;

    s16x8 Af[2][4];
#pragma unroll
    for (int mt = 0; mt < 2; ++mt) {
      int row = rb + mt * 16 + c;
      int rr = row < M ? row : M - 1;
      const unsigned short* ap = E.A + (size_t)rr * 128;
#pragma unroll
      for (int s = 0; s < 4; ++s)
        Af[mt][s] = *reinterpret_cast<const s16x8*>(ap + s * 32 + 8 * g);
    }

    f32x4 acc[2][4];
#pragma unroll
    for (int mt = 0; mt < 2; ++mt)
#pragma unroll
      for (int nb = 0; nb < 4; ++nb) { acc[mt][nb][0] = 0.f; acc[mt][nb][1] = 0.f; acc[mt][nb][2] = 0.f; acc[mt][nb][3] = 0.f; }

#pragma unroll
    for (int mt = 0; mt < 2; ++mt)
#pragma unroll
      for (int s = 0; s < 4; ++s)
#pragma unroll
        for (int nb = 0; nb < 4; ++nb)
          acc[mt][nb] = __builtin_amdgcn_mfma_f32_16x16x32_bf16(Af[mt][s], Bf[s][nb], acc[mt][nb], 0, 0, 0);

#pragma unroll
    for (int mt = 0; mt < 2; ++mt)
#pragma unroll
      for (int nb = 0; nb < 4; ++nb) {
        int col = colHalf + nb * 16 + c;
        float bv = E.bias ? E.bias[col] : 0.f;
#pragma unroll
        for (int jj = 0; jj < 4; ++jj) {
          int row = rb + mt * 16 + 4 * g + jj;
          if (row < M) {
            float v = acc[mt][nb][jj] + bv;
            if (E.act == 1) v = sigmoid_fast(v);
            if (E.outbf16) ((unsigned short*)E.out)[(size_t)row * 128 + col] = f2bf(v);
            else ((float*)E.out)[(size_t)row * 128 + col] = v;
          }
        }
      }
  }
}

// ---------------- folded attention weights ----------------
__global__ void wvbuild_kernel(const float* Wsrc, const float* Wdst, const float* bsrc, const float* bdst,
                               const float* attn, unsigned short* wv, float* bw, int l) {
  static const int RELT[3][4] = {{0, 2, 1, 3}, {3, 4, 2, 5}, {1, 5, 0, 4}};
  int t = blockIdx.x >> 4, col = blockIdx.x & 15;
  int b = col >> 2, h = col & 3;
  int r = RELT[t][b];
  bool isSrc = b < 2;
  const float* W = (isSrc ? Wsrc : Wdst) + (size_t)(l * 6 + r) * 16384;
  const float* bias = (isSrc ? bsrc : bdst) + (size_t)(l * 6 + r) * 128;
  const float* at = attn + (size_t)(l * 6 + r) * 128 + h * 32;
  int k = threadIdx.x;
  float acc = 0.f;
  for (int dh = 0; dh < 32; ++dh) acc += W[k * 128 + h * 32 + dh] * at[dh];
  wv[((size_t)t * 128 + k) * 16 + col] = f2bf(acc);
  if (k == 0) {
    float bacc = 0.f;
    for (int dh = 0; dh < 32; ++dh) bacc += bias[h * 32 + dh] * at[dh];
    bw[t * 16 + col] = bacc;
  }
}

// av16[row][16] = xs_bf[row] @ wv[type(row)] + bw
__global__ __launch_bounds__(256) void advec_kernel(const unsigned short* xs_bf,
                                                    const unsigned short* wv, const float* bw, float* av16) {
  int rb0 = blockIdx.x * 64 + (threadIdx.x >> 6) * 16;
  if (rb0 >= NTOT) return;
  int lane = threadIdx.x & 63, g = lane >> 4, c = lane & 15;
  int t = rb0 >= (NC_ + ND_) ? 2 : (rb0 >= NC_ ? 1 : 0);
  const unsigned short* wvt = wv + (size_t)t * 2048;
  s16x8 Bf[4];
#pragma unroll
  for (int s = 0; s < 4; ++s) {
    s16x8 bfr;
#pragma unroll
    for (int i = 0; i < 8; ++i) bfr[i] = (short)wvt[(s * 32 + 8 * g + i) * 16 + c];
    Bf[s] = bfr;
  }
  f32x4 acc; acc[0] = 0.f; acc[1] = 0.f; acc[2] = 0.f; acc[3] = 0.f;
  const unsigned short* ap = xs_bf + (size_t)(rb0 + c) * 128;
#pragma unroll
  for (int s = 0; s < 4; ++s) {
    s16x8 a = *reinterpret_cast<const s16x8*>(ap + s * 32 + 8 * g);
    acc = __builtin_amdgcn_mfma_f32_16x16x32_bf16(a, Bf[s], acc, 0, 0, 0);
  }
  float bv = bw[t * 16 + c];
#pragma unroll
  for (int jj = 0; jj < 4; ++jj)
    av16[(size_t)(rb0 + 4 * g + jj) * 16 + c] = acc[jj] + bv;
}

// ---------------- CSR build ----------------
struct CSRParams {
  const int* dst[6];
  int* cnt; int* rowp; int* cursor; int* col;
  int ndst[6];
};

__global__ __launch_bounds__(256) void hist_kernel(CSRParams P) {
  int gt = blockIdx.x * blockDim.x + threadIdx.x;
  int n = gridDim.x * blockDim.x;
  for (int idx = gt; idx < 6 * EE; idx += n) {
    int rel = idx / EE, i = idx - rel * EE;
    atomicAdd(&P.cnt[rel * 50000 + P.dst[rel][i]], 1);
  }
}

__global__ __launch_bounds__(1024) void scan_kernel(CSRParams P) {
  int rel = blockIdx.x;
  int n = P.ndst[rel];
  const int* c = P.cnt + rel * 50000;
  int* rp = P.rowp + rel * 50001;
  int* cur = P.cursor + rel * 50000;
  __shared__ int part[1024];
  int tid = threadIdx.x;
  int chunk = (n + 1023) / 1024;
  int lo = tid * chunk, hi = lo + chunk;
  if (hi > n) hi = n;
  int s = 0;
  for (int j = lo; j < hi; ++j) s += c[j];
  part[tid] = s;
  __syncthreads();
  if (tid == 0) {
    int acc = 0;
    for (int k = 0; k < 1024; ++k) { int v = part[k]; part[k] = acc; acc += v; }
    rp[n] = acc;
  }
  __syncthreads();
  int acc = part[tid];
  for (int j = lo; j < hi; ++j) { rp[j] = acc; cur[j] = acc; acc += c[j]; }
}

__global__ __launch_bounds__(256) void scatter_kernel(CSRParams P) {
  int gt = blockIdx.x * blockDim.x + threadIdx.x;
  int n = gridDim.x * blockDim.x;
  for (int idx = gt; idx < 6 * EE; idx += n) {
    int rel = idx / EE, i = idx - rel * EE;
    int d = P.dst[rel][i];
    int pos = atomicAdd(&P.cursor[rel * 50000 + d], 1);
    P.col[rel * EE + pos] = i;
  }
}

// ---------------- fused per-dst aggregation: 16 lanes/node, 4 nodes/wave ----------------
struct AggRel {
  const int* src; const int* col; const int* rowp;
  const float* asv; const float* adv;
  const unsigned short* hs;
  const int* ea;
  const unsigned short* G;
  int gtype;          // 0 none, 1 gtab rel0, 2 gtab rel1, 3 G buffer
};
struct AggGroup { int n; unsigned short* aggbf; AggRel rel[2]; };
struct AggParams { AggGroup grp[3]; const float* gtab; };

__global__ __launch_bounds__(256) void agg_kernel(AggParams P) {
  int gnode = (blockIdx.x * 256 + threadIdx.x) >> 4;
  int sl = threadIdx.x & 15;      // sublane within node group
  int h = sl >> 2;                // head this lane's 8 dims belong to
  int gi, node;
  int n0 = P.grp[0].n, n1 = P.grp[1].n, n2 = P.grp[2].n;
  if (gnode < n0) { gi = 0; node = gnode; }
  else if (gnode < n0 + n1) { gi = 1; node = gnode - n0; }
  else if (gnode < n0 + n1 + n2) { gi = 2; node = gnode - n0 - n1; }
  else return;
  const AggGroup& Gr = P.grp[gi];
  float acc[8];
#pragma unroll
  for (int j = 0; j < 8; ++j) acc[j] = 0.f;

  for (int rs = 0; rs < 2; ++rs) {
    const AggRel& R = Gr.rel[rs];
    int rp = R.rowp[node], re = R.rowp[node + 1];
    if (rp == re) continue;
    float4 ad4 = *reinterpret_cast<const float4*>(R.adv + (size_t)node * 16);
    int deg = re - rp;

    if (deg <= 16) {
      float e0 = -1e30f, e1 = -1e30f, e2 = -1e30f, e3 = -1e30f;
      int i_e = 0, si_e = 0, gx_e = 0;
      bool ok = sl < deg;
      if (ok) {
        i_e = R.col[rp + sl];
        si_e = R.src[i_e];
        float4 s4 = *reinterpret_cast<const float4*>(R.asv + (size_t)si_e * 16);
        e0 = s4.x + ad4.x; e0 = e0 > 0.f ? e0 : 0.2f * e0;
        e1 = s4.y + ad4.y; e1 = e1 > 0.f ? e1 : 0.2f * e1;
        e2 = s4.z + ad4.z; e2 = e2 > 0.f ? e2 : 0.2f * e2;
        e3 = s4.w + ad4.w; e3 = e3 > 0.f ? e3 : 0.2f * e3;
        if (R.gtype == 1 || R.gtype == 2)
          gx_e = R.ea[(size_t)i_e * 2] * 5 + R.ea[(size_t)i_e * 2 + 1];
      }
      float m0 = e0, m1 = e1, m2 = e2, m3 = e3;
#pragma unroll
      for (int d = 1; d < 16; d <<= 1) {
        m0 = fmaxf(m0, __shfl_xor(m0, d));
        m1 = fmaxf(m1, __shfl_xor(m1, d));
        m2 = fmaxf(m2, __shfl_xor(m2, d));
        m3 = fmaxf(m3, __shfl_xor(m3, d));
      }
      float x0 = ok ? __expf(e0 - m0) : 0.f;
      float x1 = ok ? __expf(e1 - m1) : 0.f;
      float x2 = ok ? __expf(e2 - m2) : 0.f;
      float x3 = ok ? __expf(e3 - m3) : 0.f;
      float s0 = x0, s1 = x1, s2 = x2, s3 = x3;
#pragma unroll
      for (int d = 1; d < 16; d <<= 1) {
        s0 += __shfl_xor(s0, d);
        s1 += __shfl_xor(s1, d);
        s2 += __shfl_xor(s2, d);
        s3 += __shfl_xor(s3, d);
      }
      float a0 = x0 * fast_rcp(s0 + 1e-16f);
      float a1 = x1 * fast_rcp(s1 + 1e-16f);
      float a2 = x2 * fast_rcp(s2 + 1e-16f);
      float a3 = x3 * fast_rcp(s3 + 1e-16f);

      for (int j = 0; j < deg; ++j) {
        int sij = __shfl(si_e, j, 16);
        float alpha = sel4(__shfl(a0, j, 16), __shfl(a1, j, 16),
                           __shfl(a2, j, 16), __shfl(a3, j, 16), h);
        s16x8 ms = *reinterpret_cast<const s16x8*>(R.hs + (size_t)sij * 128 + 8 * sl);
        if (R.gtype == 0) {
#pragma unroll
          for (int j2 = 0; j2 < 8; ++j2) acc[j2] += alpha * bf2f((unsigned short)ms[j2]);
        } else if (R.gtype == 3) {
          int ij = __shfl(i_e, j, 16);
          s16x8 gq = *reinterpret_cast<const s16x8*>(R.G + (size_t)ij * 128 + 8 * sl);
#pragma unroll
          for (int j2 = 0; j2 < 8; ++j2) acc[j2] += alpha * bf2f((unsigned short)ms[j2]) * bf2f((unsigned short)gq[j2]);
        } else {
          int gxj = __shfl(gx_e, j, 16);
          const float* gp = P.gtab + (size_t)((R.gtype - 1) * 50 + gxj) * 128 + 8 * sl;
          float4 g0 = *reinterpret_cast<const float4*>(gp);
          float4 g1 = *reinterpret_cast<const float4*>(gp + 4);
          acc[0] += alpha * bf2f((unsigned short)ms[0]) * g0.x;
          acc[1] += alpha * bf2f((unsigned short)ms[1]) * g0.y;
          acc[2] += alpha * bf2f((unsigned short)ms[2]) * g0.z;
          acc[3] += alpha * bf2f((unsigned short)ms[3]) * g0.w;
          acc[4] += alpha * bf2f((unsigned short)ms[4]) * g1.x;
          acc[5] += alpha * bf2f((unsigned short)ms[5]) * g1.y;
          acc[6] += alpha * bf2f((unsigned short)ms[6]) * g1.z;
          acc[7] += alpha * bf2f((unsigned short)ms[7]) * g1.w;
        }
      }
    } else {
      float m0 = -1e30f, m1 = -1e30f, m2 = -1e30f, m3 = -1e30f;
      for (int k = rp + sl; k < re; k += 16) {
        int i = R.col[k];
        int si = R.src[i];
        float4 s4 = *reinterpret_cast<const float4*>(R.asv + (size_t)si * 16);
        float e0 = s4.x + ad4.x; e0 = e0 > 0.f ? e0 : 0.2f * e0;
        float e1 = s4.y + ad4.y; e1 = e1 > 0.f ? e1 : 0.2f * e1;
        float e2 = s4.z + ad4.z; e2 = e2 > 0.f ? e2 : 0.2f * e2;
        float e3 = s4.w + ad4.w; e3 = e3 > 0.f ? e3 : 0.2f * e3;
        m0 = fmaxf(m0, e0); m1 = fmaxf(m1, e1); m2 = fmaxf(m2, e2); m3 = fmaxf(m3, e3);
      }
#pragma unroll
      for (int d = 1; d < 16; d <<= 1) {
        m0 = fmaxf(m0, __shfl_xor(m0, d));
        m1 = fmaxf(m1, __shfl_xor(m1, d));
        m2 = fmaxf(m2, __shfl_xor(m2, d));
        m3 = fmaxf(m3, __shfl_xor(m3, d));
      }
      float s0 = 0.f, s1 = 0.f, s2 = 0.f, s3 = 0.f;
      for (int k = rp + sl; k < re; k += 16) {
        int i = R.col[k];
        int si = R.src[i];
        float4 s4 = *reinterpret_cast<const float4*>(R.asv + (size_t)si * 16);
        float e0 = s4.x + ad4.x; e0 = e0 > 0.f ? e0 : 0.2f * e0;
        float e1 = s4.y + ad4.y; e1 = e1 > 0.f ? e1 : 0.2f * e1;
        float e2 = s4.z + ad4.z; e2 = e2 > 0.f ? e2 : 0.2f * e2;
        float e3 = s4.w + ad4.w; e3 = e3 > 0.f ? e3 : 0.2f * e3;
        s0 += __expf(e0 - m0); s1 += __expf(e1 - m1); s2 += __expf(e2 - m2); s3 += __expf(e3 - m3);
      }
#pragma unroll
      for (int d = 1; d < 16; d <<= 1) {
        s0 += __shfl_xor(s0, d);
        s1 += __shfl_xor(s1, d);
        s2 += __shfl_xor(s2, d);
        s3 += __shfl_xor(s3, d);
      }
      float mh = sel4(m0, m1, m2, m3, h);
      float invh = fast_rcp(sel4(s0, s1, s2, s3, h) + 1e-16f);
      float adh = sel4(ad4.x, ad4.y, ad4.z, ad4.w, h);
      for (int k = rp; k < re; ++k) {
        int i = R.col[k];
        int si = R.src[i];
        float eh = R.asv[(size_t)si * 16 + h] + adh;
        eh = eh > 0.f ? eh : 0.2f * eh;
        float alpha = __expf(eh - mh) * invh;
        s16x8 ms = *reinterpret_cast<const s16x8*>(R.hs + (size_t)si * 128 + 8 * sl);
        if (R.gtype == 0) {
#pragma unroll
          for (int j2 = 0; j2 < 8; ++j2) acc[j2] += alpha * bf2f((unsigned short)ms[j2]);
        } else if (R.gtype == 3) {
          s16x8 gq = *reinterpret_cast<const s16x8*>(R.G + (size_t)i * 128 + 8 * sl);
#pragma unroll
          for (int j2 = 0; j2 < 8; ++j2) acc[j2] += alpha * bf2f((unsigned short)ms[j2]) * bf2f((unsigned short)gq[j2]);
        } else {
          int a = R.ea[(size_t)i * 2], s2i = R.ea[(size_t)i * 2 + 1];
          const float* gp = P.gtab + (size_t)((R.gtype - 1) * 50 + a * 5 + s2i) * 128 + 8 * sl;
          float4 g0 = *reinterpret_cast<const float4*>(gp);
          float4 g1 = *reinterpret_cast<const float4*>(gp + 4);
          acc[0] += alpha * bf2f((unsigned short)ms[0]) * g0.x;
          acc[1] += alpha * bf2f((unsigned short)ms[1]) * g0.y;
          acc[2] += alpha * bf2f((unsigned short)ms[2]) * g0.z;
          acc[3] += alpha * bf2f((unsigned short)ms[3]) * g0.w;
          acc[4] += alpha * bf2f((unsigned short)ms[4]) * g1.x;
          acc[5] += alpha * bf2f((unsigned short)ms[5]) * g1.y;
          acc[6] += alpha * bf2f((unsigned short)ms[6]) * g1.z;
          acc[7] += alpha * bf2f((unsigned short)ms[7]) * g1.w;
        }
      }
    }
  }
  s16x8 o;
#pragma unroll
  for (int j = 0; j < 8; ++j) o[j] = (short)f2bf(acc[j]);
  *reinterpret_cast<s16x8*>(Gr.aggbf + (size_t)node * 128 + 8 * sl) = o;
}

// categorical gate table
__global__ void gatetab_kernel(const float* at_emb, const float* as_emb,
                               const float* Wcat, const float* bcat, float* gtab, int l) {
  int rel = blockIdx.x / 50, combo = blockIdx.x % 50;
  int a = combo / 5, s2 = combo % 5;
  int d = threadIdx.x;
  const float* Wb = Wcat + (size_t)(l * 2 + rel) * 64 * 128;
  float acc = bcat[(size_t)(l * 2 + rel) * 128 + d];
  const float* ae = at_emb + (size_t)(l * 10 + a) * 32;
  const float* se = as_emb + (size_t)(l * 5 + s2) * 32;
  for (int k = 0; k < 32; ++k) acc += ae[k] * Wb[k * 128 + d];
  for (int k = 0; k < 32; ++k) acc += se[k] * Wb[(32 + k) * 128 + d];
  gtab[(size_t)(rel * 50 + combo) * 128 + d] = 1.f / (1.f + __expf(-acc));
}

// LayerNorm(xs_bf + tmp) -> xs_bf (bf16 state)
__global__ __launch_bounds__(256) void ln_kernel(unsigned short* xs_bf, const float* tmp,
                                                 const float* g_base, const float* b_base) {
  int wid = (blockIdx.x * blockDim.x + threadIdx.x) >> 6;
  int lane = threadIdx.x & 63;
  int nw = (gridDim.x * blockDim.x) >> 6;
  for (int row = wid; row < NTOT; row += nw) {
    int t = row < NC_ ? 0 : (row < NC_ + ND_ ? 1 : 2);
    size_t ro = (size_t)row * 128 + 2 * lane;
    ushort2 xb = *reinterpret_cast<const ushort2*>(xs_bf + ro);
    float2 tv = *reinterpret_cast<const float2*>(tmp + ro);
    float a = bf2f(xb.x) + tv.x, b = bf2f(xb.y) + tv.y;
    float s = a + b;
#pragma unroll
    for (int m = 1; m <= 32; m <<= 1) s += __shfl_xor(s, m);
    float mu = s * 0.0078125f;
    float da = a - mu, db = b - mu;
    float v = da * da + db * db;
#pragma unroll
    for (int m = 1; m <= 32; m <<= 1) v += __shfl_xor(v, m);
    float rs = rsqrtf(v * 0.0078125f + 1e-5f);
    float2 gg = *reinterpret_cast<const float2*>(g_base + t * 128 + 2 * lane);
    float2 bb = *reinterpret_cast<const float2*>(b_base + t * 128 + 2 * lane);
    ushort2 ob;
    ob.x = f2bf(da * rs * gg.x + bb.x);
    ob.y = f2bf(db * rs * gg.y + bb.y);
    *reinterpret_cast<ushort2*>(xs_bf + ro) = ob;
  }
}

// init: xs_bf (bf16) from the three embedding tables
__global__ __launch_bounds__(256) void cvt_init_kernel(const float* emb_c, const float* emb_d, const float* emb_g,
                                                       unsigned short* xs_bf) {
  int i = blockIdx.x * 256 + threadIdx.x;
  if (i >= NTOT * 64) return;
  int row = i >> 6;
  int cpos = (i & 63) * 2;
  const float* src;
  if (row < NC_) src = emb_c + (size_t)row * 128;
  else if (row < NC_ + ND_) src = emb_d + (size_t)(row - NC_) * 128;
  else src = emb_g + (size_t)(row - NC_ - ND_) * 128;
  float2 v = *reinterpret_cast<const float2*>(src + cpos);
  ushort2 ob; ob.x = f2bf(v.x); ob.y = f2bf(v.y);
  *reinterpret_cast<ushort2*>(xs_bf + (size_t)row * 128 + cpos) = ob;
}

// out[p] = dot(Ybf[ps[p]], x1bf[pd[p]])
__global__ __launch_bounds__(256) void pair_kernel(const unsigned short* Ybf, const unsigned short* x1bf,
                                                   const int* ps, const int* pd, float* out) {
  int hw = (blockIdx.x * blockDim.x + threadIdx.x) >> 5;
  int lane = threadIdx.x & 31;
  int nhw = (gridDim.x * blockDim.x) >> 5;
  for (int p = hw; p < PP_; p += nhw) {
    int ai = ps[p], bi = pd[p];
    ushort4 y = *reinterpret_cast<const ushort4*>(Ybf + (size_t)ai * 128 + 4 * lane);
    ushort4 x = *reinterpret_cast<const ushort4*>(x1bf + (size_t)bi * 128 + 4 * lane);
    float s = bf2f(y.x) * bf2f(x.x) + bf2f(y.y) * bf2f(x.y) +
              bf2f(y.z) * bf2f(x.z) + bf2f(y.w) * bf2f(x.w);
#pragma unroll
    for (int m = 1; m <= 16; m <<= 1) s += __shfl_xor(s, m, 32);
    if (lane == 0) out[p] = s;
  }
}

__global__ void fill_kernel(float* out, int n, float v) {
  int i = blockIdx.x * blockDim.x + threadIdx.x;
  if (i < n) out[i] = v;
}

// ---------------- host ----------------
extern "C" void kernel_launch(void* const* d_in, const int* in_sizes, int n_in,
                              void* d_out, int out_size, void* d_ws, size_t ws_size,
                              hipStream_t stream) {
  (void)in_sizes; (void)n_in;
  const float* emb_c = (const float*)d_in[0];
  const float* emb_d = (const float*)d_in[1];
  const float* emb_g = (const float*)d_in[2];
  const float* Wsrc  = (const float*)d_in[3];
  const float* bsrc  = (const float*)d_in[4];
  const float* Wdst  = (const float*)d_in[5];
  const float* bdst  = (const float*)d_in[6];
  const float* attn  = (const float*)d_in[7];
  const float* Wout  = (const float*)d_in[8];
  const float* bout  = (const float*)d_in[9];
  const float* ln_g  = (const float*)d_in[10];
  const float* ln_b  = (const float*)d_in[11];
  const float* at_emb = (const float*)d_in[12];
  const float* as_emb = (const float*)d_in[13];
  const float* Wcat  = (const float*)d_in[14];
  const float* bcat  = (const float*)d_in[15];
  const float* Wc1   = (const float*)d_in[16];
  const float* bc1   = (const float*)d_in[17];
  const float* Wc2   = (const float*)d_in[18];
  const float* bc2   = (const float*)d_in[19];
  const float* W_cd  = (const float*)d_in[20];
  const float* ea4   = (const float*)d_in[21];
  const float* ea5   = (const float*)d_in[22];
  const int* srcs[6] = {(const int*)d_in[23], (const int*)d_in[25], (const int*)d_in[27],
                        (const int*)d_in[29], (const int*)d_in[31], (const int*)d_in[33]};
  const int* dsts[6] = {(const int*)d_in[24], (const int*)d_in[26], (const int*)d_in[28],
                        (const int*)d_in[30], (const int*)d_in[32], (const int*)d_in[34]};
  const int* ea0 = (const int*)d_in[35];
  const int* ea1 = (const int*)d_in[36];
  const int* pair_src = (const int*)d_in[37];
  const int* pair_dst = (const int*)d_in[38];

  static const int ST_[6] = {0, 2, 0, 1, 1, 2};
  static const int NT_[3] = {NC_, ND_, NG_};
  static const int HSOFF[6] = {0, 50000, 80000, 130000, 150000, 170000};
  static const int SBLK[6] = {0, 0, 1, 0, 1, 1};
  static const int DBLK[6] = {2, 2, 2, 3, 3, 3};
  static const int DT_[6] = {2, 0, 1, 0, 2, 1};
  static const int rowbase[3] = {0, 50000, 70000};

  size_t off = 0;
  auto alloc = [&](size_t bytes) { off = (off + 255) & ~(size_t)255; size_t o = off; off += bytes; return o; };
  size_t o_xsbf  = alloc((size_t)NTOT * 256);         // bf16 node state
  size_t o_agbf  = alloc((size_t)NTOT * 256);
  size_t o_hs    = alloc((size_t)200000 * 256);       // bf16 src proj | tmp f32 | Y bf16
  size_t o_G4    = alloc((size_t)200000 * 256);       // gelu-A then gate G4 (in-place GEMM)
  size_t o_G5    = alloc((size_t)200000 * 256);
  size_t o_av    = alloc((size_t)NTOT * 64);
  size_t o_wv    = alloc((size_t)3 * 128 * 16 * 2);
  size_t o_bw    = alloc((size_t)3 * 16 * 4);
  size_t o_gtab  = alloc((size_t)100 * 512);
  size_t o_wpack = alloc((size_t)23 * 16384 * 2);
  size_t o_cnt   = alloc((size_t)6 * 50000 * 4);
  size_t o_rowp  = alloc((size_t)6 * 50001 * 4);
  size_t o_cur   = alloc((size_t)6 * 50000 * 4);
  size_t o_col   = alloc((size_t)6 * EE * 4);
  if (off > ws_size) {
    fill_kernel<<<(PP_ + 255) / 256, 256, 0, stream>>>((float*)d_out, out_size, 1.0e6f);
    return;
  }

  char* ws = (char*)d_ws;
  unsigned short* xs_bf = (unsigned short*)(ws + o_xsbf);
  unsigned short* agg_bf = (unsigned short*)(ws + o_agbf);
  unsigned short* hs = (unsigned short*)(ws + o_hs);
  float* tmp = (float*)(ws + o_hs);
  unsigned short* Ybf = (unsigned short*)(ws + o_hs);
  unsigned short* G4 = (unsigned short*)(ws + o_G4);
  unsigned short* G5 = (unsigned short*)(ws + o_G5);
  float* av16 = (float*)(ws + o_av);
  unsigned short* wv = (unsigned short*)(ws + o_wv);
  float* bw = (float*)(ws + o_bw);
  float* gtab = (float*)(ws + o_gtab);
  unsigned short* wpack = (unsigned short*)(ws + o_wpack);
  int* cnt = (int*)(ws + o_cnt);
  int* rowp = (int*)(ws + o_rowp);
  int* cursor = (int*)(ws + o_cur);
  int* col = (int*)(ws + o_col);

  PackParams pk{};
  for (int l = 0; l < 2; ++l) {
    for (int r = 0; r < 6; ++r) pk.src[l * 11 + r] = Wsrc + (size_t)(l * 6 + r) * 16384;
    for (int k = 0; k < 2; ++k) pk.src[l * 11 + 6 + k] = Wc2 + (size_t)(l * 2 + k) * 16384;
    for (int t = 0; t < 3; ++t) pk.src[l * 11 + 8 + t] = Wout + (size_t)(l * 3 + t) * 16384;
  }
  pk.src[22] = W_cd;
  pk.dst = wpack;
  pack_kernel<<<23, 256, 0, stream>>>(pk);

  cvt_init_kernel<<<(NTOT * 64 + 255) / 256, 256, 0, stream>>>(emb_c, emb_d, emb_g, xs_bf);

  hipMemsetAsync(cnt, 0, (size_t)6 * 50000 * 4, stream);
  CSRParams cp{};
  for (int r = 0; r < 6; ++r) { cp.dst[r] = dsts[r]; cp.ndst[r] = NT_[DT_[r]]; }
  cp.cnt = cnt; cp.rowp = rowp; cp.cursor = cursor; cp.col = col;
  hist_kernel<<<2048, 256, 0, stream>>>(cp);
  scan_kernel<<<6, 1024, 0, stream>>>(cp);
  scatter_kernel<<<2048, 256, 0, stream>>>(cp);

  auto nb = [](int M) { return (M + 127) / 128; };

  for (int l = 0; l < 2; ++l) {
    gatetab_kernel<<<100, 128, 0, stream>>>(at_emb, as_emb, Wcat, bcat, gtab, l);
    wvbuild_kernel<<<48, 128, 0, stream>>>(Wsrc, Wdst, bsrc, bdst, attn, wv, bw, l);
    gelugen_kernel<<<2048, 256, 0, stream>>>(ea4, ea5, Wc1, bc1, G4, G5, l);

    // one dispatch: 6 projections + G4 + G5 (gates read/write in place)
    GParams2 gp{};
    int blk = 0;
    for (int r = 0; r < 6; ++r) {
      int st = ST_[r];
      gp.e[r] = {xs_bf + (size_t)rowbase[st] * 128, wpack + (size_t)(l * 11 + r) * 16384,
                 bsrc + (size_t)(l * 6 + r) * 128, (void*)(hs + (size_t)HSOFF[r] * 128),
                 NT_[st], 0, 1, blk};
      blk += nb(NT_[st]);
    }
    gp.e[6] = {G4, wpack + (size_t)(l * 11 + 6) * 16384, bc2 + (size_t)(l * 2 + 0) * 128, (void*)G4,
               EE, 1, 1, blk};
    blk += nb(EE);
    gp.e[7] = {G5, wpack + (size_t)(l * 11 + 7) * 16384, bc2 + (size_t)(l * 2 + 1) * 128, (void*)G5,
               EE, 1, 1, blk};
    blk += nb(EE);
    gp.nent = 8;
    gemm2<<<blk, 256, 0, stream>>>(gp);

    advec_kernel<<<(NTOT + 63) / 64, 256, 0, stream>>>(xs_bf, wv, bw, av16);

    auto mkrel = [&](int r) {
      AggRel R;
      R.src = srcs[r]; R.col = col + (size_t)r * EE; R.rowp = rowp + (size_t)r * 50001;
      R.asv = av16 + (size_t)rowbase[ST_[r]] * 16 + SBLK[r] * 4;
      R.adv = av16 + (size_t)rowbase[DT_[r]] * 16 + DBLK[r] * 4;
      R.hs = hs + (size_t)HSOFF[r] * 128;
      R.ea = (r == 0) ? ea0 : (r == 1) ? ea1 : nullptr;
      R.G = (r == 4) ? G4 : (r == 5) ? G5 : nullptr;
      R.gtype = (r == 0) ? 1 : (r == 1) ? 2 : (r >= 4) ? 3 : 0;
      return R;
    };

    AggParams pa{};
    pa.grp[0].n = NG_; pa.grp[0].aggbf = agg_bf + (size_t)rowbase[2] * 128;
    pa.grp[0].rel[0] = mkrel(0); pa.grp[0].rel[1] = mkrel(4);
    pa.grp[1].n = NC_; pa.grp[1].aggbf = agg_bf + (size_t)rowbase[0] * 128;
    pa.grp[1].rel[0] = mkrel(1); pa.grp[1].rel[1] = mkrel(3);
    pa.grp[2].n = ND_; pa.grp[2].aggbf = agg_bf + (size_t)rowbase[1] * 128;
    pa.grp[2].rel[0] = mkrel(2); pa.grp[2].rel[1] = mkrel(5);
    pa.gtab = gtab;
    agg_kernel<<<(NTOT * 16 + 255) / 256, 256, 0, stream>>>(pa);

    // Wout (3 entries) -> tmp f32 (aliases hs, dead after agg)
    GParams2 gw{};
    blk = 0;
    for (int t = 0; t < 3; ++t) {
      gw.e[t] = {agg_bf + (size_t)rowbase[t] * 128, wpack + (size_t)(l * 11 + 8 + t) * 16384,
                 bout + (size_t)(l * 3 + t) * 128, (void*)(tmp + (size_t)rowbase[t] * 128),
                 NT_[t], 0, 0, blk};
      blk += nb(NT_[t]);
    }
    gw.nent = 3;
    gemm2<<<blk, 256, 0, stream>>>(gw);

    ln_kernel<<<2048, 256, 0, stream>>>(xs_bf, tmp, ln_g + (size_t)l * 384, ln_b + (size_t)l * 384);
  }

  // Y = xs0 @ W_cd -> bf16
  GParams2 gy{};
  gy.e[0] = {xs_bf, wpack + (size_t)22 * 16384, nullptr, (void*)Ybf, NC_, 0, 1, 0};
  gy.nent = 1;
  gemm2<<<nb(NC_), 256, 0, stream>>>(gy);

  pair_kernel<<<2048, 256, 0, stream>>>(Ybf, xs_bf + (size_t)NC_ * 128, pair_src, pair_dst, (float*)d_out);
}